// Round 1
// baseline (836.302 us; speedup 1.0000x reference)
//
#include <hip/hip_runtime.h>
#include <math.h>

#define NEG_SLOPE 0.2f

__device__ __forceinline__ float lky(float x){ return x > 0.f ? x : NEG_SLOPE * x; }

// ---------------- CSR build ----------------
__global__ void zero_ints_kernel(int* __restrict__ p, int n){
  int i = blockIdx.x * blockDim.x + threadIdx.x;
  if (i < n) p[i] = 0;
}

__global__ void count_deg_kernel(const int* __restrict__ dst, int* __restrict__ deg, int E){
  int e = blockIdx.x * blockDim.x + threadIdx.x;
  if (e < E) atomicAdd(&deg[dst[e]], 1);
}

__global__ void scan_chunk_kernel(const int* __restrict__ deg, int* __restrict__ rowptr,
                                  int* __restrict__ bsum, int n){
  __shared__ int s[256];
  int t = threadIdx.x;
  int i = blockIdx.x * 256 + t;
  int v = (i < n) ? deg[i] : 0;
  s[t] = v; __syncthreads();
  for (int off = 1; off < 256; off <<= 1){
    int x = (t >= off) ? s[t - off] : 0;
    __syncthreads();
    s[t] += x;
    __syncthreads();
  }
  if (i < n) rowptr[i + 1] = s[t];          // inclusive within chunk
  if (t == 255) bsum[blockIdx.x] = s[255];
}

__global__ void scan_bsum_kernel(const int* __restrict__ bsum, int* __restrict__ boff, int nb){
  __shared__ int s[256];
  int t = threadIdx.x;
  int v = (t < nb) ? bsum[t] : 0;
  s[t] = v; __syncthreads();
  for (int off = 1; off < 256; off <<= 1){
    int x = (t >= off) ? s[t - off] : 0;
    __syncthreads();
    s[t] += x;
    __syncthreads();
  }
  boff[t] = s[t] - v;                        // exclusive
}

__global__ void scan_add_kernel(int* __restrict__ rowptr, const int* __restrict__ boff, int n){
  int i = blockIdx.x * 256 + threadIdx.x;
  if (i < n) rowptr[i + 1] += boff[blockIdx.x];
  if (i == 0) rowptr[0] = 0;
}

__global__ void fill_csr_kernel(const int* __restrict__ src, const int* __restrict__ dst,
                                const int* __restrict__ rowptr, int* __restrict__ cursor,
                                int* __restrict__ colv, int E){
  int e = blockIdx.x * blockDim.x + threadIdx.x;
  if (e >= E) return;
  int d = dst[e];
  int pos = atomicAdd(&cursor[d], 1);
  colv[rowptr[d] + pos] = src[e];
}

// ---------------- GEMM (K x 256) + attention scores fused ----------------
// Tile: 16 nodes x 256 cols per block of 256 threads.
// thread t: tx = t&63 -> cols tx*4..tx*4+3 ; ty = t>>6 -> nodes ty*4..ty*4+3
template<int K>
__global__ __launch_bounds__(256) void gemm_scores_kernel(
    const float* __restrict__ X, const float* __restrict__ W,
    const float* __restrict__ avs, const float* __restrict__ avd,
    float* __restrict__ Hout, float* __restrict__ Ss, float* __restrict__ Sd, int n)
{
  __shared__ float xs[16 * K];
  const int t  = threadIdx.x;
  const int tx = t & 63;
  const int ty = t >> 6;
  const long base = (long)blockIdx.x * 16;
  {
    const float4* X4 = (const float4*)X;
    float4* xs4 = (float4*)xs;
    long g0  = base * K / 4;
    long lim = (long)n * K / 4;
    for (int idx = t; idx < 16 * K / 4; idx += 256){
      long g = g0 + idx;
      xs4[idx] = (g < lim) ? X4[g] : make_float4(0.f, 0.f, 0.f, 0.f);
    }
  }
  __syncthreads();

  float acc[4][4];
  #pragma unroll
  for (int i = 0; i < 4; ++i){ acc[i][0]=0.f; acc[i][1]=0.f; acc[i][2]=0.f; acc[i][3]=0.f; }
  const int j0 = tx * 4;
  for (int k = 0; k < K; k += 4){
    float4 w0 = *(const float4*)(W + (k + 0) * 256 + j0);
    float4 w1 = *(const float4*)(W + (k + 1) * 256 + j0);
    float4 w2 = *(const float4*)(W + (k + 2) * 256 + j0);
    float4 w3 = *(const float4*)(W + (k + 3) * 256 + j0);
    #pragma unroll
    for (int i = 0; i < 4; ++i){
      float4 xv = *(const float4*)(xs + (ty * 4 + i) * K + k);   // wave-uniform -> LDS broadcast
      acc[i][0] += xv.x*w0.x + xv.y*w1.x + xv.z*w2.x + xv.w*w3.x;
      acc[i][1] += xv.x*w0.y + xv.y*w1.y + xv.z*w2.y + xv.w*w3.y;
      acc[i][2] += xv.x*w0.z + xv.y*w1.z + xv.z*w2.z + xv.w*w3.z;
      acc[i][3] += xv.x*w0.w + xv.y*w1.w + xv.z*w2.w + xv.w*w3.w;
    }
  }

  const int head = tx >> 4;       // (tx*4)>>6
  const int l16  = tx & 15;
  float4 a_s = *(const float4*)(avs + j0);
  float4 a_d = *(const float4*)(avd + j0);
  #pragma unroll
  for (int i = 0; i < 4; ++i){
    long node = base + ty * 4 + i;
    float ps = acc[i][0]*a_s.x + acc[i][1]*a_s.y + acc[i][2]*a_s.z + acc[i][3]*a_s.w;
    float pd = acc[i][0]*a_d.x + acc[i][1]*a_d.y + acc[i][2]*a_d.z + acc[i][3]*a_d.w;
    ps += __shfl_down(ps, 8); pd += __shfl_down(pd, 8);
    ps += __shfl_down(ps, 4); pd += __shfl_down(pd, 4);
    ps += __shfl_down(ps, 2); pd += __shfl_down(pd, 2);
    ps += __shfl_down(ps, 1); pd += __shfl_down(pd, 1);
    if (node < n){
      *(float4*)(Hout + node * 256 + j0) = make_float4(acc[i][0], acc[i][1], acc[i][2], acc[i][3]);
      if (l16 == 0){ Ss[node * 4 + head] = ps; Sd[node * 4 + head] = pd; }
    }
  }
}

// ---------------- mu/logvar GEMM (256 -> 32 each) + scores, fused ----------------
// Tile: 16 nodes x (32 mu | 32 lv) cols. thread t: tx=t&15 (cols), ty=t>>4 (node).
__global__ __launch_bounds__(256) void gemm_muv_kernel(
    const float* __restrict__ X, const float* __restrict__ Wmu, const float* __restrict__ Wlv,
    const float* __restrict__ avsm, const float* __restrict__ avdm,
    const float* __restrict__ avsl, const float* __restrict__ avdl,
    float* __restrict__ Hmu, float* __restrict__ Hlv,
    float* __restrict__ Ssm, float* __restrict__ Sdm,
    float* __restrict__ Ssl, float* __restrict__ Sdl, int n)
{
  __shared__ float xs[16 * 260];   // +4 pad per row: rows land on distinct banks
  const int t  = threadIdx.x;
  const int tx = t & 15;
  const int ty = t >> 4;
  const long base = (long)blockIdx.x * 16;
  {
    const float4* X4 = (const float4*)X;
    long g0  = base * 64;          // base*256/4
    long lim = (long)n * 64;
    for (int idx = t; idx < 1024; idx += 256){
      int row = idx >> 6, kq = idx & 63;
      long g = g0 + idx;
      float4 v = (g < lim) ? X4[g] : make_float4(0.f, 0.f, 0.f, 0.f);
      *(float4*)(xs + row * 260 + kq * 4) = v;
    }
  }
  __syncthreads();

  const bool isLv = (tx >= 8);
  const float* Wsel = isLv ? Wlv : Wmu;
  const int c0 = (tx & 7) * 4;
  float a0 = 0.f, a1 = 0.f, a2 = 0.f, a3 = 0.f;
  for (int k = 0; k < 256; k += 4){
    float4 xv = *(const float4*)(xs + ty * 260 + k);
    float4 w0 = *(const float4*)(Wsel + (k + 0) * 32 + c0);
    float4 w1 = *(const float4*)(Wsel + (k + 1) * 32 + c0);
    float4 w2 = *(const float4*)(Wsel + (k + 2) * 32 + c0);
    float4 w3 = *(const float4*)(Wsel + (k + 3) * 32 + c0);
    a0 += xv.x*w0.x + xv.y*w1.x + xv.z*w2.x + xv.w*w3.x;
    a1 += xv.x*w0.y + xv.y*w1.y + xv.z*w2.y + xv.w*w3.y;
    a2 += xv.x*w0.z + xv.y*w1.z + xv.z*w2.z + xv.w*w3.z;
    a3 += xv.x*w0.w + xv.y*w1.w + xv.z*w2.w + xv.w*w3.w;
  }
  long node = base + ty;
  const float* av_s = isLv ? avsl : avsm;
  const float* av_d = isLv ? avdl : avdm;
  float ps = a0*av_s[c0] + a1*av_s[c0+1] + a2*av_s[c0+2] + a3*av_s[c0+3];
  float pd = a0*av_d[c0] + a1*av_d[c0+1] + a2*av_d[c0+2] + a3*av_d[c0+3];
  ps += __shfl_down(ps, 4); pd += __shfl_down(pd, 4);
  ps += __shfl_down(ps, 2); pd += __shfl_down(pd, 2);
  ps += __shfl_down(ps, 1); pd += __shfl_down(pd, 1);
  if (node < n){
    float* Hsel = isLv ? Hlv : Hmu;
    *(float4*)(Hsel + node * 32 + c0) = make_float4(a0, a1, a2, a3);
    if ((tx & 7) == 0){
      if (isLv){ Ssl[node] = ps; Sdl[node] = pd; }
      else     { Ssm[node] = ps; Sdm[node] = pd; }
    }
  }
}

// ---------------- GAT aggregation (H=4, C=64): one block per node, one wave per head ----
__global__ __launch_bounds__(256) void gat_agg_kernel(
    const float* __restrict__ Hbuf, const float* __restrict__ Ss, const float* __restrict__ Sd,
    const int* __restrict__ rowptr, const int* __restrict__ colv,
    const float* __restrict__ bias, float* __restrict__ Out, int n, int do_relu)
{
  int node = blockIdx.x;
  if (node >= n) return;
  int head = threadIdx.x >> 6;
  int lane = threadIdx.x & 63;
  int col  = head * 64 + lane;
  float sd = Sd[node * 4 + head];
  float w  = expf(lky(Ss[node * 4 + head] + sd));   // self loop
  float sumw = w;
  float acc  = w * Hbuf[(long)node * 256 + col];
  int beg = rowptr[node], end = rowptr[node + 1];
  for (int jj = beg; jj < end; ++jj){
    int s = colv[jj];                                 // wave-uniform
    float wc = expf(lky(Ss[s * 4 + head] + sd));
    sumw += wc;
    acc  += wc * Hbuf[(long)s * 256 + col];
  }
  float o = acc / (sumw + 1e-16f) + bias[col];
  Out[(long)node * 256 + col] = do_relu ? fmaxf(o, 0.f) : o;
}

// ---------------- mu/lv aggregation + reparameterize ----------------
__global__ __launch_bounds__(256) void agg_muv_kernel(
    const float* __restrict__ Hmu, const float* __restrict__ Hlv,
    const float* __restrict__ Ssm, const float* __restrict__ Sdm,
    const float* __restrict__ Ssl, const float* __restrict__ Sdl,
    const int* __restrict__ rowptr, const int* __restrict__ colv,
    const float* __restrict__ bmu, const float* __restrict__ blv,
    const float* __restrict__ epsv,
    float* __restrict__ out_mu, float* __restrict__ out_lv, float* __restrict__ out_z, int n)
{
  int gid = blockIdx.x * blockDim.x + threadIdx.x;
  int node = gid >> 5, c = gid & 31;
  if (node >= n) return;
  float sdm = Sdm[node], sdl = Sdl[node];
  float wm = expf(lky(Ssm[node] + sdm));
  float wl = expf(lky(Ssl[node] + sdl));
  float summ = wm, suml = wl;
  float am = wm * Hmu[(long)node * 32 + c];
  float al = wl * Hlv[(long)node * 32 + c];
  int beg = rowptr[node], end = rowptr[node + 1];
  for (int jj = beg; jj < end; ++jj){
    int s = colv[jj];
    float w1 = expf(lky(Ssm[s] + sdm)); summ += w1; am += w1 * Hmu[(long)s * 32 + c];
    float w2 = expf(lky(Ssl[s] + sdl)); suml += w2; al += w2 * Hlv[(long)s * 32 + c];
  }
  float mu = am / (summ + 1e-16f) + bmu[c];
  float lv = al / (suml + 1e-16f) + blv[c];
  float z  = mu + epsv[(long)node * 32 + c] * expf(0.5f * lv);
  out_mu[(long)node * 32 + c] = mu;
  out_lv[(long)node * 32 + c] = lv;
  out_z [(long)node * 32 + c] = z;
}

// ---------------- decoder: zd = relu(z@Wfc+bfc); nf = zd@Wnode+bnode ----------------
__global__ __launch_bounds__(256) void decoder_kernel(
    const float* __restrict__ Z, const float* __restrict__ Wfc, const float* __restrict__ bfc,
    const float* __restrict__ Wnode, const float* __restrict__ bnode,
    float* __restrict__ ZD, float* __restrict__ NF, int n)
{
  __shared__ float zs[4 * 32];
  __shared__ float zds[4 * 64];
  int t = threadIdx.x;
  int i = t >> 6, j = t & 63;
  long node = (long)blockIdx.x * 4 + i;
  if (t < 128){
    long g = (long)blockIdx.x * 128 + t;
    zs[t] = (g < (long)n * 32) ? Z[g] : 0.f;
  }
  __syncthreads();
  float acc = bfc[j];
  #pragma unroll
  for (int k = 0; k < 32; ++k) acc += zs[i * 32 + k] * Wfc[k * 64 + j];
  acc = fmaxf(acc, 0.f);
  zds[i * 64 + j] = acc;
  if (node < n) ZD[node * 64 + j] = acc;
  __syncthreads();
  float nf = bnode[j];
  #pragma unroll
  for (int k = 0; k < 64; ++k) nf += zds[i * 64 + k] * Wnode[k * 64 + j];
  if (node < n) NF[node * 64 + j] = nf;
}

// ---------------- edge scores: one wave per edge ----------------
__global__ __launch_bounds__(256) void edge_score_kernel(
    const float* __restrict__ ZD, const int* __restrict__ src, const int* __restrict__ dst,
    const float* __restrict__ Wedge, const float* __restrict__ bedge,
    float* __restrict__ out_es, int E)
{
  int wv   = (blockIdx.x * blockDim.x + threadIdx.x) >> 6;
  int lane = threadIdx.x & 63;
  if (wv >= E) return;
  int s = src[wv], d = dst[wv];
  float p = ZD[(long)s * 64 + lane] * ZD[(long)d * 64 + lane] * Wedge[lane];
  p += __shfl_down(p, 32);
  p += __shfl_down(p, 16);
  p += __shfl_down(p, 8);
  p += __shfl_down(p, 4);
  p += __shfl_down(p, 2);
  p += __shfl_down(p, 1);
  if (lane == 0) out_es[wv] = p + bedge[0];
}

// ---------------- launch ----------------
extern "C" void kernel_launch(void* const* d_in, const int* in_sizes, int n_in,
                              void* d_out, int out_size, void* d_ws, size_t ws_size,
                              hipStream_t stream)
{
  const float* x     = (const float*)d_in[0];
  const int*   ei    = (const int*)  d_in[1];
  // d_in[2] = batch (unused)
  const float* epsv  = (const float*)d_in[3];
  const float* W1    = (const float*)d_in[4];
  const float* as1   = (const float*)d_in[5];
  const float* ad1   = (const float*)d_in[6];
  const float* b1    = (const float*)d_in[7];
  const float* W2    = (const float*)d_in[8];
  const float* as2   = (const float*)d_in[9];
  const float* ad2   = (const float*)d_in[10];
  const float* b2    = (const float*)d_in[11];
  const float* Wmu   = (const float*)d_in[12];
  const float* asmu  = (const float*)d_in[13];
  const float* admu  = (const float*)d_in[14];
  const float* bmu   = (const float*)d_in[15];
  const float* Wlv   = (const float*)d_in[16];
  const float* aslv  = (const float*)d_in[17];
  const float* adlv  = (const float*)d_in[18];
  const float* blv   = (const float*)d_in[19];
  const float* Wfc   = (const float*)d_in[20];
  const float* bfc   = (const float*)d_in[21];
  const float* Wnode = (const float*)d_in[22];
  const float* bnode = (const float*)d_in[23];
  const float* Wedge = (const float*)d_in[24];
  const float* bedge = (const float*)d_in[25];

  const int N = in_sizes[0] / 64;
  const int E = in_sizes[1] / 2;
  const int* srcA = ei;
  const int* dstA = ei + E;

  // workspace bump allocator (256B aligned)
  char* wsb = (char*)d_ws;
  size_t off = 0;
  auto alloc = [&](size_t bytes) -> void* {
    void* p = wsb + off;
    off += (bytes + 255) & ~(size_t)255;
    return p;
  };
  float* Abuf  = (float*)alloc((size_t)N * 256 * 4);  // h pre-aggregation
  float* Bbuf  = (float*)alloc((size_t)N * 256 * 4);  // activated layer output
  float* Hmu   = (float*)alloc((size_t)N * 32 * 4);
  float* Hlv   = (float*)alloc((size_t)N * 32 * 4);
  float* Ss    = (float*)alloc((size_t)N * 4 * 4);
  float* Sd    = (float*)alloc((size_t)N * 4 * 4);
  float* Ssm   = (float*)alloc((size_t)N * 4);
  float* Sdm   = (float*)alloc((size_t)N * 4);
  float* Ssl   = (float*)alloc((size_t)N * 4);
  float* Sdl   = (float*)alloc((size_t)N * 4);
  int*   deg   = (int*)  alloc((size_t)N * 4);
  int*   rowptr= (int*)  alloc((size_t)(N + 1) * 4);
  int*   cursor= (int*)  alloc((size_t)N * 4);
  int*   colv  = (int*)  alloc((size_t)E * 4);
  int*   bsum  = (int*)  alloc(1024);
  int*   boff  = (int*)  alloc(1024);
  float* ZD    = (float*)alloc((size_t)N * 64 * 4);
  (void)ws_size; (void)n_in; (void)out_size;

  float* out_mu = (float*)d_out;
  float* out_lv = out_mu + (size_t)N * 32;
  float* out_z  = out_lv + (size_t)N * 32;
  float* out_nf = out_z  + (size_t)N * 32;
  float* out_es = out_nf + (size_t)N * 64;

  const int nb = (N + 255) / 256;

  // CSR build
  zero_ints_kernel<<<(N + 255) / 256, 256, 0, stream>>>(deg, N);
  zero_ints_kernel<<<(N + 255) / 256, 256, 0, stream>>>(cursor, N);
  count_deg_kernel<<<(E + 255) / 256, 256, 0, stream>>>(dstA, deg, E);
  scan_chunk_kernel<<<nb, 256, 0, stream>>>(deg, rowptr, bsum, N);
  scan_bsum_kernel<<<1, 256, 0, stream>>>(bsum, boff, nb);
  scan_add_kernel<<<nb, 256, 0, stream>>>(rowptr, boff, N);
  fill_csr_kernel<<<(E + 255) / 256, 256, 0, stream>>>(srcA, dstA, rowptr, cursor, colv, E);

  const int gb = (N + 15) / 16;
  // layer 1
  gemm_scores_kernel<64><<<gb, 256, 0, stream>>>(x, W1, as1, ad1, Abuf, Ss, Sd, N);
  gat_agg_kernel<<<N, 256, 0, stream>>>(Abuf, Ss, Sd, rowptr, colv, b1, Bbuf, N, 1);
  // layer 2
  gemm_scores_kernel<256><<<gb, 256, 0, stream>>>(Bbuf, W2, as2, ad2, Abuf, Ss, Sd, N);
  gat_agg_kernel<<<N, 256, 0, stream>>>(Abuf, Ss, Sd, rowptr, colv, b2, Bbuf, N, 1);
  // mu / logvar
  gemm_muv_kernel<<<gb, 256, 0, stream>>>(Bbuf, Wmu, Wlv, asmu, admu, aslv, adlv,
                                          Hmu, Hlv, Ssm, Sdm, Ssl, Sdl, N);
  agg_muv_kernel<<<((size_t)N * 32 + 255) / 256, 256, 0, stream>>>(
      Hmu, Hlv, Ssm, Sdm, Ssl, Sdl, rowptr, colv, bmu, blv, epsv,
      out_mu, out_lv, out_z, N);
  // decoder
  decoder_kernel<<<(N + 3) / 4, 256, 0, stream>>>(out_z, Wfc, bfc, Wnode, bnode, ZD, out_nf, N);
  edge_score_kernel<<<((size_t)E * 64 + 255) / 256, 256, 0, stream>>>(
      ZD, srcA, dstA, Wedge, bedge, out_es, E);
}

// Round 2
// 594.302 us; speedup vs baseline: 1.4072x; 1.4072x over previous
//
#include <hip/hip_runtime.h>
#include <math.h>

#define NEG_SLOPE 0.2f

__device__ __forceinline__ float lky(float x){ return x > 0.f ? x : NEG_SLOPE * x; }

// bf16 <-> f32 helpers (RNE), storage = ushort to avoid struct-init issues in LDS
__device__ __forceinline__ unsigned short f2bf(float f){
  unsigned int u = __float_as_uint(f);
  unsigned int r = (u + 0x7fffu + ((u >> 16) & 1u)) >> 16;
  return (unsigned short)r;
}
__device__ __forceinline__ float bf2f(unsigned short s){
  return __uint_as_float(((unsigned int)s) << 16);
}

typedef __bf16 bf16x8 __attribute__((ext_vector_type(8)));
typedef float  f32x4  __attribute__((ext_vector_type(4)));

// ---------------- CSR build ----------------
__global__ void zero_ints_kernel(int* __restrict__ p, int n){
  int i = blockIdx.x * blockDim.x + threadIdx.x;
  if (i < n) p[i] = 0;
}

__global__ void count_deg_kernel(const int* __restrict__ dst, int* __restrict__ deg, int E){
  int e = blockIdx.x * blockDim.x + threadIdx.x;
  if (e < E) atomicAdd(&deg[dst[e]], 1);
}

__global__ void scan_chunk_kernel(const int* __restrict__ deg, int* __restrict__ rowptr,
                                  int* __restrict__ bsum, int n){
  __shared__ int s[256];
  int t = threadIdx.x;
  int i = blockIdx.x * 256 + t;
  int v = (i < n) ? deg[i] : 0;
  s[t] = v; __syncthreads();
  for (int off = 1; off < 256; off <<= 1){
    int x = (t >= off) ? s[t - off] : 0;
    __syncthreads();
    s[t] += x;
    __syncthreads();
  }
  if (i < n) rowptr[i + 1] = s[t];
  if (t == 255) bsum[blockIdx.x] = s[255];
}

__global__ void scan_bsum_kernel(const int* __restrict__ bsum, int* __restrict__ boff, int nb){
  __shared__ int s[256];
  int t = threadIdx.x;
  int v = (t < nb) ? bsum[t] : 0;
  s[t] = v; __syncthreads();
  for (int off = 1; off < 256; off <<= 1){
    int x = (t >= off) ? s[t - off] : 0;
    __syncthreads();
    s[t] += x;
    __syncthreads();
  }
  boff[t] = s[t] - v;
}

__global__ void scan_add_kernel(int* __restrict__ rowptr, const int* __restrict__ boff, int n){
  int i = blockIdx.x * 256 + threadIdx.x;
  if (i < n) rowptr[i + 1] += boff[blockIdx.x];
  if (i == 0) rowptr[0] = 0;
}

__global__ void fill_csr_kernel(const int* __restrict__ src, const int* __restrict__ dst,
                                const int* __restrict__ rowptr, int* __restrict__ cursor,
                                int* __restrict__ colv, int E){
  int e = blockIdx.x * blockDim.x + threadIdx.x;
  if (e >= E) return;
  int d = dst[e];
  int pos = atomicAdd(&cursor[d], 1);
  colv[rowptr[d] + pos] = src[e];
}

// ---------------- weight pack: fp32 [K][M] -> bf16 B-fragment layout ----------------
// out[((gct*(K/32)+s)*64 + l)*8 + j] = W[k][col], col = gct*16+(l&15), k = s*32+(l>>4)*8+j
// If Wb != null: two matrices each of width Mhalf, concatenated along cols.
__global__ void pack_w_kernel(const float* __restrict__ Wa, const float* __restrict__ Wb,
                              int K, int M, int Mhalf, unsigned short* __restrict__ out){
  int idx = blockIdx.x * 256 + threadIdx.x;
  if (idx >= K * M) return;
  int j = idx & 7;
  int l = (idx >> 3) & 63;
  int rest = idx >> 9;
  int KS = K >> 5;
  int s = rest % KS, gct = rest / KS;
  int col = gct * 16 + (l & 15);
  int k   = s * 32 + ((l >> 4) << 3) + j;
  float v;
  if (Wb == nullptr) v = Wa[(long)k * M + col];
  else v = (col < Mhalf) ? Wa[(long)k * Mhalf + col] : Wb[(long)k * Mhalf + (col - Mhalf)];
  out[idx] = f2bf(v);
}

// ---------------- MFMA GEMM + fused attention scores ----------------
// CW=4: block = 32 rows x 256 cols, wave w -> cols [w*64,+64) (head w).
// CW=1: block = 128 rows x 64 cols, wave w -> rows [w*32,+32); cols 0-31 mu, 32-63 lv.
template<int K, int CW, bool XF32>
__global__ __launch_bounds__(256) void gemm_mfma_kernel(
    const float* __restrict__ Xf, const unsigned short* __restrict__ Xb,
    const unsigned short* __restrict__ Wpk,
    const float* __restrict__ a_s, const float* __restrict__ a_d,
    const float* __restrict__ a_s2, const float* __restrict__ a_d2,
    unsigned short* __restrict__ Hout,
    float* __restrict__ Ss, float* __restrict__ Sd,
    float* __restrict__ Ss2, float* __restrict__ Sd2, int n)
{
  constexpr int BR  = (CW == 4) ? 32 : 128;
  constexpr int M   = 64 * CW;
  constexpr int KS  = K / 32;
  constexpr int LDA = K + 8;
  constexpr int SH  = (BR * LDA > BR * M) ? BR * LDA : BR * M;
  __shared__ unsigned short As[SH];

  const int t = threadIdx.x;
  const int w = t >> 6, l = t & 63;
  const int quad = l >> 4, l15 = l & 15;
  const long base = (long)blockIdx.x * BR;
  const int roww = (CW == 4) ? 0 : w;
  const int colw = (CW == 4) ? w : 0;

  // ---- stage A-tile into LDS (bf16), converting from fp32 if needed ----
  if (XF32){
    const float4* Xg = (const float4*)Xf;
    long g0 = base * (K / 4);
    long lim = (long)n * (K / 4);
    for (int c = t; c < BR * K / 4; c += 256){
      int row = c / (K / 4), kc = c % (K / 4);
      float4 v = (g0 + c < lim) ? Xg[g0 + c] : make_float4(0.f, 0.f, 0.f, 0.f);
      unsigned short* p = As + row * LDA + kc * 4;
      p[0] = f2bf(v.x); p[1] = f2bf(v.y); p[2] = f2bf(v.z); p[3] = f2bf(v.w);
    }
  } else {
    const uint4* Xg = (const uint4*)Xb;
    long g0 = base * (K / 8);
    long lim = (long)n * (K / 8);
    for (int c = t; c < BR * K / 8; c += 256){
      int row = c / (K / 8), kc = c % (K / 8);
      uint4 v = make_uint4(0u, 0u, 0u, 0u);
      if (g0 + c < lim) v = Xg[g0 + c];
      *(uint4*)(As + row * LDA + kc * 8) = v;
    }
  }
  __syncthreads();

  // ---- K loop ----
  f32x4 acc[2][4] = {};
  for (int s = 0; s < KS; ++s){
    bf16x8 af0 = *(const bf16x8*)(As + (roww * 32 + 0  + l15) * LDA + s * 32 + quad * 8);
    bf16x8 af1 = *(const bf16x8*)(As + (roww * 32 + 16 + l15) * LDA + s * 32 + quad * 8);
    #pragma unroll
    for (int ct = 0; ct < 4; ++ct){
      int gct = colw * 4 + ct;
      bf16x8 bf = *(const bf16x8*)(Wpk + (((long)gct * KS + s) * 64 + l) * 8);
      acc[0][ct] = __builtin_amdgcn_mfma_f32_16x16x32_bf16(af0, bf, acc[0][ct], 0, 0, 0);
      acc[1][ct] = __builtin_amdgcn_mfma_f32_16x16x32_bf16(af1, bf, acc[1][ct], 0, 0, 0);
    }
  }

  // ---- fused attention scores ----
  if (CW == 4){
    const int head = w;
    float asv[4], adv[4];
    #pragma unroll
    for (int ct = 0; ct < 4; ++ct){
      int col = head * 64 + ct * 16 + l15;
      asv[ct] = a_s[col]; adv[ct] = a_d[col];
    }
    #pragma unroll
    for (int rt = 0; rt < 2; ++rt){
      #pragma unroll
      for (int r = 0; r < 4; ++r){
        float ps = 0.f, pd = 0.f;
        #pragma unroll
        for (int ct = 0; ct < 4; ++ct){
          float v = acc[rt][ct][r];
          ps += v * asv[ct]; pd += v * adv[ct];
        }
        ps += __shfl_xor(ps, 8); pd += __shfl_xor(pd, 8);
        ps += __shfl_xor(ps, 4); pd += __shfl_xor(pd, 4);
        ps += __shfl_xor(ps, 2); pd += __shfl_xor(pd, 2);
        ps += __shfl_xor(ps, 1); pd += __shfl_xor(pd, 1);
        long node = base + rt * 16 + quad * 4 + r;
        if (l15 == 0 && node < n){ Ss[node * 4 + head] = ps; Sd[node * 4 + head] = pd; }
      }
    }
  } else {
    float asm_[2], adm_[2], asl_[2], adl_[2];
    #pragma unroll
    for (int ct = 0; ct < 2; ++ct){
      int col = ct * 16 + l15;
      asm_[ct] = a_s[col];  adm_[ct] = a_d[col];
      asl_[ct] = a_s2[col]; adl_[ct] = a_d2[col];
    }
    #pragma unroll
    for (int rt = 0; rt < 2; ++rt){
      #pragma unroll
      for (int r = 0; r < 4; ++r){
        float psm = 0.f, pdm = 0.f, psl = 0.f, pdl = 0.f;
        #pragma unroll
        for (int ct = 0; ct < 2; ++ct){
          float vm = acc[rt][ct][r];
          float vl = acc[rt][ct + 2][r];
          psm += vm * asm_[ct]; pdm += vm * adm_[ct];
          psl += vl * asl_[ct]; pdl += vl * adl_[ct];
        }
        #pragma unroll
        for (int d = 8; d >= 1; d >>= 1){
          psm += __shfl_xor(psm, d); pdm += __shfl_xor(pdm, d);
          psl += __shfl_xor(psl, d); pdl += __shfl_xor(pdl, d);
        }
        long node = base + w * 32 + rt * 16 + quad * 4 + r;
        if (l15 == 0 && node < n){
          Ss[node]  = psm; Sd[node]  = pdm;
          Ss2[node] = psl; Sd2[node] = pdl;
        }
      }
    }
  }

  // ---- write H (bf16) via LDS for coalescing ----
  __syncthreads();
  #pragma unroll
  for (int rt = 0; rt < 2; ++rt){
    #pragma unroll
    for (int ct = 0; ct < 4; ++ct){
      #pragma unroll
      for (int r = 0; r < 4; ++r){
        int row = roww * 32 + rt * 16 + quad * 4 + r;
        int col = colw * 64 + ct * 16 + l15;
        As[row * M + col] = f2bf(acc[rt][ct][r]);
      }
    }
  }
  __syncthreads();
  {
    uint4* Hg = (uint4*)Hout;
    for (int c = t; c < BR * M / 8; c += 256){
      int row = c / (M / 8);
      if (base + row < n) Hg[base * (M / 8) + c] = *(const uint4*)(As + c * 8);
    }
  }
}

// ---------------- GAT aggregation (H=4, C=64), bf16 in/out, relu ----------------
__global__ __launch_bounds__(256) void gat_agg_kernel(
    const unsigned short* __restrict__ Hbuf,
    const float* __restrict__ Ss, const float* __restrict__ Sd,
    const int* __restrict__ rowptr, const int* __restrict__ colv,
    const float* __restrict__ bias, unsigned short* __restrict__ Out, int n)
{
  int node = blockIdx.x;
  if (node >= n) return;
  int head = threadIdx.x >> 6;
  int lane = threadIdx.x & 63;
  int col  = head * 64 + lane;
  float sd = Sd[node * 4 + head];
  float w  = expf(lky(Ss[node * 4 + head] + sd));   // self loop
  float sumw = w;
  float acc  = w * bf2f(Hbuf[(long)node * 256 + col]);
  int beg = rowptr[node], end = rowptr[node + 1];
  for (int jj = beg; jj < end; ++jj){
    int s = colv[jj];
    float wc = expf(lky(Ss[s * 4 + head] + sd));
    sumw += wc;
    acc  += wc * bf2f(Hbuf[(long)s * 256 + col]);
  }
  float o = acc / (sumw + 1e-16f) + bias[col];
  Out[(long)node * 256 + col] = f2bf(fmaxf(o, 0.f));
}

// ---------------- mu/lv aggregation + reparameterize (bf16 in, fp32 out) ----------------
__global__ __launch_bounds__(256) void agg_muv_kernel(
    const unsigned short* __restrict__ Hmuv,
    const float* __restrict__ Ssm, const float* __restrict__ Sdm,
    const float* __restrict__ Ssl, const float* __restrict__ Sdl,
    const int* __restrict__ rowptr, const int* __restrict__ colv,
    const float* __restrict__ bmu, const float* __restrict__ blv,
    const float* __restrict__ epsv,
    float* __restrict__ out_mu, float* __restrict__ out_lv, float* __restrict__ out_z, int n)
{
  int gid = blockIdx.x * blockDim.x + threadIdx.x;
  int node = gid >> 5, c = gid & 31;
  if (node >= n) return;
  float sdm = Sdm[node], sdl = Sdl[node];
  float wm = expf(lky(Ssm[node] + sdm));
  float wl = expf(lky(Ssl[node] + sdl));
  float summ = wm, suml = wl;
  float am = wm * bf2f(Hmuv[(long)node * 64 + c]);
  float al = wl * bf2f(Hmuv[(long)node * 64 + 32 + c]);
  int beg = rowptr[node], end = rowptr[node + 1];
  for (int jj = beg; jj < end; ++jj){
    int s = colv[jj];
    float w1 = expf(lky(Ssm[s] + sdm)); summ += w1; am += w1 * bf2f(Hmuv[(long)s * 64 + c]);
    float w2 = expf(lky(Ssl[s] + sdl)); suml += w2; al += w2 * bf2f(Hmuv[(long)s * 64 + 32 + c]);
  }
  float mu = am / (summ + 1e-16f) + bmu[c];
  float lv = al / (suml + 1e-16f) + blv[c];
  float z  = mu + epsv[(long)node * 32 + c] * expf(0.5f * lv);
  out_mu[(long)node * 32 + c] = mu;
  out_lv[(long)node * 32 + c] = lv;
  out_z [(long)node * 32 + c] = z;
}

// ---------------- decoder: zd = relu(z@Wfc+bfc); nf = zd@Wnode+bnode ----------------
__global__ __launch_bounds__(256) void decoder_kernel(
    const float* __restrict__ Z, const float* __restrict__ Wfc, const float* __restrict__ bfc,
    const float* __restrict__ Wnode, const float* __restrict__ bnode,
    float* __restrict__ ZD, float* __restrict__ NF, int n)
{
  __shared__ float zs[4 * 32];
  __shared__ float zds[4 * 64];
  int t = threadIdx.x;
  int i = t >> 6, j = t & 63;
  long node = (long)blockIdx.x * 4 + i;
  if (t < 128){
    long g = (long)blockIdx.x * 128 + t;
    zs[t] = (g < (long)n * 32) ? Z[g] : 0.f;
  }
  __syncthreads();
  float acc = bfc[j];
  #pragma unroll
  for (int k = 0; k < 32; ++k) acc += zs[i * 32 + k] * Wfc[k * 64 + j];
  acc = fmaxf(acc, 0.f);
  zds[i * 64 + j] = acc;
  if (node < n) ZD[node * 64 + j] = acc;
  __syncthreads();
  float nf = bnode[j];
  #pragma unroll
  for (int k = 0; k < 64; ++k) nf += zds[i * 64 + k] * Wnode[k * 64 + j];
  if (node < n) NF[node * 64 + j] = nf;
}

// ---------------- edge scores: one wave per edge ----------------
__global__ __launch_bounds__(256) void edge_score_kernel(
    const float* __restrict__ ZD, const int* __restrict__ src, const int* __restrict__ dst,
    const float* __restrict__ Wedge, const float* __restrict__ bedge,
    float* __restrict__ out_es, int E)
{
  int wv   = (blockIdx.x * blockDim.x + threadIdx.x) >> 6;
  int lane = threadIdx.x & 63;
  if (wv >= E) return;
  int s = src[wv], d = dst[wv];
  float p = ZD[(long)s * 64 + lane] * ZD[(long)d * 64 + lane] * Wedge[lane];
  p += __shfl_down(p, 32);
  p += __shfl_down(p, 16);
  p += __shfl_down(p, 8);
  p += __shfl_down(p, 4);
  p += __shfl_down(p, 2);
  p += __shfl_down(p, 1);
  if (lane == 0) out_es[wv] = p + bedge[0];
}

// ---------------- launch ----------------
extern "C" void kernel_launch(void* const* d_in, const int* in_sizes, int n_in,
                              void* d_out, int out_size, void* d_ws, size_t ws_size,
                              hipStream_t stream)
{
  const float* x     = (const float*)d_in[0];
  const int*   ei    = (const int*)  d_in[1];
  const float* epsv  = (const float*)d_in[3];
  const float* W1    = (const float*)d_in[4];
  const float* as1   = (const float*)d_in[5];
  const float* ad1   = (const float*)d_in[6];
  const float* b1    = (const float*)d_in[7];
  const float* W2    = (const float*)d_in[8];
  const float* as2   = (const float*)d_in[9];
  const float* ad2   = (const float*)d_in[10];
  const float* b2    = (const float*)d_in[11];
  const float* Wmu   = (const float*)d_in[12];
  const float* asmu  = (const float*)d_in[13];
  const float* admu  = (const float*)d_in[14];
  const float* bmu   = (const float*)d_in[15];
  const float* Wlv   = (const float*)d_in[16];
  const float* aslv  = (const float*)d_in[17];
  const float* adlv  = (const float*)d_in[18];
  const float* blv   = (const float*)d_in[19];
  const float* Wfc   = (const float*)d_in[20];
  const float* bfc   = (const float*)d_in[21];
  const float* Wnode = (const float*)d_in[22];
  const float* bnode = (const float*)d_in[23];
  const float* Wedge = (const float*)d_in[24];
  const float* bedge = (const float*)d_in[25];

  const int N = in_sizes[0] / 64;
  const int E = in_sizes[1] / 2;
  const int* srcA = ei;
  const int* dstA = ei + E;

  char* wsb = (char*)d_ws;
  size_t off = 0;
  auto alloc = [&](size_t bytes) -> void* {
    void* p = wsb + off;
    off += (bytes + 255) & ~(size_t)255;
    return p;
  };
  unsigned short* H1    = (unsigned short*)alloc((size_t)N * 256 * 2);  // pre-agg h (bf16)
  unsigned short* B1    = (unsigned short*)alloc((size_t)N * 256 * 2);  // post-agg relu (bf16)
  unsigned short* Hmuv  = (unsigned short*)alloc((size_t)N * 64 * 2);
  unsigned short* W1pk  = (unsigned short*)alloc((size_t)64 * 256 * 2);
  unsigned short* W2pk  = (unsigned short*)alloc((size_t)256 * 256 * 2);
  unsigned short* Wmvpk = (unsigned short*)alloc((size_t)256 * 64 * 2);
  float* Ss    = (float*)alloc((size_t)N * 4 * 4);
  float* Sd    = (float*)alloc((size_t)N * 4 * 4);
  float* Ssm   = (float*)alloc((size_t)N * 4);
  float* Sdm   = (float*)alloc((size_t)N * 4);
  float* Ssl   = (float*)alloc((size_t)N * 4);
  float* Sdl   = (float*)alloc((size_t)N * 4);
  int*   deg   = (int*)  alloc((size_t)N * 2 * 4);   // deg + cursor adjacent
  int*   cursor= deg + N;
  int*   rowptr= (int*)  alloc((size_t)(N + 1) * 4);
  int*   colv  = (int*)  alloc((size_t)E * 4);
  int*   bsum  = (int*)  alloc(1024);
  int*   boff  = (int*)  alloc(1024);
  float* ZD    = (float*)alloc((size_t)N * 64 * 4);
  (void)ws_size; (void)n_in; (void)out_size;

  float* out_mu = (float*)d_out;
  float* out_lv = out_mu + (size_t)N * 32;
  float* out_z  = out_lv + (size_t)N * 32;
  float* out_nf = out_z  + (size_t)N * 32;
  float* out_es = out_nf + (size_t)N * 64;

  const int nb = (N + 255) / 256;

  // CSR build
  zero_ints_kernel<<<(2 * N + 255) / 256, 256, 0, stream>>>(deg, 2 * N);
  count_deg_kernel<<<(E + 255) / 256, 256, 0, stream>>>(dstA, deg, E);
  scan_chunk_kernel<<<nb, 256, 0, stream>>>(deg, rowptr, bsum, N);
  scan_bsum_kernel<<<1, 256, 0, stream>>>(bsum, boff, nb);
  scan_add_kernel<<<nb, 256, 0, stream>>>(rowptr, boff, N);
  fill_csr_kernel<<<(E + 255) / 256, 256, 0, stream>>>(srcA, dstA, rowptr, cursor, colv, E);

  // weight packing (bf16, MFMA B-fragment layout)
  pack_w_kernel<<<(64 * 256 + 255) / 256, 256, 0, stream>>>(W1, nullptr, 64, 256, 256, W1pk);
  pack_w_kernel<<<(256 * 256 + 255) / 256, 256, 0, stream>>>(W2, nullptr, 256, 256, 256, W2pk);
  pack_w_kernel<<<(256 * 64 + 255) / 256, 256, 0, stream>>>(Wmu, Wlv, 256, 64, 32, Wmvpk);

  // layer 1 (fp32 x converted during staging)
  gemm_mfma_kernel<64, 4, true><<<(N + 31) / 32, 256, 0, stream>>>(
      x, nullptr, W1pk, as1, ad1, nullptr, nullptr, H1, Ss, Sd, nullptr, nullptr, N);
  gat_agg_kernel<<<N, 256, 0, stream>>>(H1, Ss, Sd, rowptr, colv, b1, B1, N);
  // layer 2
  gemm_mfma_kernel<256, 4, false><<<(N + 31) / 32, 256, 0, stream>>>(
      nullptr, B1, W2pk, as2, ad2, nullptr, nullptr, H1, Ss, Sd, nullptr, nullptr, N);
  gat_agg_kernel<<<N, 256, 0, stream>>>(H1, Ss, Sd, rowptr, colv, b2, B1, N);
  // mu / logvar (fused, M=64)
  gemm_mfma_kernel<256, 1, false><<<(N + 127) / 128, 256, 0, stream>>>(
      nullptr, B1, Wmvpk, asmu, admu, aslv, adlv, Hmuv, Ssm, Sdm, Ssl, Sdl, N);
  agg_muv_kernel<<<((size_t)N * 32 + 255) / 256, 256, 0, stream>>>(
      Hmuv, Ssm, Sdm, Ssl, Sdl, rowptr, colv, bmu, blv, epsv,
      out_mu, out_lv, out_z, N);
  // decoder
  decoder_kernel<<<(N + 3) / 4, 256, 0, stream>>>(out_z, Wfc, bfc, Wnode, bnode, ZD, out_nf, N);
  edge_score_kernel<<<((size_t)E * 64 + 255) / 256, 256, 0, stream>>>(
      ZD, srcA, dstA, Wedge, bedge, out_es, E);
}

// Round 3
// 464.886 us; speedup vs baseline: 1.7989x; 1.2784x over previous
//
#include <hip/hip_runtime.h>
#include <math.h>

#define NEG_SLOPE 0.2f

__device__ __forceinline__ float lky(float x){ return x > 0.f ? x : NEG_SLOPE * x; }

__device__ __forceinline__ unsigned short f2bf(float f){
  unsigned int u = __float_as_uint(f);
  unsigned int r = (u + 0x7fffu + ((u >> 16) & 1u)) >> 16;
  return (unsigned short)r;
}
__device__ __forceinline__ float bf2f(unsigned short s){
  return __uint_as_float(((unsigned int)s) << 16);
}
__device__ __forceinline__ void unp8(uint4 v, float* f){
  f[0]=__uint_as_float(v.x<<16); f[1]=__uint_as_float(v.x&0xffff0000u);
  f[2]=__uint_as_float(v.y<<16); f[3]=__uint_as_float(v.y&0xffff0000u);
  f[4]=__uint_as_float(v.z<<16); f[5]=__uint_as_float(v.z&0xffff0000u);
  f[6]=__uint_as_float(v.w<<16); f[7]=__uint_as_float(v.w&0xffff0000u);
}
__device__ __forceinline__ uint4 pack8(const float* o){
  uint4 v;
  v.x = (unsigned)f2bf(o[0]) | ((unsigned)f2bf(o[1])<<16);
  v.y = (unsigned)f2bf(o[2]) | ((unsigned)f2bf(o[3])<<16);
  v.z = (unsigned)f2bf(o[4]) | ((unsigned)f2bf(o[5])<<16);
  v.w = (unsigned)f2bf(o[6]) | ((unsigned)f2bf(o[7])<<16);
  return v;
}

typedef __bf16 bf16x8 __attribute__((ext_vector_type(8)));
typedef float  f32x4  __attribute__((ext_vector_type(4)));

// ---------------- CSR build ----------------
__global__ void zero_ints_kernel(int* __restrict__ p, int n){
  int i = blockIdx.x * blockDim.x + threadIdx.x;
  if (i < n) p[i] = 0;
}
__global__ void count_deg_kernel(const int* __restrict__ dst, int* __restrict__ deg, int E){
  int e = blockIdx.x * blockDim.x + threadIdx.x;
  if (e < E) atomicAdd(&deg[dst[e]], 1);
}
__global__ void scan_chunk_kernel(const int* __restrict__ deg, int* __restrict__ rowptr,
                                  int* __restrict__ bsum, int n){
  __shared__ int s[256];
  int t = threadIdx.x;
  int i = blockIdx.x * 256 + t;
  int v = (i < n) ? deg[i] : 0;
  s[t] = v; __syncthreads();
  for (int off = 1; off < 256; off <<= 1){
    int x = (t >= off) ? s[t - off] : 0;
    __syncthreads();
    s[t] += x;
    __syncthreads();
  }
  if (i < n) rowptr[i + 1] = s[t];
  if (t == 255) bsum[blockIdx.x] = s[255];
}
__global__ void scan_bsum_kernel(const int* __restrict__ bsum, int* __restrict__ boff, int nb){
  __shared__ int s[256];
  int t = threadIdx.x;
  int v = (t < nb) ? bsum[t] : 0;
  s[t] = v; __syncthreads();
  for (int off = 1; off < 256; off <<= 1){
    int x = (t >= off) ? s[t - off] : 0;
    __syncthreads();
    s[t] += x;
    __syncthreads();
  }
  boff[t] = s[t] - v;
}
__global__ void scan_add_kernel(int* __restrict__ rowptr, const int* __restrict__ boff, int n){
  int i = blockIdx.x * 256 + threadIdx.x;
  if (i < n) rowptr[i + 1] += boff[blockIdx.x];
  if (i == 0) rowptr[0] = 0;
}
__global__ void fill_csr_kernel(const int* __restrict__ src, const int* __restrict__ dst,
                                const int* __restrict__ rowptr, int* __restrict__ cursor,
                                int* __restrict__ colv, int* __restrict__ dstv, int E){
  int e = blockIdx.x * blockDim.x + threadIdx.x;
  if (e >= E) return;
  int d = dst[e];
  int pos = atomicAdd(&cursor[d], 1);
  colv[rowptr[d] + pos] = src[e];
  dstv[rowptr[d] + pos] = d;
}

// ---------------- weight pack: fp32 [K][M] -> bf16 B-fragment layout ----------------
__global__ void pack_w_kernel(const float* __restrict__ Wa, const float* __restrict__ Wb,
                              int K, int M, int Mhalf, unsigned short* __restrict__ out){
  int idx = blockIdx.x * 256 + threadIdx.x;
  if (idx >= K * M) return;
  int j = idx & 7;
  int l = (idx >> 3) & 63;
  int rest = idx >> 9;
  int KS = K >> 5;
  int s = rest % KS, gct = rest / KS;
  int col = gct * 16 + (l & 15);
  int k   = s * 32 + ((l >> 4) << 3) + j;
  float v;
  if (Wb == nullptr) v = Wa[(long)k * M + col];
  else v = (col < Mhalf) ? Wa[(long)k * Mhalf + col] : Wb[(long)k * Mhalf + (col - Mhalf)];
  out[idx] = f2bf(v);
}

// ---------------- x fp32 -> bf16 ----------------
__global__ void cvt_x_kernel(const float* __restrict__ x, unsigned short* __restrict__ xb, long n4){
  long i = (long)blockIdx.x * 256 + threadIdx.x;
  if (i >= n4) return;
  float4 v = ((const float4*)x)[i];
  uint2 o;
  o.x = (unsigned)f2bf(v.x) | ((unsigned)f2bf(v.y) << 16);
  o.y = (unsigned)f2bf(v.z) | ((unsigned)f2bf(v.w) << 16);
  ((uint2*)xb)[i] = o;
}

// ---------------- P1 = W1 @ a (64 x 4 x {src,dst}) ----------------
__global__ void make_p1_kernel(const float* __restrict__ W1, const float* __restrict__ as1,
                               const float* __restrict__ ad1, float* __restrict__ P1){
  int idx = blockIdx.x * 256 + threadIdx.x;
  if (idx >= 512) return;
  int sd = idx & 1, h = (idx >> 1) & 3, k = idx >> 3;
  const float* av = sd ? ad1 : as1;
  float acc = 0.f;
  for (int c = 0; c < 64; ++c) acc += W1[k * 256 + h * 64 + c] * av[h * 64 + c];
  P1[idx] = acc;
}

// ---------------- layer-1 scores: S1 = xb @ P1 ----------------
__global__ __launch_bounds__(256) void score1_kernel(
    const unsigned short* __restrict__ xb, const float* __restrict__ P1,
    float* __restrict__ S1s, float* __restrict__ S1d, int n)
{
  __shared__ float P[512];
  int t = threadIdx.x;
  P[t] = P1[t]; P[t + 256] = P1[t + 256];
  __syncthreads();
  int nid = blockIdx.x * 256 + t;
  if (nid >= n) return;
  float acc[8] = {0,0,0,0,0,0,0,0};
  const uint4* xr = (const uint4*)xb + (long)nid * 8;
  for (int kc = 0; kc < 8; ++kc){
    uint4 v = xr[kc];
    float xf[8]; unp8(v, xf);
    #pragma unroll
    for (int j = 0; j < 8; ++j){
      int k = kc * 8 + j;
      #pragma unroll
      for (int o = 0; o < 8; ++o) acc[o] += xf[j] * P[k * 8 + o];
    }
  }
  *(float4*)(S1s + nid * 4) = make_float4(acc[0], acc[2], acc[4], acc[6]);
  *(float4*)(S1d + nid * 4) = make_float4(acc[1], acc[3], acc[5], acc[7]);
}

// ---------------- edge softmax weights (precomputed) ----------------
__global__ void edgew4_kernel(const int* __restrict__ colv, const int* __restrict__ dstv,
                              const float* __restrict__ Ss, const float* __restrict__ Sd,
                              float* __restrict__ w4, int E){
  int e = blockIdx.x * 256 + threadIdx.x;
  if (e >= E) return;
  int s = colv[e], d = dstv[e];
  float4 a = *(const float4*)(Ss + (long)s * 4);
  float4 b = *(const float4*)(Sd + (long)d * 4);
  *(float4*)(w4 + (long)e * 4) = make_float4(
      expf(lky(a.x + b.x)), expf(lky(a.y + b.y)),
      expf(lky(a.z + b.z)), expf(lky(a.w + b.w)));
}
__global__ void edgew2_kernel(const int* __restrict__ colv, const int* __restrict__ dstv,
                              const float* __restrict__ Ssm, const float* __restrict__ Sdm,
                              const float* __restrict__ Ssl, const float* __restrict__ Sdl,
                              float* __restrict__ w2, int E){
  int e = blockIdx.x * 256 + threadIdx.x;
  if (e >= E) return;
  int s = colv[e], d = dstv[e];
  float wm = expf(lky(Ssm[s] + Sdm[d]));
  float wl = expf(lky(Ssl[s] + Sdl[d]));
  *(float2*)(w2 + (long)e * 2) = make_float2(wm, wl);
}

// ---------------- layer-1: aggregate x per head (4 x 64 bf16 out) ----------------
// one wave per node: slot = l>>3 (8 edges in flight), cl = l&7 (8 cols each)
__global__ __launch_bounds__(256) void aggx_kernel(
    const unsigned short* __restrict__ xb, const float* __restrict__ w4,
    const float* __restrict__ Ss, const float* __restrict__ Sd,
    const int* __restrict__ rowptr, const int* __restrict__ colv,
    unsigned short* __restrict__ Xagg, int n)
{
  int wv = threadIdx.x >> 6, l = threadIdx.x & 63;
  int nid = blockIdx.x * 4 + wv;
  if (nid >= n) return;
  int slot = l >> 3, cl = l & 7;
  float acc[4][8] = {};
  float sumw[4] = {0.f, 0.f, 0.f, 0.f};
  int beg = rowptr[nid], end = rowptr[nid + 1];
  for (int jj = beg + slot; jj < end; jj += 8){
    int s = colv[jj];
    float4 wt = *(const float4*)(w4 + (long)jj * 4);
    uint4 hv = *((const uint4*)xb + (long)s * 8 + cl);
    float xf[8]; unp8(hv, xf);
    #pragma unroll
    for (int j = 0; j < 8; ++j){
      acc[0][j] += wt.x * xf[j];
      acc[1][j] += wt.y * xf[j];
      acc[2][j] += wt.z * xf[j];
      acc[3][j] += wt.w * xf[j];
    }
    sumw[0] += wt.x; sumw[1] += wt.y; sumw[2] += wt.z; sumw[3] += wt.w;
  }
  #pragma unroll
  for (int d = 8; d <= 32; d <<= 1){
    #pragma unroll
    for (int h = 0; h < 4; ++h){
      #pragma unroll
      for (int j = 0; j < 8; ++j) acc[h][j] += __shfl_xor(acc[h][j], d);
      sumw[h] += __shfl_xor(sumw[h], d);
    }
  }
  float4 ssv = *(const float4*)(Ss + (long)nid * 4);
  float4 sdv = *(const float4*)(Sd + (long)nid * 4);
  float wself[4] = { expf(lky(ssv.x + sdv.x)), expf(lky(ssv.y + sdv.y)),
                     expf(lky(ssv.z + sdv.z)), expf(lky(ssv.w + sdv.w)) };
  uint4 hv = *((const uint4*)xb + (long)nid * 8 + cl);
  float xf[8]; unp8(hv, xf);
  if (l < 8){
    #pragma unroll
    for (int h = 0; h < 4; ++h){
      float inv = 1.f / (sumw[h] + wself[h] + 1e-16f);
      float o[8];
      #pragma unroll
      for (int j = 0; j < 8; ++j) o[j] = (acc[h][j] + wself[h] * xf[j]) * inv;
      *((uint4*)Xagg + (long)nid * 32 + h * 8 + cl) = pack8(o);
    }
  }
}

// ---------------- MFMA GEMM (optionally block-diagonal) + fused scores/relu ----------------
template<int K, int KB, int CW, bool BD, bool SCORES, bool RELU>
__global__ __launch_bounds__(256) void gemm_mfma_kernel(
    const unsigned short* __restrict__ Xb, const unsigned short* __restrict__ Wpk,
    const float* __restrict__ a_s, const float* __restrict__ a_d,
    const float* __restrict__ a_s2, const float* __restrict__ a_d2,
    const float* __restrict__ bias,
    unsigned short* __restrict__ Hout,
    float* __restrict__ Ss, float* __restrict__ Sd,
    float* __restrict__ Ss2, float* __restrict__ Sd2, int n)
{
  constexpr int BR  = (CW == 4) ? 32 : 128;
  constexpr int M   = 64 * CW;
  constexpr int KSB = KB / 32;
  constexpr int LDA = K + 8;
  constexpr int SH  = (BR * LDA > BR * M) ? BR * LDA : BR * M;
  __shared__ unsigned short As[SH];

  const int t = threadIdx.x;
  const int w = t >> 6, l = t & 63;
  const int quad = l >> 4, l15 = l & 15;
  const long base = (long)blockIdx.x * BR;
  const int roww = (CW == 4) ? 0 : w;
  const int colw = (CW == 4) ? w : 0;
  const int abase = BD ? w * KB : 0;

  {
    const uint4* Xg = (const uint4*)Xb;
    long g0 = base * (K / 8);
    long lim = (long)n * (K / 8);
    for (int c = t; c < BR * K / 8; c += 256){
      int row = c / (K / 8), kc = c % (K / 8);
      uint4 v = make_uint4(0u, 0u, 0u, 0u);
      if (g0 + c < lim) v = Xg[g0 + c];
      *(uint4*)(As + row * LDA + kc * 8) = v;
    }
  }
  __syncthreads();

  f32x4 acc[2][4] = {};
  for (int s = 0; s < KSB; ++s){
    bf16x8 af0 = *(const bf16x8*)(As + (roww * 32 + 0  + l15) * LDA + abase + s * 32 + quad * 8);
    bf16x8 af1 = *(const bf16x8*)(As + (roww * 32 + 16 + l15) * LDA + abase + s * 32 + quad * 8);
    #pragma unroll
    for (int ct = 0; ct < 4; ++ct){
      int gct = colw * 4 + ct;
      bf16x8 bf = *(const bf16x8*)(Wpk + (((long)gct * KSB + s) * 64 + l) * 8);
      acc[0][ct] = __builtin_amdgcn_mfma_f32_16x16x32_bf16(af0, bf, acc[0][ct], 0, 0, 0);
      acc[1][ct] = __builtin_amdgcn_mfma_f32_16x16x32_bf16(af1, bf, acc[1][ct], 0, 0, 0);
    }
  }

  if constexpr (SCORES){
    if (CW == 4){
      const int head = w;
      float asv[4], adv[4];
      #pragma unroll
      for (int ct = 0; ct < 4; ++ct){
        int col = head * 64 + ct * 16 + l15;
        asv[ct] = a_s[col]; adv[ct] = a_d[col];
      }
      #pragma unroll
      for (int rt = 0; rt < 2; ++rt){
        #pragma unroll
        for (int r = 0; r < 4; ++r){
          float ps = 0.f, pd = 0.f;
          #pragma unroll
          for (int ct = 0; ct < 4; ++ct){
            float v = acc[rt][ct][r];
            ps += v * asv[ct]; pd += v * adv[ct];
          }
          ps += __shfl_xor(ps, 8); pd += __shfl_xor(pd, 8);
          ps += __shfl_xor(ps, 4); pd += __shfl_xor(pd, 4);
          ps += __shfl_xor(ps, 2); pd += __shfl_xor(pd, 2);
          ps += __shfl_xor(ps, 1); pd += __shfl_xor(pd, 1);
          long node = base + rt * 16 + quad * 4 + r;
          if (l15 == 0 && node < n){ Ss[node * 4 + head] = ps; Sd[node * 4 + head] = pd; }
        }
      }
    } else {
      float asm_[2], adm_[2], asl_[2], adl_[2];
      #pragma unroll
      for (int ct = 0; ct < 2; ++ct){
        int col = ct * 16 + l15;
        asm_[ct] = a_s[col];  adm_[ct] = a_d[col];
        asl_[ct] = a_s2[col]; adl_[ct] = a_d2[col];
      }
      #pragma unroll
      for (int rt = 0; rt < 2; ++rt){
        #pragma unroll
        for (int r = 0; r < 4; ++r){
          float psm = 0.f, pdm = 0.f, psl = 0.f, pdl = 0.f;
          #pragma unroll
          for (int ct = 0; ct < 2; ++ct){
            float vm = acc[rt][ct][r];
            float vl = acc[rt][ct + 2][r];
            psm += vm * asm_[ct]; pdm += vm * adm_[ct];
            psl += vl * asl_[ct]; pdl += vl * adl_[ct];
          }
          #pragma unroll
          for (int d = 8; d >= 1; d >>= 1){
            psm += __shfl_xor(psm, d); pdm += __shfl_xor(pdm, d);
            psl += __shfl_xor(psl, d); pdl += __shfl_xor(pdl, d);
          }
          long node = base + w * 32 + rt * 16 + quad * 4 + r;
          if (l15 == 0 && node < n){
            Ss[node]  = psm; Sd[node]  = pdm;
            Ss2[node] = psl; Sd2[node] = pdl;
          }
        }
      }
    }
  }

  __syncthreads();
  float bct[4] = {0.f, 0.f, 0.f, 0.f};
  if constexpr (RELU){
    #pragma unroll
    for (int ct = 0; ct < 4; ++ct) bct[ct] = bias[colw * 64 + ct * 16 + l15];
  }
  #pragma unroll
  for (int rt = 0; rt < 2; ++rt){
    #pragma unroll
    for (int ct = 0; ct < 4; ++ct){
      #pragma unroll
      for (int r = 0; r < 4; ++r){
        int row = roww * 32 + rt * 16 + quad * 4 + r;
        int col = colw * 64 + ct * 16 + l15;
        float o = acc[rt][ct][r];
        if constexpr (RELU) o = fmaxf(o + bct[ct], 0.f);
        As[row * M + col] = f2bf(o);
      }
    }
  }
  __syncthreads();
  {
    uint4* Hg = (uint4*)Hout;
    for (int c = t; c < BR * M / 8; c += 256){
      int row = c / (M / 8);
      if (base + row < n) Hg[base * (M / 8) + c] = *(const uint4*)(As + c * 8);
    }
  }
}

// ---------------- layer-2 aggregation: block per node, 8 edges in flight ----------------
__global__ __launch_bounds__(256) void agg256_kernel(
    const unsigned short* __restrict__ Hbuf, const float* __restrict__ w4,
    const float* __restrict__ Ss, const float* __restrict__ Sd,
    const int* __restrict__ rowptr, const int* __restrict__ colv,
    const float* __restrict__ bias, unsigned short* __restrict__ Out, int n)
{
  __shared__ float red[4 * 256];
  __shared__ float redw[16];
  int nid = blockIdx.x;
  int t = threadIdx.x;
  int w = t >> 6, l = t & 63;
  int slot = w * 2 + (l >> 5);
  int cl = l & 31;
  int head = cl >> 3;
  float acc[8] = {0,0,0,0,0,0,0,0};
  float sumw = 0.f;
  int beg = rowptr[nid], end = rowptr[nid + 1];
  for (int jj = beg + slot; jj < end; jj += 8){
    int s = colv[jj];
    float wt = w4[(long)jj * 4 + head];
    uint4 hv = *((const uint4*)Hbuf + (long)s * 32 + cl);
    float xf[8]; unp8(hv, xf);
    #pragma unroll
    for (int j = 0; j < 8; ++j) acc[j] += wt * xf[j];
    sumw += wt;
  }
  #pragma unroll
  for (int j = 0; j < 8; ++j) acc[j] += __shfl_xor(acc[j], 32);
  sumw += __shfl_xor(sumw, 32);
  if (l < 32){
    #pragma unroll
    for (int j = 0; j < 8; ++j) red[w * 256 + cl * 8 + j] = acc[j];
    if ((cl & 7) == 0) redw[w * 4 + head] = sumw;
  }
  __syncthreads();
  int col = t, hh = col >> 6;
  float tot = red[col] + red[256 + col] + red[512 + col] + red[768 + col];
  float sw  = redw[hh] + redw[4 + hh] + redw[8 + hh] + redw[12 + hh];
  float wself = expf(lky(Ss[(long)nid * 4 + hh] + Sd[(long)nid * 4 + hh]));
  float hself = bf2f(Hbuf[(long)nid * 256 + col]);
  float o = (tot + wself * hself) / (sw + wself + 1e-16f) + bias[col];
  Out[(long)nid * 256 + col] = f2bf(fmaxf(o, 0.f));
}

// ---------------- mu/lv aggregation + reparameterize ----------------
__global__ __launch_bounds__(256) void agg_muv_kernel(
    const unsigned short* __restrict__ Hmuv, const float* __restrict__ w2,
    const float* __restrict__ Ssm, const float* __restrict__ Sdm,
    const float* __restrict__ Ssl, const float* __restrict__ Sdl,
    const int* __restrict__ rowptr, const int* __restrict__ colv,
    const float* __restrict__ bmu, const float* __restrict__ blv,
    const float* __restrict__ epsv,
    float* __restrict__ out_mu, float* __restrict__ out_lv, float* __restrict__ out_z, int n)
{
  int gid = blockIdx.x * blockDim.x + threadIdx.x;
  int node = gid >> 5, c = gid & 31;
  if (node >= n) return;
  float wm = expf(lky(Ssm[node] + Sdm[node]));
  float wl = expf(lky(Ssl[node] + Sdl[node]));
  float summ = wm, suml = wl;
  float am = wm * bf2f(Hmuv[(long)node * 64 + c]);
  float al = wl * bf2f(Hmuv[(long)node * 64 + 32 + c]);
  int beg = rowptr[node], end = rowptr[node + 1];
  for (int jj = beg; jj < end; ++jj){
    int s = colv[jj];
    float2 wv = *(const float2*)(w2 + (long)jj * 2);
    summ += wv.x; am += wv.x * bf2f(Hmuv[(long)s * 64 + c]);
    suml += wv.y; al += wv.y * bf2f(Hmuv[(long)s * 64 + 32 + c]);
  }
  float mu = am / (summ + 1e-16f) + bmu[c];
  float lv = al / (suml + 1e-16f) + blv[c];
  float z  = mu + epsv[(long)node * 32 + c] * expf(0.5f * lv);
  out_mu[(long)node * 32 + c] = mu;
  out_lv[(long)node * 32 + c] = lv;
  out_z [(long)node * 32 + c] = z;
}

// ---------------- decoder ----------------
__global__ __launch_bounds__(256) void decoder_kernel(
    const float* __restrict__ Z, const float* __restrict__ Wfc, const float* __restrict__ bfc,
    const float* __restrict__ Wnode, const float* __restrict__ bnode,
    unsigned short* __restrict__ ZD, float* __restrict__ NF, int n)
{
  __shared__ float zs[4 * 32];
  __shared__ float zds[4 * 64];
  int t = threadIdx.x;
  int i = t >> 6, j = t & 63;
  long node = (long)blockIdx.x * 4 + i;
  if (t < 128){
    long g = (long)blockIdx.x * 128 + t;
    zs[t] = (g < (long)n * 32) ? Z[g] : 0.f;
  }
  __syncthreads();
  float acc = bfc[j];
  #pragma unroll
  for (int k = 0; k < 32; ++k) acc += zs[i * 32 + k] * Wfc[k * 64 + j];
  acc = fmaxf(acc, 0.f);
  zds[i * 64 + j] = acc;
  if (node < n) ZD[node * 64 + j] = f2bf(acc);
  __syncthreads();
  float nf = bnode[j];
  #pragma unroll
  for (int k = 0; k < 64; ++k) nf += zds[i * 64 + k] * Wnode[k * 64 + j];
  if (node < n) NF[node * 64 + j] = nf;
}

// ---------------- edge scores: 8 edges per wave, bf16 ZD ----------------
__global__ __launch_bounds__(256) void edge_score_kernel(
    const unsigned short* __restrict__ ZD, const int* __restrict__ src, const int* __restrict__ dst,
    const float* __restrict__ Wedge, const float* __restrict__ bedge,
    float* __restrict__ out_es, int E)
{
  int gid = blockIdx.x * 256 + threadIdx.x;
  int l = threadIdx.x & 63;
  int slot = l >> 3, chunk = l & 7;
  int e = (gid >> 6) * 8 + slot;
  float4 we0 = *(const float4*)(Wedge + chunk * 8);
  float4 we1 = *(const float4*)(Wedge + chunk * 8 + 4);
  float p = 0.f;
  if (e < E){
    int s = src[e], d = dst[e];
    uint4 zs_ = *((const uint4*)ZD + (long)s * 8 + chunk);
    uint4 zd_ = *((const uint4*)ZD + (long)d * 8 + chunk);
    float a[8], b[8]; unp8(zs_, a); unp8(zd_, b);
    p = a[0]*b[0]*we0.x + a[1]*b[1]*we0.y + a[2]*b[2]*we0.z + a[3]*b[3]*we0.w
      + a[4]*b[4]*we1.x + a[5]*b[5]*we1.y + a[6]*b[6]*we1.z + a[7]*b[7]*we1.w;
  }
  p += __shfl_xor(p, 1);
  p += __shfl_xor(p, 2);
  p += __shfl_xor(p, 4);
  if (chunk == 0 && e < E) out_es[e] = p + bedge[0];
}

// ---------------- launch ----------------
extern "C" void kernel_launch(void* const* d_in, const int* in_sizes, int n_in,
                              void* d_out, int out_size, void* d_ws, size_t ws_size,
                              hipStream_t stream)
{
  const float* x     = (const float*)d_in[0];
  const int*   ei    = (const int*)  d_in[1];
  const float* epsv  = (const float*)d_in[3];
  const float* W1    = (const float*)d_in[4];
  const float* as1   = (const float*)d_in[5];
  const float* ad1   = (const float*)d_in[6];
  const float* b1    = (const float*)d_in[7];
  const float* W2    = (const float*)d_in[8];
  const float* as2   = (const float*)d_in[9];
  const float* ad2   = (const float*)d_in[10];
  const float* b2    = (const float*)d_in[11];
  const float* Wmu   = (const float*)d_in[12];
  const float* asmu  = (const float*)d_in[13];
  const float* admu  = (const float*)d_in[14];
  const float* bmu   = (const float*)d_in[15];
  const float* Wlv   = (const float*)d_in[16];
  const float* aslv  = (const float*)d_in[17];
  const float* adlv  = (const float*)d_in[18];
  const float* blv   = (const float*)d_in[19];
  const float* Wfc   = (const float*)d_in[20];
  const float* bfc   = (const float*)d_in[21];
  const float* Wnode = (const float*)d_in[22];
  const float* bnode = (const float*)d_in[23];
  const float* Wedge = (const float*)d_in[24];
  const float* bedge = (const float*)d_in[25];

  const int N = in_sizes[0] / 64;
  const int E = in_sizes[1] / 2;
  const int* srcA = ei;
  const int* dstA = ei + E;

  char* wsb = (char*)d_ws;
  size_t off = 0;
  auto alloc = [&](size_t bytes) -> void* {
    void* p = wsb + off;
    off += (bytes + 255) & ~(size_t)255;
    return p;
  };
  unsigned short* xb    = (unsigned short*)alloc((size_t)N * 64 * 2);
  unsigned short* bufP  = (unsigned short*)alloc((size_t)N * 256 * 2);  // Xagg -> H2
  unsigned short* bufQ  = (unsigned short*)alloc((size_t)N * 256 * 2);  // B1 -> B2
  unsigned short* Hmuv  = (unsigned short*)alloc((size_t)N * 64 * 2);
  unsigned short* ZDb   = (unsigned short*)alloc((size_t)N * 64 * 2);
  unsigned short* W1pk  = (unsigned short*)alloc((size_t)64 * 256 * 2);
  unsigned short* W2pk  = (unsigned short*)alloc((size_t)256 * 256 * 2);
  unsigned short* Wmvpk = (unsigned short*)alloc((size_t)256 * 64 * 2);
  float* P1    = (float*)alloc(512 * 4);
  float* S1s   = (float*)alloc((size_t)N * 4 * 4);
  float* S1d   = (float*)alloc((size_t)N * 4 * 4);
  float* S2s   = (float*)alloc((size_t)N * 4 * 4);
  float* S2d   = (float*)alloc((size_t)N * 4 * 4);
  float* Ssm   = (float*)alloc((size_t)N * 4);
  float* Sdm   = (float*)alloc((size_t)N * 4);
  float* Ssl   = (float*)alloc((size_t)N * 4);
  float* Sdl   = (float*)alloc((size_t)N * 4);
  float* wbuf  = (float*)alloc((size_t)E * 4 * 4);    // w4 (L1) -> w4 (L2) -> w2
  int*   deg   = (int*)  alloc((size_t)N * 2 * 4);
  int*   cursor= deg + N;
  int*   rowptr= (int*)  alloc((size_t)(N + 1) * 4);
  int*   colv  = (int*)  alloc((size_t)E * 4);
  int*   dstv  = (int*)  alloc((size_t)E * 4);
  int*   bsum  = (int*)  alloc(1024);
  int*   boff  = (int*)  alloc(1024);
  (void)ws_size; (void)n_in; (void)out_size;

  float* out_mu = (float*)d_out;
  float* out_lv = out_mu + (size_t)N * 32;
  float* out_z  = out_lv + (size_t)N * 32;
  float* out_nf = out_z  + (size_t)N * 32;
  float* out_es = out_nf + (size_t)N * 64;

  const int nb = (N + 255) / 256;

  // CSR build
  zero_ints_kernel<<<(2 * N + 255) / 256, 256, 0, stream>>>(deg, 2 * N);
  count_deg_kernel<<<(E + 255) / 256, 256, 0, stream>>>(dstA, deg, E);
  scan_chunk_kernel<<<nb, 256, 0, stream>>>(deg, rowptr, bsum, N);
  scan_bsum_kernel<<<1, 256, 0, stream>>>(bsum, boff, nb);
  scan_add_kernel<<<nb, 256, 0, stream>>>(rowptr, boff, N);
  fill_csr_kernel<<<(E + 255) / 256, 256, 0, stream>>>(srcA, dstA, rowptr, cursor, colv, dstv, E);

  // weight packing + P1
  pack_w_kernel<<<(64 * 256 + 255) / 256, 256, 0, stream>>>(W1, nullptr, 64, 256, 256, W1pk);
  pack_w_kernel<<<(256 * 256 + 255) / 256, 256, 0, stream>>>(W2, nullptr, 256, 256, 256, W2pk);
  pack_w_kernel<<<(256 * 64 + 255) / 256, 256, 0, stream>>>(Wmu, Wlv, 256, 64, 32, Wmvpk);
  make_p1_kernel<<<2, 256, 0, stream>>>(W1, as1, ad1, P1);

  // layer 1: scores from x, aggregate x, block-diagonal GEMM (+bias+relu)
  cvt_x_kernel<<<((size_t)N * 16 + 255) / 256, 256, 0, stream>>>(x, xb, (long)N * 16);
  score1_kernel<<<(N + 255) / 256, 256, 0, stream>>>(xb, P1, S1s, S1d, N);
  edgew4_kernel<<<(E + 255) / 256, 256, 0, stream>>>(colv, dstv, S1s, S1d, wbuf, E);
  aggx_kernel<<<(N + 3) / 4, 256, 0, stream>>>(xb, wbuf, S1s, S1d, rowptr, colv, bufP, N);
  gemm_mfma_kernel<256, 64, 4, true, false, true><<<(N + 31) / 32, 256, 0, stream>>>(
      bufP, W1pk, nullptr, nullptr, nullptr, nullptr, b1, bufQ,
      nullptr, nullptr, nullptr, nullptr, N);

  // layer 2: GEMM(+scores), edge weights, aggregate(+bias+relu)
  gemm_mfma_kernel<256, 256, 4, false, true, false><<<(N + 31) / 32, 256, 0, stream>>>(
      bufQ, W2pk, as2, ad2, nullptr, nullptr, nullptr, bufP,
      S2s, S2d, nullptr, nullptr, N);
  edgew4_kernel<<<(E + 255) / 256, 256, 0, stream>>>(colv, dstv, S2s, S2d, wbuf, E);
  agg256_kernel<<<N, 256, 0, stream>>>(bufP, wbuf, S2s, S2d, rowptr, colv, b2, bufQ, N);

  // mu / logvar
  gemm_mfma_kernel<256, 256, 1, false, true, false><<<(N + 127) / 128, 256, 0, stream>>>(
      bufQ, Wmvpk, asmu, admu, aslv, adlv, nullptr, Hmuv,
      Ssm, Sdm, Ssl, Sdl, N);
  edgew2_kernel<<<(E + 255) / 256, 256, 0, stream>>>(colv, dstv, Ssm, Sdm, Ssl, Sdl, wbuf, E);
  agg_muv_kernel<<<((size_t)N * 32 + 255) / 256, 256, 0, stream>>>(
      Hmuv, wbuf, Ssm, Sdm, Ssl, Sdl, rowptr, colv, bmu, blv, epsv,
      out_mu, out_lv, out_z, N);

  // decoder
  decoder_kernel<<<(N + 3) / 4, 256, 0, stream>>>(out_z, Wfc, bfc, Wnode, bnode, ZDb, out_nf, N);
  {
    long waves = ((long)E + 7) / 8;
    long blocks = (waves + 3) / 4;
    edge_score_kernel<<<(int)blocks, 256, 0, stream>>>(ZDb, srcA, dstA, Wedge, bedge, out_es, E);
  }
}

// Round 4
// 419.172 us; speedup vs baseline: 1.9951x; 1.1091x over previous
//
#include <hip/hip_runtime.h>
#include <math.h>

#define NEG_SLOPE 0.2f

__device__ __forceinline__ float lky(float x){ return x > 0.f ? x : NEG_SLOPE * x; }

__device__ __forceinline__ unsigned short f2bf(float f){
  unsigned int u = __float_as_uint(f);
  unsigned int r = (u + 0x7fffu + ((u >> 16) & 1u)) >> 16;
  return (unsigned short)r;
}
__device__ __forceinline__ float bf2f(unsigned short s){
  return __uint_as_float(((unsigned int)s) << 16);
}
__device__ __forceinline__ void unp8(uint4 v, float* f){
  f[0]=__uint_as_float(v.x<<16); f[1]=__uint_as_float(v.x&0xffff0000u);
  f[2]=__uint_as_float(v.y<<16); f[3]=__uint_as_float(v.y&0xffff0000u);
  f[4]=__uint_as_float(v.z<<16); f[5]=__uint_as_float(v.z&0xffff0000u);
  f[6]=__uint_as_float(v.w<<16); f[7]=__uint_as_float(v.w&0xffff0000u);
}
__device__ __forceinline__ uint4 pack8(const float* o){
  uint4 v;
  v.x = (unsigned)f2bf(o[0]) | ((unsigned)f2bf(o[1])<<16);
  v.y = (unsigned)f2bf(o[2]) | ((unsigned)f2bf(o[3])<<16);
  v.z = (unsigned)f2bf(o[4]) | ((unsigned)f2bf(o[5])<<16);
  v.w = (unsigned)f2bf(o[6]) | ((unsigned)f2bf(o[7])<<16);
  return v;
}

typedef __bf16 bf16x8 __attribute__((ext_vector_type(8)));
typedef float  f32x4  __attribute__((ext_vector_type(4)));

// ---------------- CSR build ----------------
__global__ void zero_ints_kernel(int* __restrict__ p, int n){
  int i = blockIdx.x * blockDim.x + threadIdx.x;
  if (i < n) p[i] = 0;
}
__global__ void count_deg_kernel(const int* __restrict__ dst, int* __restrict__ deg, int E){
  int e = blockIdx.x * blockDim.x + threadIdx.x;
  if (e < E) atomicAdd(&deg[dst[e]], 1);
}
__global__ void scan_chunk_kernel(const int* __restrict__ deg, int* __restrict__ rowptr,
                                  int* __restrict__ bsum, int n){
  __shared__ int s[256];
  int t = threadIdx.x;
  int i = blockIdx.x * 256 + t;
  int v = (i < n) ? deg[i] : 0;
  s[t] = v; __syncthreads();
  for (int off = 1; off < 256; off <<= 1){
    int x = (t >= off) ? s[t - off] : 0;
    __syncthreads();
    s[t] += x;
    __syncthreads();
  }
  if (i < n) rowptr[i + 1] = s[t];
  if (t == 255) bsum[blockIdx.x] = s[255];
}
__global__ void scan_bsum_kernel(const int* __restrict__ bsum, int* __restrict__ boff, int nb){
  __shared__ int s[256];
  int t = threadIdx.x;
  int v = (t < nb) ? bsum[t] : 0;
  s[t] = v; __syncthreads();
  for (int off = 1; off < 256; off <<= 1){
    int x = (t >= off) ? s[t - off] : 0;
    __syncthreads();
    s[t] += x;
    __syncthreads();
  }
  boff[t] = s[t] - v;
}
__global__ void scan_add_kernel(int* __restrict__ rowptr, const int* __restrict__ boff, int n){
  int i = blockIdx.x * 256 + threadIdx.x;
  if (i < n) rowptr[i + 1] += boff[blockIdx.x];
  if (i == 0) rowptr[0] = 0;
}
__global__ void fill_csr_kernel(const int* __restrict__ src, const int* __restrict__ dst,
                                const int* __restrict__ rowptr, int* __restrict__ cursor,
                                int* __restrict__ colv, int* __restrict__ dstv, int E){
  int e = blockIdx.x * blockDim.x + threadIdx.x;
  if (e >= E) return;
  int d = dst[e];
  int pos = atomicAdd(&cursor[d], 1);
  colv[rowptr[d] + pos] = src[e];
  dstv[rowptr[d] + pos] = d;
}

// ---------------- weight pack: fp32 [K][M] -> bf16 B-fragment layout ----------------
__global__ void pack_w_kernel(const float* __restrict__ Wa, const float* __restrict__ Wb,
                              int K, int M, int Mhalf, unsigned short* __restrict__ out){
  int idx = blockIdx.x * 256 + threadIdx.x;
  if (idx >= K * M) return;
  int j = idx & 7;
  int l = (idx >> 3) & 63;
  int rest = idx >> 9;
  int KS = K >> 5;
  int s = rest % KS, gct = rest / KS;
  int col = gct * 16 + (l & 15);
  int k   = s * 32 + ((l >> 4) << 3) + j;
  float v;
  if (Wb == nullptr) v = Wa[(long)k * M + col];
  else v = (col < Mhalf) ? Wa[(long)k * Mhalf + col] : Wb[(long)k * Mhalf + (col - Mhalf)];
  out[idx] = f2bf(v);
}

// ---------------- x fp32 -> bf16 ----------------
__global__ void cvt_x_kernel(const float* __restrict__ x, unsigned short* __restrict__ xb, long n4){
  long i = (long)blockIdx.x * 256 + threadIdx.x;
  if (i >= n4) return;
  float4 v = ((const float4*)x)[i];
  uint2 o;
  o.x = (unsigned)f2bf(v.x) | ((unsigned)f2bf(v.y) << 16);
  o.y = (unsigned)f2bf(v.z) | ((unsigned)f2bf(v.w) << 16);
  ((uint2*)xb)[i] = o;
}

// ---------------- P1 = W1 @ a (64 x 4 x {src,dst}) ----------------
__global__ void make_p1_kernel(const float* __restrict__ W1, const float* __restrict__ as1,
                               const float* __restrict__ ad1, float* __restrict__ P1){
  int idx = blockIdx.x * 256 + threadIdx.x;
  if (idx >= 512) return;
  int sd = idx & 1, h = (idx >> 1) & 3, k = idx >> 3;
  const float* av = sd ? ad1 : as1;
  float acc = 0.f;
  for (int c = 0; c < 64; ++c) acc += W1[k * 256 + h * 64 + c] * av[h * 64 + c];
  P1[idx] = acc;
}

// ---------------- layer-1 scores: S1 = xb @ P1 ----------------
__global__ __launch_bounds__(256) void score1_kernel(
    const unsigned short* __restrict__ xb, const float* __restrict__ P1,
    float* __restrict__ S1s, float* __restrict__ S1d, int n)
{
  __shared__ float P[512];
  int t = threadIdx.x;
  P[t] = P1[t]; P[t + 256] = P1[t + 256];
  __syncthreads();
  int nid = blockIdx.x * 256 + t;
  if (nid >= n) return;
  float acc[8] = {0,0,0,0,0,0,0,0};
  const uint4* xr = (const uint4*)xb + (long)nid * 8;
  for (int kc = 0; kc < 8; ++kc){
    uint4 v = xr[kc];
    float xf[8]; unp8(v, xf);
    #pragma unroll
    for (int j = 0; j < 8; ++j){
      int k = kc * 8 + j;
      #pragma unroll
      for (int o = 0; o < 8; ++o) acc[o] += xf[j] * P[k * 8 + o];
    }
  }
  *(float4*)(S1s + nid * 4) = make_float4(acc[0], acc[2], acc[4], acc[6]);
  *(float4*)(S1d + nid * 4) = make_float4(acc[1], acc[3], acc[5], acc[7]);
}

// ---------------- edge softmax weights (precomputed) ----------------
__global__ void edgew4_kernel(const int* __restrict__ colv, const int* __restrict__ dstv,
                              const float* __restrict__ Ss, const float* __restrict__ Sd,
                              float* __restrict__ w4, int E){
  int e = blockIdx.x * 256 + threadIdx.x;
  if (e >= E) return;
  int s = colv[e], d = dstv[e];
  float4 a = *(const float4*)(Ss + (long)s * 4);
  float4 b = *(const float4*)(Sd + (long)d * 4);
  *(float4*)(w4 + (long)e * 4) = make_float4(
      expf(lky(a.x + b.x)), expf(lky(a.y + b.y)),
      expf(lky(a.z + b.z)), expf(lky(a.w + b.w)));
}
__global__ void edgew2_kernel(const int* __restrict__ colv, const int* __restrict__ dstv,
                              const float* __restrict__ Ssm, const float* __restrict__ Sdm,
                              const float* __restrict__ Ssl, const float* __restrict__ Sdl,
                              float* __restrict__ w2, int E){
  int e = blockIdx.x * 256 + threadIdx.x;
  if (e >= E) return;
  int s = colv[e], d = dstv[e];
  float wm = expf(lky(Ssm[s] + Sdm[d]));
  float wl = expf(lky(Ssl[s] + Sdl[d]));
  *(float2*)(w2 + (long)e * 2) = make_float2(wm, wl);
}

// ---------------- layer-1 aggregation of x: one wave per node, 2 edges in flight ----
// lane: slot = l>>5 (edge), cl = l&31 (bf16 column pair -> cols 2cl, 2cl+1)
__global__ __launch_bounds__(256) void aggx_kernel(
    const unsigned short* __restrict__ xb, const float* __restrict__ w4,
    const float* __restrict__ Ss, const float* __restrict__ Sd,
    const int* __restrict__ rowptr, const int* __restrict__ colv,
    unsigned short* __restrict__ Xagg, int n)
{
  int wv = threadIdx.x >> 6, l = threadIdx.x & 63;
  int nid = blockIdx.x * 4 + wv;
  if (nid >= n) return;
  int slot = l >> 5;
  int cl = l & 31;
  float acc[4][2] = {};
  float sumw[4] = {0.f, 0.f, 0.f, 0.f};
  int beg = rowptr[nid], end = rowptr[nid + 1];
  for (int jj = beg + slot; jj < end; jj += 2){
    int s = colv[jj];
    float4 wt = *(const float4*)(w4 + (long)jj * 4);
    unsigned xv = *((const unsigned*)xb + (long)s * 32 + cl);
    float f0 = __uint_as_float(xv << 16);
    float f1 = __uint_as_float(xv & 0xffff0000u);
    acc[0][0] += wt.x * f0; acc[0][1] += wt.x * f1;
    acc[1][0] += wt.y * f0; acc[1][1] += wt.y * f1;
    acc[2][0] += wt.z * f0; acc[2][1] += wt.z * f1;
    acc[3][0] += wt.w * f0; acc[3][1] += wt.w * f1;
    sumw[0] += wt.x; sumw[1] += wt.y; sumw[2] += wt.z; sumw[3] += wt.w;
  }
  #pragma unroll
  for (int h = 0; h < 4; ++h){
    acc[h][0] += __shfl_xor(acc[h][0], 32);
    acc[h][1] += __shfl_xor(acc[h][1], 32);
    sumw[h]   += __shfl_xor(sumw[h], 32);
  }
  float4 ssv = *(const float4*)(Ss + (long)nid * 4);
  float4 sdv = *(const float4*)(Sd + (long)nid * 4);
  unsigned xv = *((const unsigned*)xb + (long)nid * 32 + cl);
  float f0 = __uint_as_float(xv << 16);
  float f1 = __uint_as_float(xv & 0xffff0000u);
  float wsh[4] = { expf(lky(ssv.x + sdv.x)), expf(lky(ssv.y + sdv.y)),
                   expf(lky(ssv.z + sdv.z)), expf(lky(ssv.w + sdv.w)) };
  if (l < 32){
    #pragma unroll
    for (int h = 0; h < 4; ++h){
      float inv = 1.f / (sumw[h] + wsh[h] + 1e-16f);
      float o0 = (acc[h][0] + wsh[h] * f0) * inv;
      float o1 = (acc[h][1] + wsh[h] * f1) * inv;
      unsigned ov = (unsigned)f2bf(o0) | ((unsigned)f2bf(o1) << 16);
      *((unsigned*)Xagg + (long)nid * 128 + h * 32 + cl) = ov;
    }
  }
}

// ---------------- MFMA GEMM (optionally block-diagonal) + fused scores/relu ----------------
template<int K, int KB, int CW, bool BD, bool SCORES, bool RELU>
__global__ __launch_bounds__(256) void gemm_mfma_kernel(
    const unsigned short* __restrict__ Xb, const unsigned short* __restrict__ Wpk,
    const float* __restrict__ a_s, const float* __restrict__ a_d,
    const float* __restrict__ a_s2, const float* __restrict__ a_d2,
    const float* __restrict__ bias,
    unsigned short* __restrict__ Hout,
    float* __restrict__ Ss, float* __restrict__ Sd,
    float* __restrict__ Ss2, float* __restrict__ Sd2, int n)
{
  constexpr int BR  = (CW == 4) ? 32 : 128;
  constexpr int M   = 64 * CW;
  constexpr int KSB = KB / 32;
  constexpr int LDA = K + 8;
  constexpr int SH  = (BR * LDA > BR * M) ? BR * LDA : BR * M;
  __shared__ unsigned short As[SH];

  const int t = threadIdx.x;
  const int w = t >> 6, l = t & 63;
  const int quad = l >> 4, l15 = l & 15;
  const long base = (long)blockIdx.x * BR;
  const int roww = (CW == 4) ? 0 : w;
  const int colw = (CW == 4) ? w : 0;
  const int abase = BD ? w * KB : 0;

  {
    const uint4* Xg = (const uint4*)Xb;
    long g0 = base * (K / 8);
    long lim = (long)n * (K / 8);
    for (int c = t; c < BR * K / 8; c += 256){
      int row = c / (K / 8), kc = c % (K / 8);
      uint4 v = make_uint4(0u, 0u, 0u, 0u);
      if (g0 + c < lim) v = Xg[g0 + c];
      *(uint4*)(As + row * LDA + kc * 8) = v;
    }
  }
  __syncthreads();

  f32x4 acc[2][4] = {};
  for (int s = 0; s < KSB; ++s){
    bf16x8 af0 = *(const bf16x8*)(As + (roww * 32 + 0  + l15) * LDA + abase + s * 32 + quad * 8);
    bf16x8 af1 = *(const bf16x8*)(As + (roww * 32 + 16 + l15) * LDA + abase + s * 32 + quad * 8);
    #pragma unroll
    for (int ct = 0; ct < 4; ++ct){
      int gct = colw * 4 + ct;
      bf16x8 bf = *(const bf16x8*)(Wpk + (((long)gct * KSB + s) * 64 + l) * 8);
      acc[0][ct] = __builtin_amdgcn_mfma_f32_16x16x32_bf16(af0, bf, acc[0][ct], 0, 0, 0);
      acc[1][ct] = __builtin_amdgcn_mfma_f32_16x16x32_bf16(af1, bf, acc[1][ct], 0, 0, 0);
    }
  }

  if constexpr (SCORES){
    if (CW == 4){
      const int head = w;
      float asv[4], adv[4];
      #pragma unroll
      for (int ct = 0; ct < 4; ++ct){
        int col = head * 64 + ct * 16 + l15;
        asv[ct] = a_s[col]; adv[ct] = a_d[col];
      }
      #pragma unroll
      for (int rt = 0; rt < 2; ++rt){
        #pragma unroll
        for (int r = 0; r < 4; ++r){
          float ps = 0.f, pd = 0.f;
          #pragma unroll
          for (int ct = 0; ct < 4; ++ct){
            float v = acc[rt][ct][r];
            ps += v * asv[ct]; pd += v * adv[ct];
          }
          ps += __shfl_xor(ps, 8); pd += __shfl_xor(pd, 8);
          ps += __shfl_xor(ps, 4); pd += __shfl_xor(pd, 4);
          ps += __shfl_xor(ps, 2); pd += __shfl_xor(pd, 2);
          ps += __shfl_xor(ps, 1); pd += __shfl_xor(pd, 1);
          long node = base + rt * 16 + quad * 4 + r;
          if (l15 == 0 && node < n){ Ss[node * 4 + head] = ps; Sd[node * 4 + head] = pd; }
        }
      }
    } else {
      float asm_[2], adm_[2], asl_[2], adl_[2];
      #pragma unroll
      for (int ct = 0; ct < 2; ++ct){
        int col = ct * 16 + l15;
        asm_[ct] = a_s[col];  adm_[ct] = a_d[col];
        asl_[ct] = a_s2[col]; adl_[ct] = a_d2[col];
      }
      #pragma unroll
      for (int rt = 0; rt < 2; ++rt){
        #pragma unroll
        for (int r = 0; r < 4; ++r){
          float psm = 0.f, pdm = 0.f, psl = 0.f, pdl = 0.f;
          #pragma unroll
          for (int ct = 0; ct < 2; ++ct){
            float vm = acc[rt][ct][r];
            float vl = acc[rt][ct + 2][r];
            psm += vm * asm_[ct]; pdm += vm * adm_[ct];
            psl += vl * asl_[ct]; pdl += vl * adl_[ct];
          }
          #pragma unroll
          for (int d = 8; d >= 1; d >>= 1){
            psm += __shfl_xor(psm, d); pdm += __shfl_xor(pdm, d);
            psl += __shfl_xor(psl, d); pdl += __shfl_xor(pdl, d);
          }
          long node = base + w * 32 + rt * 16 + quad * 4 + r;
          if (l15 == 0 && node < n){
            Ss[node]  = psm; Sd[node]  = pdm;
            Ss2[node] = psl; Sd2[node] = pdl;
          }
        }
      }
    }
  }

  __syncthreads();
  float bct[4] = {0.f, 0.f, 0.f, 0.f};
  if constexpr (RELU){
    #pragma unroll
    for (int ct = 0; ct < 4; ++ct) bct[ct] = bias[colw * 64 + ct * 16 + l15];
  }
  #pragma unroll
  for (int rt = 0; rt < 2; ++rt){
    #pragma unroll
    for (int ct = 0; ct < 4; ++ct){
      #pragma unroll
      for (int r = 0; r < 4; ++r){
        int row = roww * 32 + rt * 16 + quad * 4 + r;
        int col = colw * 64 + ct * 16 + l15;
        float o = acc[rt][ct][r];
        if constexpr (RELU) o = fmaxf(o + bct[ct], 0.f);
        As[row * M + col] = f2bf(o);
      }
    }
  }
  __syncthreads();
  {
    uint4* Hg = (uint4*)Hout;
    for (int c = t; c < BR * M / 8; c += 256){
      int row = c / (M / 8);
      if (base + row < n) Hg[base * (M / 8) + c] = *(const uint4*)(As + c * 8);
    }
  }
}

// ---------------- layer-2 aggregation: one wave per node, 2 edges in flight ----------------
// lane: slot = l>>5, cl = l&31 (8 cols: 8cl..8cl+7, head = cl>>3)
__global__ __launch_bounds__(256) void agg256_kernel(
    const unsigned short* __restrict__ Hbuf, const float* __restrict__ w4,
    const float* __restrict__ Ss, const float* __restrict__ Sd,
    const int* __restrict__ rowptr, const int* __restrict__ colv,
    const float* __restrict__ bias, unsigned short* __restrict__ Out, int n)
{
  int wv = threadIdx.x >> 6, l = threadIdx.x & 63;
  int nid = blockIdx.x * 4 + wv;
  if (nid >= n) return;
  int slot = l >> 5;
  int cl = l & 31;
  int head = cl >> 3;
  float acc[8] = {0,0,0,0,0,0,0,0};
  float sumw = 0.f;
  int beg = rowptr[nid], end = rowptr[nid + 1];
  for (int jj = beg + slot; jj < end; jj += 2){
    int s = colv[jj];
    float wt = w4[(long)jj * 4 + head];
    uint4 hv = *((const uint4*)Hbuf + (long)s * 32 + cl);
    float xf[8]; unp8(hv, xf);
    #pragma unroll
    for (int j = 0; j < 8; ++j) acc[j] += wt * xf[j];
    sumw += wt;
  }
  #pragma unroll
  for (int j = 0; j < 8; ++j) acc[j] += __shfl_xor(acc[j], 32);
  sumw += __shfl_xor(sumw, 32);
  float wself = expf(lky(Ss[(long)nid * 4 + head] + Sd[(long)nid * 4 + head]));
  uint4 hv = *((const uint4*)Hbuf + (long)nid * 32 + cl);
  float xf[8]; unp8(hv, xf);
  if (l < 32){
    float inv = 1.f / (sumw + wself + 1e-16f);
    float4 bv0 = *(const float4*)(bias + cl * 8);
    float4 bv1 = *(const float4*)(bias + cl * 8 + 4);
    float o[8];
    o[0] = fmaxf((acc[0] + wself * xf[0]) * inv + bv0.x, 0.f);
    o[1] = fmaxf((acc[1] + wself * xf[1]) * inv + bv0.y, 0.f);
    o[2] = fmaxf((acc[2] + wself * xf[2]) * inv + bv0.z, 0.f);
    o[3] = fmaxf((acc[3] + wself * xf[3]) * inv + bv0.w, 0.f);
    o[4] = fmaxf((acc[4] + wself * xf[4]) * inv + bv1.x, 0.f);
    o[5] = fmaxf((acc[5] + wself * xf[5]) * inv + bv1.y, 0.f);
    o[6] = fmaxf((acc[6] + wself * xf[6]) * inv + bv1.z, 0.f);
    o[7] = fmaxf((acc[7] + wself * xf[7]) * inv + bv1.w, 0.f);
    *((uint4*)Out + (long)nid * 32 + cl) = pack8(o);
  }
}

// ---------------- mu/lv aggregation + reparameterize ----------------
__global__ __launch_bounds__(256) void agg_muv_kernel(
    const unsigned short* __restrict__ Hmuv, const float* __restrict__ w2,
    const float* __restrict__ Ssm, const float* __restrict__ Sdm,
    const float* __restrict__ Ssl, const float* __restrict__ Sdl,
    const int* __restrict__ rowptr, const int* __restrict__ colv,
    const float* __restrict__ bmu, const float* __restrict__ blv,
    const float* __restrict__ epsv,
    float* __restrict__ out_mu, float* __restrict__ out_lv, float* __restrict__ out_z, int n)
{
  int gid = blockIdx.x * blockDim.x + threadIdx.x;
  int node = gid >> 5, c = gid & 31;
  if (node >= n) return;
  float wm = expf(lky(Ssm[node] + Sdm[node]));
  float wl = expf(lky(Ssl[node] + Sdl[node]));
  float summ = wm, suml = wl;
  float am = wm * bf2f(Hmuv[(long)node * 64 + c]);
  float al = wl * bf2f(Hmuv[(long)node * 64 + 32 + c]);
  int beg = rowptr[node], end = rowptr[node + 1];
  for (int jj = beg; jj < end; ++jj){
    int s = colv[jj];
    float2 wv = *(const float2*)(w2 + (long)jj * 2);
    summ += wv.x; am += wv.x * bf2f(Hmuv[(long)s * 64 + c]);
    suml += wv.y; al += wv.y * bf2f(Hmuv[(long)s * 64 + 32 + c]);
  }
  float mu = am / (summ + 1e-16f) + bmu[c];
  float lv = al / (suml + 1e-16f) + blv[c];
  float z  = mu + epsv[(long)node * 32 + c] * expf(0.5f * lv);
  out_mu[(long)node * 32 + c] = mu;
  out_lv[(long)node * 32 + c] = lv;
  out_z [(long)node * 32 + c] = z;
}

// ---------------- decoder ----------------
__global__ __launch_bounds__(256) void decoder_kernel(
    const float* __restrict__ Z, const float* __restrict__ Wfc, const float* __restrict__ bfc,
    const float* __restrict__ Wnode, const float* __restrict__ bnode,
    unsigned short* __restrict__ ZD, float* __restrict__ NF, int n)
{
  __shared__ float zs[4 * 32];
  __shared__ float zds[4 * 64];
  int t = threadIdx.x;
  int i = t >> 6, j = t & 63;
  long node = (long)blockIdx.x * 4 + i;
  if (t < 128){
    long g = (long)blockIdx.x * 128 + t;
    zs[t] = (g < (long)n * 32) ? Z[g] : 0.f;
  }
  __syncthreads();
  float acc = bfc[j];
  #pragma unroll
  for (int k = 0; k < 32; ++k) acc += zs[i * 32 + k] * Wfc[k * 64 + j];
  acc = fmaxf(acc, 0.f);
  zds[i * 64 + j] = acc;
  if (node < n) ZD[node * 64 + j] = f2bf(acc);
  __syncthreads();
  float nf = bnode[j];
  #pragma unroll
  for (int k = 0; k < 64; ++k) nf += zds[i * 64 + k] * Wnode[k * 64 + j];
  if (node < n) NF[node * 64 + j] = nf;
}

// ---------------- edge scores: 8 edges per wave, bf16 ZD ----------------
__global__ __launch_bounds__(256) void edge_score_kernel(
    const unsigned short* __restrict__ ZD, const int* __restrict__ src, const int* __restrict__ dst,
    const float* __restrict__ Wedge, const float* __restrict__ bedge,
    float* __restrict__ out_es, int E)
{
  int gid = blockIdx.x * 256 + threadIdx.x;
  int l = threadIdx.x & 63;
  int slot = l >> 3, chunk = l & 7;
  int e = (gid >> 6) * 8 + slot;
  float4 we0 = *(const float4*)(Wedge + chunk * 8);
  float4 we1 = *(const float4*)(Wedge + chunk * 8 + 4);
  float p = 0.f;
  if (e < E){
    int s = src[e], d = dst[e];
    uint4 zs_ = *((const uint4*)ZD + (long)s * 8 + chunk);
    uint4 zd_ = *((const uint4*)ZD + (long)d * 8 + chunk);
    float a[8], b[8]; unp8(zs_, a); unp8(zd_, b);
    p = a[0]*b[0]*we0.x + a[1]*b[1]*we0.y + a[2]*b[2]*we0.z + a[3]*b[3]*we0.w
      + a[4]*b[4]*we1.x + a[5]*b[5]*we1.y + a[6]*b[6]*we1.z + a[7]*b[7]*we1.w;
  }
  p += __shfl_xor(p, 1);
  p += __shfl_xor(p, 2);
  p += __shfl_xor(p, 4);
  if (chunk == 0 && e < E) out_es[e] = p + bedge[0];
}

// ---------------- launch ----------------
extern "C" void kernel_launch(void* const* d_in, const int* in_sizes, int n_in,
                              void* d_out, int out_size, void* d_ws, size_t ws_size,
                              hipStream_t stream)
{
  const float* x     = (const float*)d_in[0];
  const int*   ei    = (const int*)  d_in[1];
  const float* epsv  = (const float*)d_in[3];
  const float* W1    = (const float*)d_in[4];
  const float* as1   = (const float*)d_in[5];
  const float* ad1   = (const float*)d_in[6];
  const float* b1    = (const float*)d_in[7];
  const float* W2    = (const float*)d_in[8];
  const float* as2   = (const float*)d_in[9];
  const float* ad2   = (const float*)d_in[10];
  const float* b2    = (const float*)d_in[11];
  const float* Wmu   = (const float*)d_in[12];
  const float* asmu  = (const float*)d_in[13];
  const float* admu  = (const float*)d_in[14];
  const float* bmu   = (const float*)d_in[15];
  const float* Wlv   = (const float*)d_in[16];
  const float* aslv  = (const float*)d_in[17];
  const float* adlv  = (const float*)d_in[18];
  const float* blv   = (const float*)d_in[19];
  const float* Wfc   = (const float*)d_in[20];
  const float* bfc   = (const float*)d_in[21];
  const float* Wnode = (const float*)d_in[22];
  const float* bnode = (const float*)d_in[23];
  const float* Wedge = (const float*)d_in[24];
  const float* bedge = (const float*)d_in[25];

  const int N = in_sizes[0] / 64;
  const int E = in_sizes[1] / 2;
  const int* srcA = ei;
  const int* dstA = ei + E;

  char* wsb = (char*)d_ws;
  size_t off = 0;
  auto alloc = [&](size_t bytes) -> void* {
    void* p = wsb + off;
    off += (bytes + 255) & ~(size_t)255;
    return p;
  };
  unsigned short* xb    = (unsigned short*)alloc((size_t)N * 64 * 2);
  unsigned short* bufP  = (unsigned short*)alloc((size_t)N * 256 * 2);  // Xagg -> H2
  unsigned short* bufQ  = (unsigned short*)alloc((size_t)N * 256 * 2);  // B1 -> B2
  unsigned short* Hmuv  = (unsigned short*)alloc((size_t)N * 64 * 2);
  unsigned short* ZDb   = (unsigned short*)alloc((size_t)N * 64 * 2);
  unsigned short* W1pk  = (unsigned short*)alloc((size_t)64 * 256 * 2);
  unsigned short* W2pk  = (unsigned short*)alloc((size_t)256 * 256 * 2);
  unsigned short* Wmvpk = (unsigned short*)alloc((size_t)256 * 64 * 2);
  float* P1    = (float*)alloc(512 * 4);
  float* S1s   = (float*)alloc((size_t)N * 4 * 4);
  float* S1d   = (float*)alloc((size_t)N * 4 * 4);
  float* S2s   = (float*)alloc((size_t)N * 4 * 4);
  float* S2d   = (float*)alloc((size_t)N * 4 * 4);
  float* Ssm   = (float*)alloc((size_t)N * 4);
  float* Sdm   = (float*)alloc((size_t)N * 4);
  float* Ssl   = (float*)alloc((size_t)N * 4);
  float* Sdl   = (float*)alloc((size_t)N * 4);
  float* wbuf  = (float*)alloc((size_t)E * 4 * 4);    // w4 (L1) -> w4 (L2) -> w2
  int*   deg   = (int*)  alloc((size_t)N * 2 * 4);
  int*   cursor= deg + N;
  int*   rowptr= (int*)  alloc((size_t)(N + 1) * 4);
  int*   colv  = (int*)  alloc((size_t)E * 4);
  int*   dstv  = (int*)  alloc((size_t)E * 4);
  int*   bsum  = (int*)  alloc(1024);
  int*   boff  = (int*)  alloc(1024);
  (void)ws_size; (void)n_in; (void)out_size;

  float* out_mu = (float*)d_out;
  float* out_lv = out_mu + (size_t)N * 32;
  float* out_z  = out_lv + (size_t)N * 32;
  float* out_nf = out_z  + (size_t)N * 32;
  float* out_es = out_nf + (size_t)N * 64;

  const int nb = (N + 255) / 256;

  // CSR build
  zero_ints_kernel<<<(2 * N + 255) / 256, 256, 0, stream>>>(deg, 2 * N);
  count_deg_kernel<<<(E + 255) / 256, 256, 0, stream>>>(dstA, deg, E);
  scan_chunk_kernel<<<nb, 256, 0, stream>>>(deg, rowptr, bsum, N);
  scan_bsum_kernel<<<1, 256, 0, stream>>>(bsum, boff, nb);
  scan_add_kernel<<<nb, 256, 0, stream>>>(rowptr, boff, N);
  fill_csr_kernel<<<(E + 255) / 256, 256, 0, stream>>>(srcA, dstA, rowptr, cursor, colv, dstv, E);

  // weight packing + P1
  pack_w_kernel<<<(64 * 256 + 255) / 256, 256, 0, stream>>>(W1, nullptr, 64, 256, 256, W1pk);
  pack_w_kernel<<<(256 * 256 + 255) / 256, 256, 0, stream>>>(W2, nullptr, 256, 256, 256, W2pk);
  pack_w_kernel<<<(256 * 64 + 255) / 256, 256, 0, stream>>>(Wmu, Wlv, 256, 64, 32, Wmvpk);
  make_p1_kernel<<<2, 256, 0, stream>>>(W1, as1, ad1, P1);

  // layer 1: scores from x, aggregate x, block-diagonal GEMM (+bias+relu)
  cvt_x_kernel<<<((size_t)N * 16 + 255) / 256, 256, 0, stream>>>(x, xb, (long)N * 16);
  score1_kernel<<<(N + 255) / 256, 256, 0, stream>>>(xb, P1, S1s, S1d, N);
  edgew4_kernel<<<(E + 255) / 256, 256, 0, stream>>>(colv, dstv, S1s, S1d, wbuf, E);
  aggx_kernel<<<(N + 3) / 4, 256, 0, stream>>>(xb, wbuf, S1s, S1d, rowptr, colv, bufP, N);
  gemm_mfma_kernel<256, 64, 4, true, false, true><<<(N + 31) / 32, 256, 0, stream>>>(
      bufP, W1pk, nullptr, nullptr, nullptr, nullptr, b1, bufQ,
      nullptr, nullptr, nullptr, nullptr, N);

  // layer 2: GEMM(+scores), edge weights, aggregate(+bias+relu)
  gemm_mfma_kernel<256, 256, 4, false, true, false><<<(N + 31) / 32, 256, 0, stream>>>(
      bufQ, W2pk, as2, ad2, nullptr, nullptr, nullptr, bufP,
      S2s, S2d, nullptr, nullptr, N);
  edgew4_kernel<<<(E + 255) / 256, 256, 0, stream>>>(colv, dstv, S2s, S2d, wbuf, E);
  agg256_kernel<<<(N + 3) / 4, 256, 0, stream>>>(bufP, wbuf, S2s, S2d, rowptr, colv, b2, bufQ, N);

  // mu / logvar
  gemm_mfma_kernel<256, 256, 1, false, true, false><<<(N + 127) / 128, 256, 0, stream>>>(
      bufQ, Wmvpk, asmu, admu, aslv, adlv, nullptr, Hmuv,
      Ssm, Sdm, Ssl, Sdl, N);
  edgew2_kernel<<<(E + 255) / 256, 256, 0, stream>>>(colv, dstv, Ssm, Sdm, Ssl, Sdl, wbuf, E);
  agg_muv_kernel<<<((size_t)N * 32 + 255) / 256, 256, 0, stream>>>(
      Hmuv, wbuf, Ssm, Sdm, Ssl, Sdl, rowptr, colv, bmu, blv, epsv,
      out_mu, out_lv, out_z, N);

  // decoder
  decoder_kernel<<<(N + 3) / 4, 256, 0, stream>>>(out_z, Wfc, bfc, Wnode, bnode, ZDb, out_nf, N);
  {
    long waves = ((long)E + 7) / 8;
    long blocks = (waves + 3) / 4;
    edge_score_kernel<<<(int)blocks, 256, 0, stream>>>(ZDb, srcA, dstA, Wedge, bedge, out_es, E);
  }
}

// Round 5
// 390.216 us; speedup vs baseline: 2.1432x; 1.0742x over previous
//
#include <hip/hip_runtime.h>
#include <math.h>

#define NEG_SLOPE 0.2f

__device__ __forceinline__ float lky(float x){ return x > 0.f ? x : NEG_SLOPE * x; }

__device__ __forceinline__ unsigned short f2bf(float f){
  unsigned int u = __float_as_uint(f);
  unsigned int r = (u + 0x7fffu + ((u >> 16) & 1u)) >> 16;
  return (unsigned short)r;
}
__device__ __forceinline__ float bf2f(unsigned short s){
  return __uint_as_float(((unsigned int)s) << 16);
}
__device__ __forceinline__ void unp8(uint4 v, float* f){
  f[0]=__uint_as_float(v.x<<16); f[1]=__uint_as_float(v.x&0xffff0000u);
  f[2]=__uint_as_float(v.y<<16); f[3]=__uint_as_float(v.y&0xffff0000u);
  f[4]=__uint_as_float(v.z<<16); f[5]=__uint_as_float(v.z&0xffff0000u);
  f[6]=__uint_as_float(v.w<<16); f[7]=__uint_as_float(v.w&0xffff0000u);
}
__device__ __forceinline__ uint4 pack8(const float* o){
  uint4 v;
  v.x = (unsigned)f2bf(o[0]) | ((unsigned)f2bf(o[1])<<16);
  v.y = (unsigned)f2bf(o[2]) | ((unsigned)f2bf(o[3])<<16);
  v.z = (unsigned)f2bf(o[4]) | ((unsigned)f2bf(o[5])<<16);
  v.w = (unsigned)f2bf(o[6]) | ((unsigned)f2bf(o[7])<<16);
  return v;
}

typedef __bf16 bf16x8 __attribute__((ext_vector_type(8)));
typedef float  f32x4  __attribute__((ext_vector_type(4)));

// ---------------- CSR build ----------------
__global__ void zero_ints_kernel(int* __restrict__ p, int n){
  int i = blockIdx.x * blockDim.x + threadIdx.x;
  if (i < n) p[i] = 0;
}
__global__ void count_deg_kernel(const int* __restrict__ dst, int* __restrict__ deg, int E){
  int e = blockIdx.x * blockDim.x + threadIdx.x;
  if (e < E) atomicAdd(&deg[dst[e]], 1);
}
__global__ void scan_chunk_kernel(const int* __restrict__ deg, int* __restrict__ rowptr,
                                  int* __restrict__ bsum, int n){
  __shared__ int s[256];
  int t = threadIdx.x;
  int i = blockIdx.x * 256 + t;
  int v = (i < n) ? deg[i] : 0;
  s[t] = v; __syncthreads();
  for (int off = 1; off < 256; off <<= 1){
    int x = (t >= off) ? s[t - off] : 0;
    __syncthreads();
    s[t] += x;
    __syncthreads();
  }
  if (i < n) rowptr[i + 1] = s[t];
  if (t == 255) bsum[blockIdx.x] = s[255];
}
__global__ void scan_bsum_kernel(const int* __restrict__ bsum, int* __restrict__ boff, int nb){
  __shared__ int s[256];
  int t = threadIdx.x;
  int v = (t < nb) ? bsum[t] : 0;
  s[t] = v; __syncthreads();
  for (int off = 1; off < 256; off <<= 1){
    int x = (t >= off) ? s[t - off] : 0;
    __syncthreads();
    s[t] += x;
    __syncthreads();
  }
  boff[t] = s[t] - v;
}
__global__ void scan_add_kernel(int* __restrict__ rowptr, const int* __restrict__ boff, int n){
  int i = blockIdx.x * 256 + threadIdx.x;
  if (i < n) rowptr[i + 1] += boff[blockIdx.x];
  if (i == 0) rowptr[0] = 0;
}
__global__ void fill_csr_kernel(const int* __restrict__ src, const int* __restrict__ dst,
                                const int* __restrict__ rowptr, int* __restrict__ cursor,
                                int* __restrict__ colv, int* __restrict__ dstv, int E){
  int e = blockIdx.x * blockDim.x + threadIdx.x;
  if (e >= E) return;
  int d = dst[e];
  int pos = atomicAdd(&cursor[d], 1);
  colv[rowptr[d] + pos] = src[e];
  dstv[rowptr[d] + pos] = d;
}

// ---------------- weight pack: fp32 [K][M] -> bf16 B-fragment layout ----------------
__global__ void pack_w_kernel(const float* __restrict__ Wa, const float* __restrict__ Wb,
                              int K, int M, int Mhalf, unsigned short* __restrict__ out){
  int idx = blockIdx.x * 256 + threadIdx.x;
  if (idx >= K * M) return;
  int j = idx & 7;
  int l = (idx >> 3) & 63;
  int rest = idx >> 9;
  int KS = K >> 5;
  int s = rest % KS, gct = rest / KS;
  int col = gct * 16 + (l & 15);
  int k   = s * 32 + ((l >> 4) << 3) + j;
  float v;
  if (Wb == nullptr) v = Wa[(long)k * M + col];
  else v = (col < Mhalf) ? Wa[(long)k * Mhalf + col] : Wb[(long)k * Mhalf + (col - Mhalf)];
  out[idx] = f2bf(v);
}

// ---------------- x fp32 -> bf16 ----------------
__global__ void cvt_x_kernel(const float* __restrict__ x, unsigned short* __restrict__ xb, long n4){
  long i = (long)blockIdx.x * 256 + threadIdx.x;
  if (i >= n4) return;
  float4 v = ((const float4*)x)[i];
  uint2 o;
  o.x = (unsigned)f2bf(v.x) | ((unsigned)f2bf(v.y) << 16);
  o.y = (unsigned)f2bf(v.z) | ((unsigned)f2bf(v.w) << 16);
  ((uint2*)xb)[i] = o;
}

// ---------------- P1 = W1 @ a (64 x 4 x {src,dst}) ----------------
__global__ void make_p1_kernel(const float* __restrict__ W1, const float* __restrict__ as1,
                               const float* __restrict__ ad1, float* __restrict__ P1){
  int idx = blockIdx.x * 256 + threadIdx.x;
  if (idx >= 512) return;
  int sd = idx & 1, h = (idx >> 1) & 3, k = idx >> 3;
  const float* av = sd ? ad1 : as1;
  float acc = 0.f;
  for (int c = 0; c < 64; ++c) acc += W1[k * 256 + h * 64 + c] * av[h * 64 + c];
  P1[idx] = acc;
}

// ---------------- layer-1 scores: S1 = xb @ P1 ----------------
__global__ __launch_bounds__(256) void score1_kernel(
    const unsigned short* __restrict__ xb, const float* __restrict__ P1,
    float* __restrict__ S1s, float* __restrict__ S1d, int n)
{
  __shared__ float P[512];
  int t = threadIdx.x;
  P[t] = P1[t]; P[t + 256] = P1[t + 256];
  __syncthreads();
  int nid = blockIdx.x * 256 + t;
  if (nid >= n) return;
  float acc[8] = {0,0,0,0,0,0,0,0};
  const uint4* xr = (const uint4*)xb + (long)nid * 8;
  for (int kc = 0; kc < 8; ++kc){
    uint4 v = xr[kc];
    float xf[8]; unp8(v, xf);
    #pragma unroll
    for (int j = 0; j < 8; ++j){
      int k = kc * 8 + j;
      #pragma unroll
      for (int o = 0; o < 8; ++o) acc[o] += xf[j] * P[k * 8 + o];
    }
  }
  *(float4*)(S1s + nid * 4) = make_float4(acc[0], acc[2], acc[4], acc[6]);
  *(float4*)(S1d + nid * 4) = make_float4(acc[1], acc[3], acc[5], acc[7]);
}

// ---------------- edge softmax weights (precomputed) ----------------
__global__ void edgew4_kernel(const int* __restrict__ colv, const int* __restrict__ dstv,
                              const float* __restrict__ Ss, const float* __restrict__ Sd,
                              float* __restrict__ w4, int E){
  int e = blockIdx.x * 256 + threadIdx.x;
  if (e >= E) return;
  int s = colv[e], d = dstv[e];
  float4 a = *(const float4*)(Ss + (long)s * 4);
  float4 b = *(const float4*)(Sd + (long)d * 4);
  *(float4*)(w4 + (long)e * 4) = make_float4(
      expf(lky(a.x + b.x)), expf(lky(a.y + b.y)),
      expf(lky(a.z + b.z)), expf(lky(a.w + b.w)));
}
__global__ void edgew2_kernel(const int* __restrict__ colv, const int* __restrict__ dstv,
                              const float* __restrict__ Ssm, const float* __restrict__ Sdm,
                              const float* __restrict__ Ssl, const float* __restrict__ Sdl,
                              float* __restrict__ w2, int E){
  int e = blockIdx.x * 256 + threadIdx.x;
  if (e >= E) return;
  int s = colv[e], d = dstv[e];
  float wm = expf(lky(Ssm[s] + Sdm[d]));
  float wl = expf(lky(Ssl[s] + Sdl[d]));
  *(float2*)(w2 + (long)e * 2) = make_float2(wm, wl);
}

// ---------------- layer-1 aggregation of x: one wave per node, 2 edges in flight ----
__global__ __launch_bounds__(256) void aggx_kernel(
    const unsigned short* __restrict__ xb, const float* __restrict__ w4,
    const float* __restrict__ Ss, const float* __restrict__ Sd,
    const int* __restrict__ rowptr, const int* __restrict__ colv,
    unsigned short* __restrict__ Xagg, int n)
{
  int wv = threadIdx.x >> 6, l = threadIdx.x & 63;
  int nid = blockIdx.x * 4 + wv;
  if (nid >= n) return;
  int slot = l >> 5;
  int cl = l & 31;
  float acc[4][2] = {};
  float sumw[4] = {0.f, 0.f, 0.f, 0.f};
  int beg = rowptr[nid], end = rowptr[nid + 1];
  for (int jj = beg + slot; jj < end; jj += 2){
    int s = colv[jj];
    float4 wt = *(const float4*)(w4 + (long)jj * 4);
    unsigned xv = *((const unsigned*)xb + (long)s * 32 + cl);
    float f0 = __uint_as_float(xv << 16);
    float f1 = __uint_as_float(xv & 0xffff0000u);
    acc[0][0] += wt.x * f0; acc[0][1] += wt.x * f1;
    acc[1][0] += wt.y * f0; acc[1][1] += wt.y * f1;
    acc[2][0] += wt.z * f0; acc[2][1] += wt.z * f1;
    acc[3][0] += wt.w * f0; acc[3][1] += wt.w * f1;
    sumw[0] += wt.x; sumw[1] += wt.y; sumw[2] += wt.z; sumw[3] += wt.w;
  }
  #pragma unroll
  for (int h = 0; h < 4; ++h){
    acc[h][0] += __shfl_xor(acc[h][0], 32);
    acc[h][1] += __shfl_xor(acc[h][1], 32);
    sumw[h]   += __shfl_xor(sumw[h], 32);
  }
  float4 ssv = *(const float4*)(Ss + (long)nid * 4);
  float4 sdv = *(const float4*)(Sd + (long)nid * 4);
  unsigned xv = *((const unsigned*)xb + (long)nid * 32 + cl);
  float f0 = __uint_as_float(xv << 16);
  float f1 = __uint_as_float(xv & 0xffff0000u);
  float wsh[4] = { expf(lky(ssv.x + sdv.x)), expf(lky(ssv.y + sdv.y)),
                   expf(lky(ssv.z + sdv.z)), expf(lky(ssv.w + sdv.w)) };
  if (l < 32){
    #pragma unroll
    for (int h = 0; h < 4; ++h){
      float inv = 1.f / (sumw[h] + wsh[h] + 1e-16f);
      float o0 = (acc[h][0] + wsh[h] * f0) * inv;
      float o1 = (acc[h][1] + wsh[h] * f1) * inv;
      unsigned ov = (unsigned)f2bf(o0) | ((unsigned)f2bf(o1) << 16);
      *((unsigned*)Xagg + (long)nid * 128 + h * 32 + cl) = ov;
    }
  }
}

// ---------------- MFMA GEMM (optionally block-diagonal) + fused scores/relu ----------------
template<int K, int KB, int CW, bool BD, bool SCORES, bool RELU>
__global__ __launch_bounds__(256) void gemm_mfma_kernel(
    const unsigned short* __restrict__ Xb, const unsigned short* __restrict__ Wpk,
    const float* __restrict__ a_s, const float* __restrict__ a_d,
    const float* __restrict__ a_s2, const float* __restrict__ a_d2,
    const float* __restrict__ bias,
    unsigned short* __restrict__ Hout,
    float* __restrict__ Ss, float* __restrict__ Sd,
    float* __restrict__ Ss2, float* __restrict__ Sd2, int n)
{
  constexpr int BR  = (CW == 4) ? 32 : 128;
  constexpr int M   = 64 * CW;
  constexpr int KSB = KB / 32;
  constexpr int LDA = K + 8;
  constexpr int SH  = (BR * LDA > BR * M) ? BR * LDA : BR * M;
  __shared__ unsigned short As[SH];

  const int t = threadIdx.x;
  const int w = t >> 6, l = t & 63;
  const int quad = l >> 4, l15 = l & 15;
  const long base = (long)blockIdx.x * BR;
  const int roww = (CW == 4) ? 0 : w;
  const int colw = (CW == 4) ? w : 0;
  const int abase = BD ? w * KB : 0;

  {
    const uint4* Xg = (const uint4*)Xb;
    long g0 = base * (K / 8);
    long lim = (long)n * (K / 8);
    for (int c = t; c < BR * K / 8; c += 256){
      int row = c / (K / 8), kc = c % (K / 8);
      uint4 v = make_uint4(0u, 0u, 0u, 0u);
      if (g0 + c < lim) v = Xg[g0 + c];
      *(uint4*)(As + row * LDA + kc * 8) = v;
    }
  }
  __syncthreads();

  f32x4 acc[2][4] = {};
  for (int s = 0; s < KSB; ++s){
    bf16x8 af0 = *(const bf16x8*)(As + (roww * 32 + 0  + l15) * LDA + abase + s * 32 + quad * 8);
    bf16x8 af1 = *(const bf16x8*)(As + (roww * 32 + 16 + l15) * LDA + abase + s * 32 + quad * 8);
    #pragma unroll
    for (int ct = 0; ct < 4; ++ct){
      int gct = colw * 4 + ct;
      bf16x8 bf = *(const bf16x8*)(Wpk + (((long)gct * KSB + s) * 64 + l) * 8);
      acc[0][ct] = __builtin_amdgcn_mfma_f32_16x16x32_bf16(af0, bf, acc[0][ct], 0, 0, 0);
      acc[1][ct] = __builtin_amdgcn_mfma_f32_16x16x32_bf16(af1, bf, acc[1][ct], 0, 0, 0);
    }
  }

  if constexpr (SCORES){
    if (CW == 4){
      const int head = w;
      float asv[4], adv[4];
      #pragma unroll
      for (int ct = 0; ct < 4; ++ct){
        int col = head * 64 + ct * 16 + l15;
        asv[ct] = a_s[col]; adv[ct] = a_d[col];
      }
      #pragma unroll
      for (int rt = 0; rt < 2; ++rt){
        #pragma unroll
        for (int r = 0; r < 4; ++r){
          float ps = 0.f, pd = 0.f;
          #pragma unroll
          for (int ct = 0; ct < 4; ++ct){
            float v = acc[rt][ct][r];
            ps += v * asv[ct]; pd += v * adv[ct];
          }
          ps += __shfl_xor(ps, 8); pd += __shfl_xor(pd, 8);
          ps += __shfl_xor(ps, 4); pd += __shfl_xor(pd, 4);
          ps += __shfl_xor(ps, 2); pd += __shfl_xor(pd, 2);
          ps += __shfl_xor(ps, 1); pd += __shfl_xor(pd, 1);
          long node = base + rt * 16 + quad * 4 + r;
          if (l15 == 0 && node < n){ Ss[node * 4 + head] = ps; Sd[node * 4 + head] = pd; }
        }
      }
    } else {
      float asm_[2], adm_[2], asl_[2], adl_[2];
      #pragma unroll
      for (int ct = 0; ct < 2; ++ct){
        int col = ct * 16 + l15;
        asm_[ct] = a_s[col];  adm_[ct] = a_d[col];
        asl_[ct] = a_s2[col]; adl_[ct] = a_d2[col];
      }
      #pragma unroll
      for (int rt = 0; rt < 2; ++rt){
        #pragma unroll
        for (int r = 0; r < 4; ++r){
          float psm = 0.f, pdm = 0.f, psl = 0.f, pdl = 0.f;
          #pragma unroll
          for (int ct = 0; ct < 2; ++ct){
            float vm = acc[rt][ct][r];
            float vl = acc[rt][ct + 2][r];
            psm += vm * asm_[ct]; pdm += vm * adm_[ct];
            psl += vl * asl_[ct]; pdl += vl * adl_[ct];
          }
          #pragma unroll
          for (int d = 8; d >= 1; d >>= 1){
            psm += __shfl_xor(psm, d); pdm += __shfl_xor(pdm, d);
            psl += __shfl_xor(psl, d); pdl += __shfl_xor(pdl, d);
          }
          long node = base + w * 32 + rt * 16 + quad * 4 + r;
          if (l15 == 0 && node < n){
            Ss[node]  = psm; Sd[node]  = pdm;
            Ss2[node] = psl; Sd2[node] = pdl;
          }
        }
      }
    }
  }

  __syncthreads();
  float bct[4] = {0.f, 0.f, 0.f, 0.f};
  if constexpr (RELU){
    #pragma unroll
    for (int ct = 0; ct < 4; ++ct) bct[ct] = bias[colw * 64 + ct * 16 + l15];
  }
  #pragma unroll
  for (int rt = 0; rt < 2; ++rt){
    #pragma unroll
    for (int ct = 0; ct < 4; ++ct){
      #pragma unroll
      for (int r = 0; r < 4; ++r){
        int row = roww * 32 + rt * 16 + quad * 4 + r;
        int col = colw * 64 + ct * 16 + l15;
        float o = acc[rt][ct][r];
        if constexpr (RELU) o = fmaxf(o + bct[ct], 0.f);
        As[row * M + col] = f2bf(o);
      }
    }
  }
  __syncthreads();
  {
    uint4* Hg = (uint4*)Hout;
    for (int c = t; c < BR * M / 8; c += 256){
      int row = c / (M / 8);
      if (base + row < n) Hg[base * (M / 8) + c] = *(const uint4*)(As + c * 8);
    }
  }
}

// ---------------- layer-2 aggregation: one wave per node, 2 edges in flight ----------------
__global__ __launch_bounds__(256) void agg256_kernel(
    const unsigned short* __restrict__ Hbuf, const float* __restrict__ w4,
    const float* __restrict__ Ss, const float* __restrict__ Sd,
    const int* __restrict__ rowptr, const int* __restrict__ colv,
    const float* __restrict__ bias, unsigned short* __restrict__ Out, int n)
{
  int wv = threadIdx.x >> 6, l = threadIdx.x & 63;
  int nid = blockIdx.x * 4 + wv;
  if (nid >= n) return;
  int slot = l >> 5;
  int cl = l & 31;
  int head = cl >> 3;
  float acc[8] = {0,0,0,0,0,0,0,0};
  float sumw = 0.f;
  int beg = rowptr[nid], end = rowptr[nid + 1];
  for (int jj = beg + slot; jj < end; jj += 2){
    int s = colv[jj];
    float wt = w4[(long)jj * 4 + head];
    uint4 hv = *((const uint4*)Hbuf + (long)s * 32 + cl);
    float xf[8]; unp8(hv, xf);
    #pragma unroll
    for (int j = 0; j < 8; ++j) acc[j] += wt * xf[j];
    sumw += wt;
  }
  #pragma unroll
  for (int j = 0; j < 8; ++j) acc[j] += __shfl_xor(acc[j], 32);
  sumw += __shfl_xor(sumw, 32);
  float wself = expf(lky(Ss[(long)nid * 4 + head] + Sd[(long)nid * 4 + head]));
  uint4 hv = *((const uint4*)Hbuf + (long)nid * 32 + cl);
  float xf[8]; unp8(hv, xf);
  if (l < 32){
    float inv = 1.f / (sumw + wself + 1e-16f);
    float4 bv0 = *(const float4*)(bias + cl * 8);
    float4 bv1 = *(const float4*)(bias + cl * 8 + 4);
    float o[8];
    o[0] = fmaxf((acc[0] + wself * xf[0]) * inv + bv0.x, 0.f);
    o[1] = fmaxf((acc[1] + wself * xf[1]) * inv + bv0.y, 0.f);
    o[2] = fmaxf((acc[2] + wself * xf[2]) * inv + bv0.z, 0.f);
    o[3] = fmaxf((acc[3] + wself * xf[3]) * inv + bv0.w, 0.f);
    o[4] = fmaxf((acc[4] + wself * xf[4]) * inv + bv1.x, 0.f);
    o[5] = fmaxf((acc[5] + wself * xf[5]) * inv + bv1.y, 0.f);
    o[6] = fmaxf((acc[6] + wself * xf[6]) * inv + bv1.z, 0.f);
    o[7] = fmaxf((acc[7] + wself * xf[7]) * inv + bv1.w, 0.f);
    *((uint4*)Out + (long)nid * 32 + cl) = pack8(o);
  }
}

// ---------------- mu/lv aggregation + reparameterize (also writes z as bf16) ----------------
__global__ __launch_bounds__(256) void agg_muv_kernel(
    const unsigned short* __restrict__ Hmuv, const float* __restrict__ w2,
    const float* __restrict__ Ssm, const float* __restrict__ Sdm,
    const float* __restrict__ Ssl, const float* __restrict__ Sdl,
    const int* __restrict__ rowptr, const int* __restrict__ colv,
    const float* __restrict__ bmu, const float* __restrict__ blv,
    const float* __restrict__ epsv,
    float* __restrict__ out_mu, float* __restrict__ out_lv, float* __restrict__ out_z,
    unsigned short* __restrict__ zb, int n)
{
  int gid = blockIdx.x * blockDim.x + threadIdx.x;
  int node = gid >> 5, c = gid & 31;
  if (node >= n) return;
  float wm = expf(lky(Ssm[node] + Sdm[node]));
  float wl = expf(lky(Ssl[node] + Sdl[node]));
  float summ = wm, suml = wl;
  float am = wm * bf2f(Hmuv[(long)node * 64 + c]);
  float al = wl * bf2f(Hmuv[(long)node * 64 + 32 + c]);
  int beg = rowptr[node], end = rowptr[node + 1];
  for (int jj = beg; jj < end; ++jj){
    int s = colv[jj];
    float2 wv = *(const float2*)(w2 + (long)jj * 2);
    summ += wv.x; am += wv.x * bf2f(Hmuv[(long)s * 64 + c]);
    suml += wv.y; al += wv.y * bf2f(Hmuv[(long)s * 64 + 32 + c]);
  }
  float mu = am / (summ + 1e-16f) + bmu[c];
  float lv = al / (suml + 1e-16f) + blv[c];
  float z  = mu + epsv[(long)node * 32 + c] * expf(0.5f * lv);
  out_mu[(long)node * 32 + c] = mu;
  out_lv[(long)node * 32 + c] = lv;
  out_z [(long)node * 32 + c] = z;
  zb[(long)node * 32 + c] = f2bf(z);
}

// ---------------- decoder: MFMA fused zd=relu(z@Wfc+bfc); nf=zd@Wnode+bnode ----------------
// block = 128 nodes, wave w -> rows [w*32, +32)
__global__ __launch_bounds__(256) void decoder_mfma_kernel(
    const unsigned short* __restrict__ zb,
    const unsigned short* __restrict__ Wfcpk, const float* __restrict__ bfc,
    const unsigned short* __restrict__ Wndpk, const float* __restrict__ bnode,
    unsigned short* __restrict__ ZD, float* __restrict__ NF, int n)
{
  constexpr int LDA = 40;   // 32 + 8
  constexpr int LDZ = 72;   // 64 + 8
  __shared__ unsigned short As[128 * LDA];
  __shared__ unsigned short Zs[128 * LDZ];
  const int t = threadIdx.x;
  const int w = t >> 6, l = t & 63;
  const int quad = l >> 4, l15 = l & 15;
  const long base = (long)blockIdx.x * 128;

  {
    const uint4* Zg = (const uint4*)zb;
    long g0 = base * 4;
    long lim = (long)n * 4;
    for (int c = t; c < 512; c += 256){
      int row = c >> 2, kc = c & 3;
      uint4 v = make_uint4(0u, 0u, 0u, 0u);
      if (g0 + c < lim) v = Zg[g0 + c];
      *(uint4*)(As + row * LDA + kc * 8) = v;
    }
  }
  __syncthreads();

  // phase 1: K=32 -> 64 cols (zd)
  f32x4 acc[2][4] = {};
  {
    bf16x8 af0 = *(const bf16x8*)(As + (w * 32 + 0  + l15) * LDA + quad * 8);
    bf16x8 af1 = *(const bf16x8*)(As + (w * 32 + 16 + l15) * LDA + quad * 8);
    #pragma unroll
    for (int ct = 0; ct < 4; ++ct){
      bf16x8 bf = *(const bf16x8*)(Wfcpk + (((long)ct) * 64 + l) * 8);
      acc[0][ct] = __builtin_amdgcn_mfma_f32_16x16x32_bf16(af0, bf, acc[0][ct], 0, 0, 0);
      acc[1][ct] = __builtin_amdgcn_mfma_f32_16x16x32_bf16(af1, bf, acc[1][ct], 0, 0, 0);
    }
  }
  #pragma unroll
  for (int rt = 0; rt < 2; ++rt){
    #pragma unroll
    for (int ct = 0; ct < 4; ++ct){
      float b = bfc[ct * 16 + l15];
      #pragma unroll
      for (int r = 0; r < 4; ++r){
        int row = w * 32 + rt * 16 + quad * 4 + r;
        Zs[row * LDZ + ct * 16 + l15] = f2bf(fmaxf(acc[rt][ct][r] + b, 0.f));
      }
    }
  }
  __syncthreads();

  // write ZD (bf16) coalesced from Zs
  {
    uint4* Zgo = (uint4*)ZD;
    for (int c = t; c < 1024; c += 256){
      int row = c >> 3, kc = c & 7;
      if (base + row < n) Zgo[base * 8 + c] = *(const uint4*)(Zs + row * LDZ + kc * 8);
    }
  }

  // phase 2: K=64 -> 64 cols (nf), fp32 out
  f32x4 acc2[2][4] = {};
  #pragma unroll
  for (int s = 0; s < 2; ++s){
    bf16x8 af0 = *(const bf16x8*)(Zs + (w * 32 + 0  + l15) * LDZ + s * 32 + quad * 8);
    bf16x8 af1 = *(const bf16x8*)(Zs + (w * 32 + 16 + l15) * LDZ + s * 32 + quad * 8);
    #pragma unroll
    for (int ct = 0; ct < 4; ++ct){
      bf16x8 bf = *(const bf16x8*)(Wndpk + (((long)ct * 2 + s) * 64 + l) * 8);
      acc2[0][ct] = __builtin_amdgcn_mfma_f32_16x16x32_bf16(af0, bf, acc2[0][ct], 0, 0, 0);
      acc2[1][ct] = __builtin_amdgcn_mfma_f32_16x16x32_bf16(af1, bf, acc2[1][ct], 0, 0, 0);
    }
  }
  #pragma unroll
  for (int rt = 0; rt < 2; ++rt){
    #pragma unroll
    for (int ct = 0; ct < 4; ++ct){
      float b = bnode[ct * 16 + l15];
      #pragma unroll
      for (int r = 0; r < 4; ++r){
        long row = base + w * 32 + rt * 16 + quad * 4 + r;
        if (row < n) NF[row * 64 + ct * 16 + l15] = acc2[rt][ct][r] + b;
      }
    }
  }
}

// ---------------- edge scores: 8 edges per wave, bf16 ZD ----------------
__global__ __launch_bounds__(256) void edge_score_kernel(
    const unsigned short* __restrict__ ZD, const int* __restrict__ src, const int* __restrict__ dst,
    const float* __restrict__ Wedge, const float* __restrict__ bedge,
    float* __restrict__ out_es, int E)
{
  int gid = blockIdx.x * 256 + threadIdx.x;
  int l = threadIdx.x & 63;
  int slot = l >> 3, chunk = l & 7;
  int e = (gid >> 6) * 8 + slot;
  float4 we0 = *(const float4*)(Wedge + chunk * 8);
  float4 we1 = *(const float4*)(Wedge + chunk * 8 + 4);
  float p = 0.f;
  if (e < E){
    int s = src[e], d = dst[e];
    uint4 zs_ = *((const uint4*)ZD + (long)s * 8 + chunk);
    uint4 zd_ = *((const uint4*)ZD + (long)d * 8 + chunk);
    float a[8], b[8]; unp8(zs_, a); unp8(zd_, b);
    p = a[0]*b[0]*we0.x + a[1]*b[1]*we0.y + a[2]*b[2]*we0.z + a[3]*b[3]*we0.w
      + a[4]*b[4]*we1.x + a[5]*b[5]*we1.y + a[6]*b[6]*we1.z + a[7]*b[7]*we1.w;
  }
  p += __shfl_xor(p, 1);
  p += __shfl_xor(p, 2);
  p += __shfl_xor(p, 4);
  if (chunk == 0 && e < E) out_es[e] = p + bedge[0];
}

// ---------------- launch ----------------
extern "C" void kernel_launch(void* const* d_in, const int* in_sizes, int n_in,
                              void* d_out, int out_size, void* d_ws, size_t ws_size,
                              hipStream_t stream)
{
  const float* x     = (const float*)d_in[0];
  const int*   ei    = (const int*)  d_in[1];
  const float* epsv  = (const float*)d_in[3];
  const float* W1    = (const float*)d_in[4];
  const float* as1   = (const float*)d_in[5];
  const float* ad1   = (const float*)d_in[6];
  const float* b1    = (const float*)d_in[7];
  const float* W2    = (const float*)d_in[8];
  const float* as2   = (const float*)d_in[9];
  const float* ad2   = (const float*)d_in[10];
  const float* b2    = (const float*)d_in[11];
  const float* Wmu   = (const float*)d_in[12];
  const float* asmu  = (const float*)d_in[13];
  const float* admu  = (const float*)d_in[14];
  const float* bmu   = (const float*)d_in[15];
  const float* Wlv   = (const float*)d_in[16];
  const float* aslv  = (const float*)d_in[17];
  const float* adlv  = (const float*)d_in[18];
  const float* blv   = (const float*)d_in[19];
  const float* Wfc   = (const float*)d_in[20];
  const float* bfc   = (const float*)d_in[21];
  const float* Wnode = (const float*)d_in[22];
  const float* bnode = (const float*)d_in[23];
  const float* Wedge = (const float*)d_in[24];
  const float* bedge = (const float*)d_in[25];

  const int N = in_sizes[0] / 64;
  const int E = in_sizes[1] / 2;
  const int* srcA = ei;
  const int* dstA = ei + E;

  char* wsb = (char*)d_ws;
  size_t off = 0;
  auto alloc = [&](size_t bytes) -> void* {
    void* p = wsb + off;
    off += (bytes + 255) & ~(size_t)255;
    return p;
  };
  unsigned short* xb    = (unsigned short*)alloc((size_t)N * 64 * 2);
  unsigned short* bufP  = (unsigned short*)alloc((size_t)N * 256 * 2);  // Xagg -> H2
  unsigned short* bufQ  = (unsigned short*)alloc((size_t)N * 256 * 2);  // B1 -> B2
  unsigned short* Hmuv  = (unsigned short*)alloc((size_t)N * 64 * 2);
  unsigned short* ZDb   = (unsigned short*)alloc((size_t)N * 64 * 2);
  unsigned short* zbb   = (unsigned short*)alloc((size_t)N * 32 * 2);
  unsigned short* W1pk  = (unsigned short*)alloc((size_t)64 * 256 * 2);
  unsigned short* W2pk  = (unsigned short*)alloc((size_t)256 * 256 * 2);
  unsigned short* Wmvpk = (unsigned short*)alloc((size_t)256 * 64 * 2);
  unsigned short* Wfcpk = (unsigned short*)alloc((size_t)32 * 64 * 2);
  unsigned short* Wndpk = (unsigned short*)alloc((size_t)64 * 64 * 2);
  float* P1    = (float*)alloc(512 * 4);
  float* S1s   = (float*)alloc((size_t)N * 4 * 4);
  float* S1d   = (float*)alloc((size_t)N * 4 * 4);
  float* S2s   = (float*)alloc((size_t)N * 4 * 4);
  float* S2d   = (float*)alloc((size_t)N * 4 * 4);
  float* Ssm   = (float*)alloc((size_t)N * 4);
  float* Sdm   = (float*)alloc((size_t)N * 4);
  float* Ssl   = (float*)alloc((size_t)N * 4);
  float* Sdl   = (float*)alloc((size_t)N * 4);
  float* wbuf  = (float*)alloc((size_t)E * 4 * 4);
  int*   deg   = (int*)  alloc((size_t)N * 2 * 4);
  int*   cursor= deg + N;
  int*   rowptr= (int*)  alloc((size_t)(N + 1) * 4);
  int*   colv  = (int*)  alloc((size_t)E * 4);
  int*   dstv  = (int*)  alloc((size_t)E * 4);
  int*   bsum  = (int*)  alloc(1024);
  int*   boff  = (int*)  alloc(1024);
  (void)ws_size; (void)n_in; (void)out_size;

  float* out_mu = (float*)d_out;
  float* out_lv = out_mu + (size_t)N * 32;
  float* out_z  = out_lv + (size_t)N * 32;
  float* out_nf = out_z  + (size_t)N * 32;
  float* out_es = out_nf + (size_t)N * 64;

  const int nb = (N + 255) / 256;

  // CSR build
  zero_ints_kernel<<<(2 * N + 255) / 256, 256, 0, stream>>>(deg, 2 * N);
  count_deg_kernel<<<(E + 255) / 256, 256, 0, stream>>>(dstA, deg, E);
  scan_chunk_kernel<<<nb, 256, 0, stream>>>(deg, rowptr, bsum, N);
  scan_bsum_kernel<<<1, 256, 0, stream>>>(bsum, boff, nb);
  scan_add_kernel<<<nb, 256, 0, stream>>>(rowptr, boff, N);
  fill_csr_kernel<<<(E + 255) / 256, 256, 0, stream>>>(srcA, dstA, rowptr, cursor, colv, dstv, E);

  // weight packing + P1
  pack_w_kernel<<<(64 * 256 + 255) / 256, 256, 0, stream>>>(W1, nullptr, 64, 256, 256, W1pk);
  pack_w_kernel<<<(256 * 256 + 255) / 256, 256, 0, stream>>>(W2, nullptr, 256, 256, 256, W2pk);
  pack_w_kernel<<<(256 * 64 + 255) / 256, 256, 0, stream>>>(Wmu, Wlv, 256, 64, 32, Wmvpk);
  pack_w_kernel<<<(32 * 64 + 255) / 256, 256, 0, stream>>>(Wfc, nullptr, 32, 64, 64, Wfcpk);
  pack_w_kernel<<<(64 * 64 + 255) / 256, 256, 0, stream>>>(Wnode, nullptr, 64, 64, 64, Wndpk);
  make_p1_kernel<<<2, 256, 0, stream>>>(W1, as1, ad1, P1);

  // layer 1: scores from x, aggregate x, block-diagonal GEMM (+bias+relu)
  cvt_x_kernel<<<((size_t)N * 16 + 255) / 256, 256, 0, stream>>>(x, xb, (long)N * 16);
  score1_kernel<<<(N + 255) / 256, 256, 0, stream>>>(xb, P1, S1s, S1d, N);
  edgew4_kernel<<<(E + 255) / 256, 256, 0, stream>>>(colv, dstv, S1s, S1d, wbuf, E);
  aggx_kernel<<<(N + 3) / 4, 256, 0, stream>>>(xb, wbuf, S1s, S1d, rowptr, colv, bufP, N);
  gemm_mfma_kernel<256, 64, 4, true, false, true><<<(N + 31) / 32, 256, 0, stream>>>(
      bufP, W1pk, nullptr, nullptr, nullptr, nullptr, b1, bufQ,
      nullptr, nullptr, nullptr, nullptr, N);

  // layer 2: GEMM(+scores), edge weights, aggregate(+bias+relu)
  gemm_mfma_kernel<256, 256, 4, false, true, false><<<(N + 31) / 32, 256, 0, stream>>>(
      bufQ, W2pk, as2, ad2, nullptr, nullptr, nullptr, bufP,
      S2s, S2d, nullptr, nullptr, N);
  edgew4_kernel<<<(E + 255) / 256, 256, 0, stream>>>(colv, dstv, S2s, S2d, wbuf, E);
  agg256_kernel<<<(N + 3) / 4, 256, 0, stream>>>(bufP, wbuf, S2s, S2d, rowptr, colv, b2, bufQ, N);

  // mu / logvar
  gemm_mfma_kernel<256, 256, 1, false, true, false><<<(N + 127) / 128, 256, 0, stream>>>(
      bufQ, Wmvpk, asmu, admu, aslv, adlv, nullptr, Hmuv,
      Ssm, Sdm, Ssl, Sdl, N);
  edgew2_kernel<<<(E + 255) / 256, 256, 0, stream>>>(colv, dstv, Ssm, Sdm, Ssl, Sdl, wbuf, E);
  agg_muv_kernel<<<((size_t)N * 32 + 255) / 256, 256, 0, stream>>>(
      Hmuv, wbuf, Ssm, Sdm, Ssl, Sdl, rowptr, colv, bmu, blv, epsv,
      out_mu, out_lv, out_z, zbb, N);

  // decoder (MFMA fused)
  decoder_mfma_kernel<<<(N + 127) / 128, 256, 0, stream>>>(
      zbb, Wfcpk, bfc, Wndpk, bnode, ZDb, out_nf, N);
  {
    long waves = ((long)E + 7) / 8;
    long blocks = (waves + 3) / 4;
    edge_score_kernel<<<(int)blocks, 256, 0, stream>>>(ZDb, srcA, dstA, Wedge, bedge, out_es, E);
  }
}

// Round 6
// 365.542 us; speedup vs baseline: 2.2878x; 1.0675x over previous
//
#include <hip/hip_runtime.h>
#include <math.h>

#define NEG_SLOPE 0.2f

__device__ __forceinline__ float lky(float x){ return x > 0.f ? x : NEG_SLOPE * x; }

__device__ __forceinline__ unsigned short f2bf(float f){
  unsigned int u = __float_as_uint(f);
  unsigned int r = (u + 0x7fffu + ((u >> 16) & 1u)) >> 16;
  return (unsigned short)r;
}
__device__ __forceinline__ float bf2f(unsigned short s){
  return __uint_as_float(((unsigned int)s) << 16);
}
__device__ __forceinline__ void unp8(uint4 v, float* f){
  f[0]=__uint_as_float(v.x<<16); f[1]=__uint_as_float(v.x&0xffff0000u);
  f[2]=__uint_as_float(v.y<<16); f[3]=__uint_as_float(v.y&0xffff0000u);
  f[4]=__uint_as_float(v.z<<16); f[5]=__uint_as_float(v.z&0xffff0000u);
  f[6]=__uint_as_float(v.w<<16); f[7]=__uint_as_float(v.w&0xffff0000u);
}
__device__ __forceinline__ uint4 pack8(const float* o){
  uint4 v;
  v.x = (unsigned)f2bf(o[0]) | ((unsigned)f2bf(o[1])<<16);
  v.y = (unsigned)f2bf(o[2]) | ((unsigned)f2bf(o[3])<<16);
  v.z = (unsigned)f2bf(o[4]) | ((unsigned)f2bf(o[5])<<16);
  v.w = (unsigned)f2bf(o[6]) | ((unsigned)f2bf(o[7])<<16);
  return v;
}

typedef __bf16 bf16x8 __attribute__((ext_vector_type(8)));
typedef float  f32x4  __attribute__((ext_vector_type(4)));
typedef float  f32x2  __attribute__((ext_vector_type(2)));

// fp8 e4m3 pack/unpack via HW cvt
__device__ __forceinline__ uint2 pk_fp8(const float* f){
  unsigned lo = 0u, hi = 0u;
  lo = __builtin_amdgcn_cvt_pk_fp8_f32(f[0], f[1], (int)lo, false);
  lo = __builtin_amdgcn_cvt_pk_fp8_f32(f[2], f[3], (int)lo, true);
  hi = __builtin_amdgcn_cvt_pk_fp8_f32(f[4], f[5], (int)hi, false);
  hi = __builtin_amdgcn_cvt_pk_fp8_f32(f[6], f[7], (int)hi, true);
  return make_uint2(lo, hi);
}
__device__ __forceinline__ void unpk_fp8(uint2 v, float* f){
  f32x2 a0 = __builtin_amdgcn_cvt_pk_f32_fp8((int)v.x, false);
  f32x2 a1 = __builtin_amdgcn_cvt_pk_f32_fp8((int)v.x, true);
  f32x2 a2 = __builtin_amdgcn_cvt_pk_f32_fp8((int)v.y, false);
  f32x2 a3 = __builtin_amdgcn_cvt_pk_f32_fp8((int)v.y, true);
  f[0]=a0[0]; f[1]=a0[1]; f[2]=a1[0]; f[3]=a1[1];
  f[4]=a2[0]; f[5]=a2[1]; f[6]=a3[0]; f[7]=a3[1];
}

// ---------------- CSR build ----------------
__global__ void zero_ints_kernel(int* __restrict__ p, int n){
  int i = blockIdx.x * blockDim.x + threadIdx.x;
  if (i < n) p[i] = 0;
}
__global__ void count_deg_kernel(const int* __restrict__ dst, int* __restrict__ deg, int E){
  int e = blockIdx.x * blockDim.x + threadIdx.x;
  if (e < E) atomicAdd(&deg[dst[e]], 1);
}
__global__ void scan_chunk_kernel(const int* __restrict__ deg, int* __restrict__ rowptr,
                                  int* __restrict__ bsum, int n){
  __shared__ int s[256];
  int t = threadIdx.x;
  int i = blockIdx.x * 256 + t;
  int v = (i < n) ? deg[i] : 0;
  s[t] = v; __syncthreads();
  for (int off = 1; off < 256; off <<= 1){
    int x = (t >= off) ? s[t - off] : 0;
    __syncthreads();
    s[t] += x;
    __syncthreads();
  }
  if (i < n) rowptr[i + 1] = s[t];
  if (t == 255) bsum[blockIdx.x] = s[255];
}
__global__ void scan_bsum_kernel(const int* __restrict__ bsum, int* __restrict__ boff, int nb){
  __shared__ int s[256];
  int t = threadIdx.x;
  int v = (t < nb) ? bsum[t] : 0;
  s[t] = v; __syncthreads();
  for (int off = 1; off < 256; off <<= 1){
    int x = (t >= off) ? s[t - off] : 0;
    __syncthreads();
    s[t] += x;
    __syncthreads();
  }
  boff[t] = s[t] - v;
}
__global__ void scan_add_kernel(int* __restrict__ rowptr, const int* __restrict__ boff, int n){
  int i = blockIdx.x * 256 + threadIdx.x;
  if (i < n) rowptr[i + 1] += boff[blockIdx.x];
  if (i == 0) rowptr[0] = 0;
}
__global__ void fill_csr_kernel(const int* __restrict__ src, const int* __restrict__ dst,
                                const int* __restrict__ rowptr, int* __restrict__ cursor,
                                int* __restrict__ colv, int E){
  int e = blockIdx.x * blockDim.x + threadIdx.x;
  if (e >= E) return;
  int d = dst[e];
  int pos = atomicAdd(&cursor[d], 1);
  colv[rowptr[d] + pos] = src[e];
}

// ---------------- weight pack: fp32 [K][M] -> bf16 B-fragment layout ----------------
__global__ void pack_w_kernel(const float* __restrict__ Wa, const float* __restrict__ Wb,
                              int K, int M, int Mhalf, unsigned short* __restrict__ out){
  int idx = blockIdx.x * 256 + threadIdx.x;
  if (idx >= K * M) return;
  int j = idx & 7;
  int l = (idx >> 3) & 63;
  int rest = idx >> 9;
  int KS = K >> 5;
  int s = rest % KS, gct = rest / KS;
  int col = gct * 16 + (l & 15);
  int k   = s * 32 + ((l >> 4) << 3) + j;
  float v;
  if (Wb == nullptr) v = Wa[(long)k * M + col];
  else v = (col < Mhalf) ? Wa[(long)k * Mhalf + col] : Wb[(long)k * Mhalf + (col - Mhalf)];
  out[idx] = f2bf(v);
}

// ---------------- P1 = W1 @ a (64 x 4 x {src,dst}) ----------------
__global__ void make_p1_kernel(const float* __restrict__ W1, const float* __restrict__ as1,
                               const float* __restrict__ ad1, float* __restrict__ P1){
  int idx = blockIdx.x * 256 + threadIdx.x;
  if (idx >= 512) return;
  int sd = idx & 1, h = (idx >> 1) & 3, k = idx >> 3;
  const float* av = sd ? ad1 : as1;
  float acc = 0.f;
  for (int c = 0; c < 64; ++c) acc += W1[k * 256 + h * 64 + c] * av[h * 64 + c];
  P1[idx] = acc;
}

// ---------------- fused cvt_x + layer-1 scores ----------------
__global__ __launch_bounds__(256) void score1cvt_kernel(
    const float* __restrict__ x, const float* __restrict__ P1,
    unsigned short* __restrict__ xb,
    float* __restrict__ S1s, float* __restrict__ S1d, int n)
{
  __shared__ float P[512];
  int t = threadIdx.x;
  P[t] = P1[t]; P[t + 256] = P1[t + 256];
  __syncthreads();
  int nid = blockIdx.x * 256 + t;
  if (nid >= n) return;
  const float4* xr = (const float4*)x + (long)nid * 16;
  uint4* xw = (uint4*)xb + (long)nid * 8;
  float acc[8] = {0,0,0,0,0,0,0,0};
  for (int kc = 0; kc < 16; kc += 2){
    float4 v0 = xr[kc], v1 = xr[kc + 1];
    uint4 o;
    o.x = (unsigned)f2bf(v0.x) | ((unsigned)f2bf(v0.y) << 16);
    o.y = (unsigned)f2bf(v0.z) | ((unsigned)f2bf(v0.w) << 16);
    o.z = (unsigned)f2bf(v1.x) | ((unsigned)f2bf(v1.y) << 16);
    o.w = (unsigned)f2bf(v1.z) | ((unsigned)f2bf(v1.w) << 16);
    xw[kc >> 1] = o;
    float vf[8] = {v0.x, v0.y, v0.z, v0.w, v1.x, v1.y, v1.z, v1.w};
    #pragma unroll
    for (int j = 0; j < 8; ++j){
      int k = kc * 4 + j;
      #pragma unroll
      for (int o8 = 0; o8 < 8; ++o8) acc[o8] += vf[j] * P[k * 8 + o8];
    }
  }
  *(float4*)(S1s + nid * 4) = make_float4(acc[0], acc[2], acc[4], acc[6]);
  *(float4*)(S1d + nid * 4) = make_float4(acc[1], acc[3], acc[5], acc[7]);
}

// ---------------- layer-1 aggregation of x (inline softmax exp) ----------------
__global__ __launch_bounds__(256) void aggx_kernel(
    const unsigned short* __restrict__ xb,
    const float* __restrict__ Ss, const float* __restrict__ Sd,
    const int* __restrict__ rowptr, const int* __restrict__ colv,
    unsigned short* __restrict__ Xagg, int n)
{
  int wv = threadIdx.x >> 6, l = threadIdx.x & 63;
  int nid = blockIdx.x * 4 + wv;
  if (nid >= n) return;
  int slot = l >> 5;
  int cl = l & 31;
  float4 sdv = *(const float4*)(Sd + (long)nid * 4);
  float acc[4][2] = {};
  float sumw[4] = {0.f, 0.f, 0.f, 0.f};
  int beg = rowptr[nid], end = rowptr[nid + 1];
  for (int jj = beg + slot; jj < end; jj += 2){
    int s = colv[jj];
    float4 a = *(const float4*)(Ss + (long)s * 4);
    float wx = __expf(lky(a.x + sdv.x));
    float wy = __expf(lky(a.y + sdv.y));
    float wz = __expf(lky(a.z + sdv.z));
    float ww = __expf(lky(a.w + sdv.w));
    unsigned xv = *((const unsigned*)xb + (long)s * 32 + cl);
    float f0 = __uint_as_float(xv << 16);
    float f1 = __uint_as_float(xv & 0xffff0000u);
    acc[0][0] += wx * f0; acc[0][1] += wx * f1;
    acc[1][0] += wy * f0; acc[1][1] += wy * f1;
    acc[2][0] += wz * f0; acc[2][1] += wz * f1;
    acc[3][0] += ww * f0; acc[3][1] += ww * f1;
    sumw[0] += wx; sumw[1] += wy; sumw[2] += wz; sumw[3] += ww;
  }
  #pragma unroll
  for (int h = 0; h < 4; ++h){
    acc[h][0] += __shfl_xor(acc[h][0], 32);
    acc[h][1] += __shfl_xor(acc[h][1], 32);
    sumw[h]   += __shfl_xor(sumw[h], 32);
  }
  float4 ssv = *(const float4*)(Ss + (long)nid * 4);
  unsigned xv = *((const unsigned*)xb + (long)nid * 32 + cl);
  float f0 = __uint_as_float(xv << 16);
  float f1 = __uint_as_float(xv & 0xffff0000u);
  float wsh[4] = { __expf(lky(ssv.x + sdv.x)), __expf(lky(ssv.y + sdv.y)),
                   __expf(lky(ssv.z + sdv.z)), __expf(lky(ssv.w + sdv.w)) };
  if (l < 32){
    #pragma unroll
    for (int h = 0; h < 4; ++h){
      float inv = 1.f / (sumw[h] + wsh[h] + 1e-16f);
      float o0 = (acc[h][0] + wsh[h] * f0) * inv;
      float o1 = (acc[h][1] + wsh[h] * f1) * inv;
      unsigned ov = (unsigned)f2bf(o0) | ((unsigned)f2bf(o1) << 16);
      *((unsigned*)Xagg + (long)nid * 128 + h * 32 + cl) = ov;
    }
  }
}

// ---------------- MFMA GEMM (opt. block-diagonal) + fused scores/relu, bf16 or fp8 out ----
template<int K, int KB, int CW, bool BD, bool SCORES, bool RELU, bool OUT8>
__global__ __launch_bounds__(256) void gemm_mfma_kernel(
    const unsigned short* __restrict__ Xb, const unsigned short* __restrict__ Wpk,
    const float* __restrict__ a_s, const float* __restrict__ a_d,
    const float* __restrict__ a_s2, const float* __restrict__ a_d2,
    const float* __restrict__ bias,
    void* __restrict__ Hout,
    float* __restrict__ Ss, float* __restrict__ Sd,
    float* __restrict__ Ss2, float* __restrict__ Sd2, int n)
{
  constexpr int BR  = (CW == 4) ? 32 : 128;
  constexpr int M   = 64 * CW;
  constexpr int KSB = KB / 32;
  constexpr int LDA = K + 8;
  constexpr int SH  = (BR * LDA > BR * M) ? BR * LDA : BR * M;
  __shared__ unsigned short As[SH];

  const int t = threadIdx.x;
  const int w = t >> 6, l = t & 63;
  const int quad = l >> 4, l15 = l & 15;
  const long base = (long)blockIdx.x * BR;
  const int roww = (CW == 4) ? 0 : w;
  const int colw = (CW == 4) ? w : 0;
  const int abase = BD ? w * KB : 0;

  {
    const uint4* Xg = (const uint4*)Xb;
    long g0 = base * (K / 8);
    long lim = (long)n * (K / 8);
    for (int c = t; c < BR * K / 8; c += 256){
      int row = c / (K / 8), kc = c % (K / 8);
      uint4 v = make_uint4(0u, 0u, 0u, 0u);
      if (g0 + c < lim) v = Xg[g0 + c];
      *(uint4*)(As + row * LDA + kc * 8) = v;
    }
  }
  __syncthreads();

  f32x4 acc[2][4] = {};
  for (int s = 0; s < KSB; ++s){
    bf16x8 af0 = *(const bf16x8*)(As + (roww * 32 + 0  + l15) * LDA + abase + s * 32 + quad * 8);
    bf16x8 af1 = *(const bf16x8*)(As + (roww * 32 + 16 + l15) * LDA + abase + s * 32 + quad * 8);
    #pragma unroll
    for (int ct = 0; ct < 4; ++ct){
      int gct = colw * 4 + ct;
      bf16x8 bf = *(const bf16x8*)(Wpk + (((long)gct * KSB + s) * 64 + l) * 8);
      acc[0][ct] = __builtin_amdgcn_mfma_f32_16x16x32_bf16(af0, bf, acc[0][ct], 0, 0, 0);
      acc[1][ct] = __builtin_amdgcn_mfma_f32_16x16x32_bf16(af1, bf, acc[1][ct], 0, 0, 0);
    }
  }

  if constexpr (SCORES){
    if (CW == 4){
      const int head = w;
      float asv[4], adv[4];
      #pragma unroll
      for (int ct = 0; ct < 4; ++ct){
        int col = head * 64 + ct * 16 + l15;
        asv[ct] = a_s[col]; adv[ct] = a_d[col];
      }
      #pragma unroll
      for (int rt = 0; rt < 2; ++rt){
        #pragma unroll
        for (int r = 0; r < 4; ++r){
          float ps = 0.f, pd = 0.f;
          #pragma unroll
          for (int ct = 0; ct < 4; ++ct){
            float v = acc[rt][ct][r];
            ps += v * asv[ct]; pd += v * adv[ct];
          }
          ps += __shfl_xor(ps, 8); pd += __shfl_xor(pd, 8);
          ps += __shfl_xor(ps, 4); pd += __shfl_xor(pd, 4);
          ps += __shfl_xor(ps, 2); pd += __shfl_xor(pd, 2);
          ps += __shfl_xor(ps, 1); pd += __shfl_xor(pd, 1);
          long node = base + rt * 16 + quad * 4 + r;
          if (l15 == 0 && node < n){ Ss[node * 4 + head] = ps; Sd[node * 4 + head] = pd; }
        }
      }
    } else {
      float asm_[2], adm_[2], asl_[2], adl_[2];
      #pragma unroll
      for (int ct = 0; ct < 2; ++ct){
        int col = ct * 16 + l15;
        asm_[ct] = a_s[col];  adm_[ct] = a_d[col];
        asl_[ct] = a_s2[col]; adl_[ct] = a_d2[col];
      }
      #pragma unroll
      for (int rt = 0; rt < 2; ++rt){
        #pragma unroll
        for (int r = 0; r < 4; ++r){
          float psm = 0.f, pdm = 0.f, psl = 0.f, pdl = 0.f;
          #pragma unroll
          for (int ct = 0; ct < 2; ++ct){
            float vm = acc[rt][ct][r];
            float vl = acc[rt][ct + 2][r];
            psm += vm * asm_[ct]; pdm += vm * adm_[ct];
            psl += vl * asl_[ct]; pdl += vl * adl_[ct];
          }
          #pragma unroll
          for (int d = 8; d >= 1; d >>= 1){
            psm += __shfl_xor(psm, d); pdm += __shfl_xor(pdm, d);
            psl += __shfl_xor(psl, d); pdl += __shfl_xor(pdl, d);
          }
          long node = base + w * 32 + rt * 16 + quad * 4 + r;
          if (l15 == 0 && node < n){
            Ss[node]  = psm; Sd[node]  = pdm;
            Ss2[node] = psl; Sd2[node] = pdl;
          }
        }
      }
    }
  }

  __syncthreads();
  float bct[4] = {0.f, 0.f, 0.f, 0.f};
  if constexpr (RELU){
    #pragma unroll
    for (int ct = 0; ct < 4; ++ct) bct[ct] = bias[colw * 64 + ct * 16 + l15];
  }
  #pragma unroll
  for (int rt = 0; rt < 2; ++rt){
    #pragma unroll
    for (int ct = 0; ct < 4; ++ct){
      #pragma unroll
      for (int r = 0; r < 4; ++r){
        int row = roww * 32 + rt * 16 + quad * 4 + r;
        int col = colw * 64 + ct * 16 + l15;
        float o = acc[rt][ct][r];
        if constexpr (RELU) o = fmaxf(o + bct[ct], 0.f);
        As[row * M + col] = f2bf(o);
      }
    }
  }
  __syncthreads();
  if constexpr (OUT8){
    uint2* Hg = (uint2*)Hout;
    for (int c = t; c < BR * M / 8; c += 256){
      int row = c / (M / 8);
      uint4 v = *(const uint4*)(As + c * 8);
      float f[8]; unp8(v, f);
      if (base + row < n) Hg[base * (M / 8) + c] = pk_fp8(f);
    }
  } else {
    uint4* Hg = (uint4*)Hout;
    for (int c = t; c < BR * M / 8; c += 256){
      int row = c / (M / 8);
      if (base + row < n) Hg[base * (M / 8) + c] = *(const uint4*)(As + c * 8);
    }
  }
}

// ---------------- layer-2 aggregation: fp8 gather, inline exp ----------------
__global__ __launch_bounds__(256) void agg256_kernel(
    const unsigned char* __restrict__ H8,
    const float* __restrict__ Ss, const float* __restrict__ Sd,
    const int* __restrict__ rowptr, const int* __restrict__ colv,
    const float* __restrict__ bias, unsigned short* __restrict__ Out, int n)
{
  int wv = threadIdx.x >> 6, l = threadIdx.x & 63;
  int nid = blockIdx.x * 4 + wv;
  if (nid >= n) return;
  int slot = l >> 5;
  int cl = l & 31;
  int head = cl >> 3;
  float sdv = Sd[(long)nid * 4 + head];
  const uint2* H8v = (const uint2*)H8;
  float acc[8] = {0,0,0,0,0,0,0,0};
  float sumw = 0.f;
  int beg = rowptr[nid], end = rowptr[nid + 1];
  for (int jj = beg + slot; jj < end; jj += 2){
    int s = colv[jj];
    float wt = __expf(lky(Ss[(long)s * 4 + head] + sdv));
    uint2 hv = H8v[(long)s * 32 + cl];
    float xf[8]; unpk_fp8(hv, xf);
    #pragma unroll
    for (int j = 0; j < 8; ++j) acc[j] += wt * xf[j];
    sumw += wt;
  }
  #pragma unroll
  for (int j = 0; j < 8; ++j) acc[j] += __shfl_xor(acc[j], 32);
  sumw += __shfl_xor(sumw, 32);
  float wself = __expf(lky(Ss[(long)nid * 4 + head] + sdv));
  uint2 hv = H8v[(long)nid * 32 + cl];
  float xf[8]; unpk_fp8(hv, xf);
  if (l < 32){
    float inv = 1.f / (sumw + wself + 1e-16f);
    float4 bv0 = *(const float4*)(bias + cl * 8);
    float4 bv1 = *(const float4*)(bias + cl * 8 + 4);
    float o[8];
    o[0] = fmaxf((acc[0] + wself * xf[0]) * inv + bv0.x, 0.f);
    o[1] = fmaxf((acc[1] + wself * xf[1]) * inv + bv0.y, 0.f);
    o[2] = fmaxf((acc[2] + wself * xf[2]) * inv + bv0.z, 0.f);
    o[3] = fmaxf((acc[3] + wself * xf[3]) * inv + bv0.w, 0.f);
    o[4] = fmaxf((acc[4] + wself * xf[4]) * inv + bv1.x, 0.f);
    o[5] = fmaxf((acc[5] + wself * xf[5]) * inv + bv1.y, 0.f);
    o[6] = fmaxf((acc[6] + wself * xf[6]) * inv + bv1.z, 0.f);
    o[7] = fmaxf((acc[7] + wself * xf[7]) * inv + bv1.w, 0.f);
    *((uint4*)Out + (long)nid * 32 + cl) = pack8(o);
  }
}

// ---------------- mu/lv aggregation + reparameterize (inline exp, writes z bf16) ----------
__global__ __launch_bounds__(256) void agg_muv_kernel(
    const unsigned short* __restrict__ Hmuv,
    const float* __restrict__ Ssm, const float* __restrict__ Sdm,
    const float* __restrict__ Ssl, const float* __restrict__ Sdl,
    const int* __restrict__ rowptr, const int* __restrict__ colv,
    const float* __restrict__ bmu, const float* __restrict__ blv,
    const float* __restrict__ epsv,
    float* __restrict__ out_mu, float* __restrict__ out_lv, float* __restrict__ out_z,
    unsigned short* __restrict__ zb, int n)
{
  int gid = blockIdx.x * blockDim.x + threadIdx.x;
  int node = gid >> 5, c = gid & 31;
  if (node >= n) return;
  float sdm = Sdm[node], sdl = Sdl[node];
  float wm = __expf(lky(Ssm[node] + sdm));
  float wl = __expf(lky(Ssl[node] + sdl));
  float summ = wm, suml = wl;
  float am = wm * bf2f(Hmuv[(long)node * 64 + c]);
  float al = wl * bf2f(Hmuv[(long)node * 64 + 32 + c]);
  int beg = rowptr[node], end = rowptr[node + 1];
  for (int jj = beg; jj < end; ++jj){
    int s = colv[jj];
    float w1 = __expf(lky(Ssm[s] + sdm));
    float w2 = __expf(lky(Ssl[s] + sdl));
    summ += w1; am += w1 * bf2f(Hmuv[(long)s * 64 + c]);
    suml += w2; al += w2 * bf2f(Hmuv[(long)s * 64 + 32 + c]);
  }
  float mu = am / (summ + 1e-16f) + bmu[c];
  float lv = al / (suml + 1e-16f) + blv[c];
  float z  = mu + epsv[(long)node * 32 + c] * expf(0.5f * lv);
  out_mu[(long)node * 32 + c] = mu;
  out_lv[(long)node * 32 + c] = lv;
  out_z [(long)node * 32 + c] = z;
  zb[(long)node * 32 + c] = f2bf(z);
}

// ---------------- decoder: MFMA fused ----------------
__global__ __launch_bounds__(256) void decoder_mfma_kernel(
    const unsigned short* __restrict__ zb,
    const unsigned short* __restrict__ Wfcpk, const float* __restrict__ bfc,
    const unsigned short* __restrict__ Wndpk, const float* __restrict__ bnode,
    unsigned short* __restrict__ ZD, float* __restrict__ NF, int n)
{
  constexpr int LDA = 40;
  constexpr int LDZ = 72;
  __shared__ unsigned short As[128 * LDA];
  __shared__ unsigned short Zs[128 * LDZ];
  const int t = threadIdx.x;
  const int w = t >> 6, l = t & 63;
  const int quad = l >> 4, l15 = l & 15;
  const long base = (long)blockIdx.x * 128;

  {
    const uint4* Zg = (const uint4*)zb;
    long g0 = base * 4;
    long lim = (long)n * 4;
    for (int c = t; c < 512; c += 256){
      int row = c >> 2, kc = c & 3;
      uint4 v = make_uint4(0u, 0u, 0u, 0u);
      if (g0 + c < lim) v = Zg[g0 + c];
      *(uint4*)(As + row * LDA + kc * 8) = v;
    }
  }
  __syncthreads();

  f32x4 acc[2][4] = {};
  {
    bf16x8 af0 = *(const bf16x8*)(As + (w * 32 + 0  + l15) * LDA + quad * 8);
    bf16x8 af1 = *(const bf16x8*)(As + (w * 32 + 16 + l15) * LDA + quad * 8);
    #pragma unroll
    for (int ct = 0; ct < 4; ++ct){
      bf16x8 bf = *(const bf16x8*)(Wfcpk + (((long)ct) * 64 + l) * 8);
      acc[0][ct] = __builtin_amdgcn_mfma_f32_16x16x32_bf16(af0, bf, acc[0][ct], 0, 0, 0);
      acc[1][ct] = __builtin_amdgcn_mfma_f32_16x16x32_bf16(af1, bf, acc[1][ct], 0, 0, 0);
    }
  }
  #pragma unroll
  for (int rt = 0; rt < 2; ++rt){
    #pragma unroll
    for (int ct = 0; ct < 4; ++ct){
      float b = bfc[ct * 16 + l15];
      #pragma unroll
      for (int r = 0; r < 4; ++r){
        int row = w * 32 + rt * 16 + quad * 4 + r;
        Zs[row * LDZ + ct * 16 + l15] = f2bf(fmaxf(acc[rt][ct][r] + b, 0.f));
      }
    }
  }
  __syncthreads();

  {
    uint4* Zgo = (uint4*)ZD;
    for (int c = t; c < 1024; c += 256){
      int row = c >> 3, kc = c & 7;
      if (base + row < n) Zgo[base * 8 + c] = *(const uint4*)(Zs + row * LDZ + kc * 8);
    }
  }

  f32x4 acc2[2][4] = {};
  #pragma unroll
  for (int s = 0; s < 2; ++s){
    bf16x8 af0 = *(const bf16x8*)(Zs + (w * 32 + 0  + l15) * LDZ + s * 32 + quad * 8);
    bf16x8 af1 = *(const bf16x8*)(Zs + (w * 32 + 16 + l15) * LDZ + s * 32 + quad * 8);
    #pragma unroll
    for (int ct = 0; ct < 4; ++ct){
      bf16x8 bf = *(const bf16x8*)(Wndpk + (((long)ct * 2 + s) * 64 + l) * 8);
      acc2[0][ct] = __builtin_amdgcn_mfma_f32_16x16x32_bf16(af0, bf, acc2[0][ct], 0, 0, 0);
      acc2[1][ct] = __builtin_amdgcn_mfma_f32_16x16x32_bf16(af1, bf, acc2[1][ct], 0, 0, 0);
    }
  }
  #pragma unroll
  for (int rt = 0; rt < 2; ++rt){
    #pragma unroll
    for (int ct = 0; ct < 4; ++ct){
      float b = bnode[ct * 16 + l15];
      #pragma unroll
      for (int r = 0; r < 4; ++r){
        long row = base + w * 32 + rt * 16 + quad * 4 + r;
        if (row < n) NF[row * 64 + ct * 16 + l15] = acc2[rt][ct][r] + b;
      }
    }
  }
}

// ---------------- edge scores: 8 edges per wave, bf16 ZD ----------------
__global__ __launch_bounds__(256) void edge_score_kernel(
    const unsigned short* __restrict__ ZD, const int* __restrict__ src, const int* __restrict__ dst,
    const float* __restrict__ Wedge, const float* __restrict__ bedge,
    float* __restrict__ out_es, int E)
{
  int gid = blockIdx.x * 256 + threadIdx.x;
  int l = threadIdx.x & 63;
  int slot = l >> 3, chunk = l & 7;
  int e = (gid >> 6) * 8 + slot;
  float4 we0 = *(const float4*)(Wedge + chunk * 8);
  float4 we1 = *(const float4*)(Wedge + chunk * 8 + 4);
  float p = 0.f;
  if (e < E){
    int s = src[e], d = dst[e];
    uint4 zs_ = *((const uint4*)ZD + (long)s * 8 + chunk);
    uint4 zd_ = *((const uint4*)ZD + (long)d * 8 + chunk);
    float a[8], b[8]; unp8(zs_, a); unp8(zd_, b);
    p = a[0]*b[0]*we0.x + a[1]*b[1]*we0.y + a[2]*b[2]*we0.z + a[3]*b[3]*we0.w
      + a[4]*b[4]*we1.x + a[5]*b[5]*we1.y + a[6]*b[6]*we1.z + a[7]*b[7]*we1.w;
  }
  p += __shfl_xor(p, 1);
  p += __shfl_xor(p, 2);
  p += __shfl_xor(p, 4);
  if (chunk == 0 && e < E) out_es[e] = p + bedge[0];
}

// ---------------- launch ----------------
extern "C" void kernel_launch(void* const* d_in, const int* in_sizes, int n_in,
                              void* d_out, int out_size, void* d_ws, size_t ws_size,
                              hipStream_t stream)
{
  const float* x     = (const float*)d_in[0];
  const int*   ei    = (const int*)  d_in[1];
  const float* epsv  = (const float*)d_in[3];
  const float* W1    = (const float*)d_in[4];
  const float* as1   = (const float*)d_in[5];
  const float* ad1   = (const float*)d_in[6];
  const float* b1    = (const float*)d_in[7];
  const float* W2    = (const float*)d_in[8];
  const float* as2   = (const float*)d_in[9];
  const float* ad2   = (const float*)d_in[10];
  const float* b2    = (const float*)d_in[11];
  const float* Wmu   = (const float*)d_in[12];
  const float* asmu  = (const float*)d_in[13];
  const float* admu  = (const float*)d_in[14];
  const float* bmu   = (const float*)d_in[15];
  const float* Wlv   = (const float*)d_in[16];
  const float* aslv  = (const float*)d_in[17];
  const float* adlv  = (const float*)d_in[18];
  const float* blv   = (const float*)d_in[19];
  const float* Wfc   = (const float*)d_in[20];
  const float* bfc   = (const float*)d_in[21];
  const float* Wnode = (const float*)d_in[22];
  const float* bnode = (const float*)d_in[23];
  const float* Wedge = (const float*)d_in[24];
  const float* bedge = (const float*)d_in[25];

  const int N = in_sizes[0] / 64;
  const int E = in_sizes[1] / 2;
  const int* srcA = ei;
  const int* dstA = ei + E;

  char* wsb = (char*)d_ws;
  size_t off = 0;
  auto alloc = [&](size_t bytes) -> void* {
    void* p = wsb + off;
    off += (bytes + 255) & ~(size_t)255;
    return p;
  };
  unsigned short* xb    = (unsigned short*)alloc((size_t)N * 64 * 2);
  unsigned short* bufP  = (unsigned short*)alloc((size_t)N * 256 * 2);  // Xagg, later B2
  unsigned short* bufQ  = (unsigned short*)alloc((size_t)N * 256 * 2);  // B1
  unsigned char*  H8    = (unsigned char*) alloc((size_t)N * 256);     // h2 fp8
  unsigned short* Hmuv  = (unsigned short*)alloc((size_t)N * 64 * 2);
  unsigned short* ZDb   = (unsigned short*)alloc((size_t)N * 64 * 2);
  unsigned short* zbb   = (unsigned short*)alloc((size_t)N * 32 * 2);
  unsigned short* W1pk  = (unsigned short*)alloc((size_t)64 * 256 * 2);
  unsigned short* W2pk  = (unsigned short*)alloc((size_t)256 * 256 * 2);
  unsigned short* Wmvpk = (unsigned short*)alloc((size_t)256 * 64 * 2);
  unsigned short* Wfcpk = (unsigned short*)alloc((size_t)32 * 64 * 2);
  unsigned short* Wndpk = (unsigned short*)alloc((size_t)64 * 64 * 2);
  float* P1    = (float*)alloc(512 * 4);
  float* S1s   = (float*)alloc((size_t)N * 4 * 4);
  float* S1d   = (float*)alloc((size_t)N * 4 * 4);
  float* S2s   = (float*)alloc((size_t)N * 4 * 4);
  float* S2d   = (float*)alloc((size_t)N * 4 * 4);
  float* Ssm   = (float*)alloc((size_t)N * 4);
  float* Sdm   = (float*)alloc((size_t)N * 4);
  float* Ssl   = (float*)alloc((size_t)N * 4);
  float* Sdl   = (float*)alloc((size_t)N * 4);
  int*   deg   = (int*)  alloc((size_t)N * 2 * 4);
  int*   cursor= deg + N;
  int*   rowptr= (int*)  alloc((size_t)(N + 1) * 4);
  int*   colv  = (int*)  alloc((size_t)E * 4);
  int*   bsum  = (int*)  alloc(1024);
  int*   boff  = (int*)  alloc(1024);
  (void)ws_size; (void)n_in; (void)out_size;

  float* out_mu = (float*)d_out;
  float* out_lv = out_mu + (size_t)N * 32;
  float* out_z  = out_lv + (size_t)N * 32;
  float* out_nf = out_z  + (size_t)N * 32;
  float* out_es = out_nf + (size_t)N * 64;

  const int nb = (N + 255) / 256;

  // CSR build
  zero_ints_kernel<<<(2 * N + 255) / 256, 256, 0, stream>>>(deg, 2 * N);
  count_deg_kernel<<<(E + 255) / 256, 256, 0, stream>>>(dstA, deg, E);
  scan_chunk_kernel<<<nb, 256, 0, stream>>>(deg, rowptr, bsum, N);
  scan_bsum_kernel<<<1, 256, 0, stream>>>(bsum, boff, nb);
  scan_add_kernel<<<nb, 256, 0, stream>>>(rowptr, boff, N);
  fill_csr_kernel<<<(E + 255) / 256, 256, 0, stream>>>(srcA, dstA, rowptr, cursor, colv, E);

  // weight packing + P1
  pack_w_kernel<<<(64 * 256 + 255) / 256, 256, 0, stream>>>(W1, nullptr, 64, 256, 256, W1pk);
  pack_w_kernel<<<(256 * 256 + 255) / 256, 256, 0, stream>>>(W2, nullptr, 256, 256, 256, W2pk);
  pack_w_kernel<<<(256 * 64 + 255) / 256, 256, 0, stream>>>(Wmu, Wlv, 256, 64, 32, Wmvpk);
  pack_w_kernel<<<(32 * 64 + 255) / 256, 256, 0, stream>>>(Wfc, nullptr, 32, 64, 64, Wfcpk);
  pack_w_kernel<<<(64 * 64 + 255) / 256, 256, 0, stream>>>(Wnode, nullptr, 64, 64, 64, Wndpk);
  make_p1_kernel<<<2, 256, 0, stream>>>(W1, as1, ad1, P1);

  // layer 1
  score1cvt_kernel<<<(N + 255) / 256, 256, 0, stream>>>(x, P1, xb, S1s, S1d, N);
  aggx_kernel<<<(N + 3) / 4, 256, 0, stream>>>(xb, S1s, S1d, rowptr, colv, bufP, N);
  gemm_mfma_kernel<256, 64, 4, true, false, true, false><<<(N + 31) / 32, 256, 0, stream>>>(
      bufP, W1pk, nullptr, nullptr, nullptr, nullptr, b1, bufQ,
      nullptr, nullptr, nullptr, nullptr, N);

  // layer 2
  gemm_mfma_kernel<256, 256, 4, false, true, false, true><<<(N + 31) / 32, 256, 0, stream>>>(
      bufQ, W2pk, as2, ad2, nullptr, nullptr, nullptr, H8,
      S2s, S2d, nullptr, nullptr, N);
  agg256_kernel<<<(N + 3) / 4, 256, 0, stream>>>(H8, S2s, S2d, rowptr, colv, b2, bufP, N);

  // mu / logvar
  gemm_mfma_kernel<256, 256, 1, false, true, false, false><<<(N + 127) / 128, 256, 0, stream>>>(
      bufP, Wmvpk, asmu, admu, aslv, adlv, nullptr, Hmuv,
      Ssm, Sdm, Ssl, Sdl, N);
  agg_muv_kernel<<<((size_t)N * 32 + 255) / 256, 256, 0, stream>>>(
      Hmuv, Ssm, Sdm, Ssl, Sdl, rowptr, colv, bmu, blv, epsv,
      out_mu, out_lv, out_z, zbb, N);

  // decoder
  decoder_mfma_kernel<<<(N + 127) / 128, 256, 0, stream>>>(
      zbb, Wfcpk, bfc, Wndpk, bnode, ZDb, out_nf, N);
  {
    long waves = ((long)E + 7) / 8;
    long blocks = (waves + 3) / 4;
    edge_score_kernel<<<(int)blocks, 256, 0, stream>>>(ZDb, srcA, dstA, Wedge, bedge, out_es, E);
  }
}

// Round 7
// 354.292 us; speedup vs baseline: 2.3605x; 1.0318x over previous
//
#include <hip/hip_runtime.h>
#include <math.h>

#define NEG_SLOPE 0.2f

__device__ __forceinline__ float lky(float x){ return x > 0.f ? x : NEG_SLOPE * x; }

__device__ __forceinline__ unsigned short f2bf(float f){
  unsigned int u = __float_as_uint(f);
  unsigned int r = (u + 0x7fffu + ((u >> 16) & 1u)) >> 16;
  return (unsigned short)r;
}
__device__ __forceinline__ float bf2f(unsigned short s){
  return __uint_as_float(((unsigned int)s) << 16);
}
__device__ __forceinline__ void unp8(uint4 v, float* f){
  f[0]=__uint_as_float(v.x<<16); f[1]=__uint_as_float(v.x&0xffff0000u);
  f[2]=__uint_as_float(v.y<<16); f[3]=__uint_as_float(v.y&0xffff0000u);
  f[4]=__uint_as_float(v.z<<16); f[5]=__uint_as_float(v.z&0xffff0000u);
  f[6]=__uint_as_float(v.w<<16); f[7]=__uint_as_float(v.w&0xffff0000u);
}
__device__ __forceinline__ uint4 pack8(const float* o){
  uint4 v;
  v.x = (unsigned)f2bf(o[0]) | ((unsigned)f2bf(o[1])<<16);
  v.y = (unsigned)f2bf(o[2]) | ((unsigned)f2bf(o[3])<<16);
  v.z = (unsigned)f2bf(o[4]) | ((unsigned)f2bf(o[5])<<16);
  v.w = (unsigned)f2bf(o[6]) | ((unsigned)f2bf(o[7])<<16);
  return v;
}

typedef __bf16 bf16x8 __attribute__((ext_vector_type(8)));
typedef float  f32x4  __attribute__((ext_vector_type(4)));
typedef float  f32x2  __attribute__((ext_vector_type(2)));

// fp8 e4m3 pack/unpack via HW cvt
__device__ __forceinline__ uint2 pk_fp8(const float* f){
  unsigned lo = 0u, hi = 0u;
  lo = __builtin_amdgcn_cvt_pk_fp8_f32(f[0], f[1], (int)lo, false);
  lo = __builtin_amdgcn_cvt_pk_fp8_f32(f[2], f[3], (int)lo, true);
  hi = __builtin_amdgcn_cvt_pk_fp8_f32(f[4], f[5], (int)hi, false);
  hi = __builtin_amdgcn_cvt_pk_fp8_f32(f[6], f[7], (int)hi, true);
  return make_uint2(lo, hi);
}
__device__ __forceinline__ unsigned pk_fp8x4(float f0, float f1, float f2, float f3){
  unsigned u = 0u;
  u = __builtin_amdgcn_cvt_pk_fp8_f32(f0, f1, (int)u, false);
  u = __builtin_amdgcn_cvt_pk_fp8_f32(f2, f3, (int)u, true);
  return u;
}
__device__ __forceinline__ void unpk_fp8(uint2 v, float* f){
  f32x2 a0 = __builtin_amdgcn_cvt_pk_f32_fp8((int)v.x, false);
  f32x2 a1 = __builtin_amdgcn_cvt_pk_f32_fp8((int)v.x, true);
  f32x2 a2 = __builtin_amdgcn_cvt_pk_f32_fp8((int)v.y, false);
  f32x2 a3 = __builtin_amdgcn_cvt_pk_f32_fp8((int)v.y, true);
  f[0]=a0[0]; f[1]=a0[1]; f[2]=a1[0]; f[3]=a1[1];
  f[4]=a2[0]; f[5]=a2[1]; f[6]=a3[0]; f[7]=a3[1];
}

// ---------------- CSR build ----------------
__global__ void zero_ints_kernel(int* __restrict__ p, int n){
  int i = blockIdx.x * blockDim.x + threadIdx.x;
  if (i < n) p[i] = 0;
}
__global__ void count_deg_kernel(const int* __restrict__ dst, int* __restrict__ deg, int E){
  int e = blockIdx.x * blockDim.x + threadIdx.x;
  if (e < E) atomicAdd(&deg[dst[e]], 1);
}
__global__ void scan_chunk_kernel(const int* __restrict__ deg, int* __restrict__ rowptr,
                                  int* __restrict__ bsum, int n){
  __shared__ int s[256];
  int t = threadIdx.x;
  int i = blockIdx.x * 256 + t;
  int v = (i < n) ? deg[i] : 0;
  s[t] = v; __syncthreads();
  for (int off = 1; off < 256; off <<= 1){
    int x = (t >= off) ? s[t - off] : 0;
    __syncthreads();
    s[t] += x;
    __syncthreads();
  }
  if (i < n) rowptr[i + 1] = s[t];
  if (t == 255) bsum[blockIdx.x] = s[255];
}
// scan bsum in every block (nb<=256) and add exclusive prefix
__global__ void scan_add_kernel(int* __restrict__ rowptr, const int* __restrict__ bsum,
                                int nb, int n){
  __shared__ int s[256];
  int t = threadIdx.x;
  int v = (t < nb) ? bsum[t] : 0;
  s[t] = v; __syncthreads();
  for (int off = 1; off < 256; off <<= 1){
    int x = (t >= off) ? s[t - off] : 0;
    __syncthreads();
    s[t] += x;
    __syncthreads();
  }
  int b = blockIdx.x;
  int excl = (b == 0) ? 0 : s[b - 1];
  int i = b * 256 + t;
  if (i < n) rowptr[i + 1] += excl;
  if (i == 0) rowptr[0] = 0;
}
__global__ void fill_csr_kernel(const int* __restrict__ src, const int* __restrict__ dst,
                                const int* __restrict__ rowptr, int* __restrict__ cursor,
                                int* __restrict__ colv, int E){
  int e = blockIdx.x * blockDim.x + threadIdx.x;
  if (e >= E) return;
  int d = dst[e];
  int pos = atomicAdd(&cursor[d], 1);
  colv[rowptr[d] + pos] = src[e];
}

// ---------------- fused weight packing (all matrices + P1) ----------------
__device__ __forceinline__ void pack_one(const float* Wa, const float* Wb,
                                         int K, int M, int Mhalf,
                                         unsigned short* out, int idx){
  if (idx >= K * M) return;
  int j = idx & 7;
  int l = (idx >> 3) & 63;
  int rest = idx >> 9;
  int KS = K >> 5;
  int s = rest % KS, gct = rest / KS;
  int col = gct * 16 + (l & 15);
  int k   = s * 32 + ((l >> 4) << 3) + j;
  float v;
  if (Wb == nullptr) v = Wa[(long)k * M + col];
  else v = (col < Mhalf) ? Wa[(long)k * Mhalf + col] : Wb[(long)k * Mhalf + (col - Mhalf)];
  out[idx] = f2bf(v);
}

__global__ __launch_bounds__(256) void packall_kernel(
    const float* __restrict__ W1,  unsigned short* __restrict__ W1pk,
    const float* __restrict__ W2,  unsigned short* __restrict__ W2pk,
    const float* __restrict__ Wmu, const float* __restrict__ Wlv,
    unsigned short* __restrict__ Wmvpk,
    const float* __restrict__ Wfc, unsigned short* __restrict__ Wfcpk,
    const float* __restrict__ Wnd, unsigned short* __restrict__ Wndpk,
    const float* __restrict__ as1, const float* __restrict__ ad1,
    float* __restrict__ P1)
{
  int b = blockIdx.x, t = threadIdx.x;
  if (b < 64){                      // W1: 64x256
    pack_one(W1, nullptr, 64, 256, 256, W1pk, b * 256 + t);
  } else if (b < 320){              // W2: 256x256
    pack_one(W2, nullptr, 256, 256, 256, W2pk, (b - 64) * 256 + t);
  } else if (b < 384){              // Wmu|Wlv: 256x64
    pack_one(Wmu, Wlv, 256, 64, 32, Wmvpk, (b - 320) * 256 + t);
  } else if (b < 392){              // Wfc: 32x64
    pack_one(Wfc, nullptr, 32, 64, 64, Wfcpk, (b - 384) * 256 + t);
  } else if (b < 408){              // Wnode: 64x64
    pack_one(Wnd, nullptr, 64, 64, 64, Wndpk, (b - 392) * 256 + t);
  } else {                          // P1: 512 entries
    int idx = (b - 408) * 256 + t;
    if (idx < 512){
      int sd = idx & 1, h = (idx >> 1) & 3, k = idx >> 3;
      const float* av = sd ? ad1 : as1;
      float acc = 0.f;
      for (int c = 0; c < 64; ++c) acc += W1[k * 256 + h * 64 + c] * av[h * 64 + c];
      P1[idx] = acc;
    }
  }
}

// ---------------- fused cvt_x + layer-1 scores ----------------
__global__ __launch_bounds__(256) void score1cvt_kernel(
    const float* __restrict__ x, const float* __restrict__ P1,
    unsigned short* __restrict__ xb,
    float* __restrict__ S1s, float* __restrict__ S1d, int n)
{
  __shared__ float P[512];
  int t = threadIdx.x;
  P[t] = P1[t]; P[t + 256] = P1[t + 256];
  __syncthreads();
  int nid = blockIdx.x * 256 + t;
  if (nid >= n) return;
  const float4* xr = (const float4*)x + (long)nid * 16;
  uint4* xw = (uint4*)xb + (long)nid * 8;
  float acc[8] = {0,0,0,0,0,0,0,0};
  for (int kc = 0; kc < 16; kc += 2){
    float4 v0 = xr[kc], v1 = xr[kc + 1];
    uint4 o;
    o.x = (unsigned)f2bf(v0.x) | ((unsigned)f2bf(v0.y) << 16);
    o.y = (unsigned)f2bf(v0.z) | ((unsigned)f2bf(v0.w) << 16);
    o.z = (unsigned)f2bf(v1.x) | ((unsigned)f2bf(v1.y) << 16);
    o.w = (unsigned)f2bf(v1.z) | ((unsigned)f2bf(v1.w) << 16);
    xw[kc >> 1] = o;
    float vf[8] = {v0.x, v0.y, v0.z, v0.w, v1.x, v1.y, v1.z, v1.w};
    #pragma unroll
    for (int j = 0; j < 8; ++j){
      int k = kc * 4 + j;
      #pragma unroll
      for (int o8 = 0; o8 < 8; ++o8) acc[o8] += vf[j] * P[k * 8 + o8];
    }
  }
  *(float4*)(S1s + nid * 4) = make_float4(acc[0], acc[2], acc[4], acc[6]);
  *(float4*)(S1d + nid * 4) = make_float4(acc[1], acc[3], acc[5], acc[7]);
}

// ---------------- layer-1 aggregation of x (inline softmax exp) ----------------
__global__ __launch_bounds__(256) void aggx_kernel(
    const unsigned short* __restrict__ xb,
    const float* __restrict__ Ss, const float* __restrict__ Sd,
    const int* __restrict__ rowptr, const int* __restrict__ colv,
    unsigned short* __restrict__ Xagg, int n)
{
  int wv = threadIdx.x >> 6, l = threadIdx.x & 63;
  int nid = blockIdx.x * 4 + wv;
  if (nid >= n) return;
  int slot = l >> 5;
  int cl = l & 31;
  float4 sdv = *(const float4*)(Sd + (long)nid * 4);
  float acc[4][2] = {};
  float sumw[4] = {0.f, 0.f, 0.f, 0.f};
  int beg = rowptr[nid], end = rowptr[nid + 1];
  for (int jj = beg + slot; jj < end; jj += 2){
    int s = colv[jj];
    float4 a = *(const float4*)(Ss + (long)s * 4);
    float wx = __expf(lky(a.x + sdv.x));
    float wy = __expf(lky(a.y + sdv.y));
    float wz = __expf(lky(a.z + sdv.z));
    float ww = __expf(lky(a.w + sdv.w));
    unsigned xv = *((const unsigned*)xb + (long)s * 32 + cl);
    float f0 = __uint_as_float(xv << 16);
    float f1 = __uint_as_float(xv & 0xffff0000u);
    acc[0][0] += wx * f0; acc[0][1] += wx * f1;
    acc[1][0] += wy * f0; acc[1][1] += wy * f1;
    acc[2][0] += wz * f0; acc[2][1] += wz * f1;
    acc[3][0] += ww * f0; acc[3][1] += ww * f1;
    sumw[0] += wx; sumw[1] += wy; sumw[2] += wz; sumw[3] += ww;
  }
  #pragma unroll
  for (int h = 0; h < 4; ++h){
    acc[h][0] += __shfl_xor(acc[h][0], 32);
    acc[h][1] += __shfl_xor(acc[h][1], 32);
    sumw[h]   += __shfl_xor(sumw[h], 32);
  }
  float4 ssv = *(const float4*)(Ss + (long)nid * 4);
  unsigned xv = *((const unsigned*)xb + (long)nid * 32 + cl);
  float f0 = __uint_as_float(xv << 16);
  float f1 = __uint_as_float(xv & 0xffff0000u);
  float wsh[4] = { __expf(lky(ssv.x + sdv.x)), __expf(lky(ssv.y + sdv.y)),
                   __expf(lky(ssv.z + sdv.z)), __expf(lky(ssv.w + sdv.w)) };
  if (l < 32){
    #pragma unroll
    for (int h = 0; h < 4; ++h){
      float inv = 1.f / (sumw[h] + wsh[h] + 1e-16f);
      float o0 = (acc[h][0] + wsh[h] * f0) * inv;
      float o1 = (acc[h][1] + wsh[h] * f1) * inv;
      unsigned ov = (unsigned)f2bf(o0) | ((unsigned)f2bf(o1) << 16);
      *((unsigned*)Xagg + (long)nid * 128 + h * 32 + cl) = ov;
    }
  }
}

// ---------------- MFMA GEMM (opt. block-diagonal) + fused scores/relu ----------------
// OUT8: epilogue converts to fp8. CW==1 stores mu/lv interleaved (pos mapping).
template<int K, int KB, int CW, bool BD, bool SCORES, bool RELU, bool OUT8>
__global__ __launch_bounds__(256) void gemm_mfma_kernel(
    const unsigned short* __restrict__ Xb, const unsigned short* __restrict__ Wpk,
    const float* __restrict__ a_s, const float* __restrict__ a_d,
    const float* __restrict__ a_s2, const float* __restrict__ a_d2,
    const float* __restrict__ bias,
    void* __restrict__ Hout,
    float* __restrict__ Ss, float* __restrict__ Sd,
    float* __restrict__ Ss2, float* __restrict__ Sd2, int n)
{
  constexpr int BR  = (CW == 4) ? 32 : 128;
  constexpr int M   = 64 * CW;
  constexpr int KSB = KB / 32;
  constexpr int LDA = K + 8;
  constexpr int SH  = (BR * LDA > BR * M) ? BR * LDA : BR * M;
  __shared__ unsigned short As[SH];

  const int t = threadIdx.x;
  const int w = t >> 6, l = t & 63;
  const int quad = l >> 4, l15 = l & 15;
  const long base = (long)blockIdx.x * BR;
  const int roww = (CW == 4) ? 0 : w;
  const int colw = (CW == 4) ? w : 0;
  const int abase = BD ? w * KB : 0;

  {
    const uint4* Xg = (const uint4*)Xb;
    long g0 = base * (K / 8);
    long lim = (long)n * (K / 8);
    for (int c = t; c < BR * K / 8; c += 256){
      int row = c / (K / 8), kc = c % (K / 8);
      uint4 v = make_uint4(0u, 0u, 0u, 0u);
      if (g0 + c < lim) v = Xg[g0 + c];
      *(uint4*)(As + row * LDA + kc * 8) = v;
    }
  }
  __syncthreads();

  f32x4 acc[2][4] = {};
  for (int s = 0; s < KSB; ++s){
    bf16x8 af0 = *(const bf16x8*)(As + (roww * 32 + 0  + l15) * LDA + abase + s * 32 + quad * 8);
    bf16x8 af1 = *(const bf16x8*)(As + (roww * 32 + 16 + l15) * LDA + abase + s * 32 + quad * 8);
    #pragma unroll
    for (int ct = 0; ct < 4; ++ct){
      int gct = colw * 4 + ct;
      bf16x8 bf = *(const bf16x8*)(Wpk + (((long)gct * KSB + s) * 64 + l) * 8);
      acc[0][ct] = __builtin_amdgcn_mfma_f32_16x16x32_bf16(af0, bf, acc[0][ct], 0, 0, 0);
      acc[1][ct] = __builtin_amdgcn_mfma_f32_16x16x32_bf16(af1, bf, acc[1][ct], 0, 0, 0);
    }
  }

  if constexpr (SCORES){
    if (CW == 4){
      const int head = w;
      float asv[4], adv[4];
      #pragma unroll
      for (int ct = 0; ct < 4; ++ct){
        int col = head * 64 + ct * 16 + l15;
        asv[ct] = a_s[col]; adv[ct] = a_d[col];
      }
      #pragma unroll
      for (int rt = 0; rt < 2; ++rt){
        #pragma unroll
        for (int r = 0; r < 4; ++r){
          float ps = 0.f, pd = 0.f;
          #pragma unroll
          for (int ct = 0; ct < 4; ++ct){
            float v = acc[rt][ct][r];
            ps += v * asv[ct]; pd += v * adv[ct];
          }
          ps += __shfl_xor(ps, 8); pd += __shfl_xor(pd, 8);
          ps += __shfl_xor(ps, 4); pd += __shfl_xor(pd, 4);
          ps += __shfl_xor(ps, 2); pd += __shfl_xor(pd, 2);
          ps += __shfl_xor(ps, 1); pd += __shfl_xor(pd, 1);
          long node = base + rt * 16 + quad * 4 + r;
          if (l15 == 0 && node < n){ Ss[node * 4 + head] = ps; Sd[node * 4 + head] = pd; }
        }
      }
    } else {
      float asm_[2], adm_[2], asl_[2], adl_[2];
      #pragma unroll
      for (int ct = 0; ct < 2; ++ct){
        int col = ct * 16 + l15;
        asm_[ct] = a_s[col];  adm_[ct] = a_d[col];
        asl_[ct] = a_s2[col]; adl_[ct] = a_d2[col];
      }
      #pragma unroll
      for (int rt = 0; rt < 2; ++rt){
        #pragma unroll
        for (int r = 0; r < 4; ++r){
          float psm = 0.f, pdm = 0.f, psl = 0.f, pdl = 0.f;
          #pragma unroll
          for (int ct = 0; ct < 2; ++ct){
            float vm = acc[rt][ct][r];
            float vl = acc[rt][ct + 2][r];
            psm += vm * asm_[ct]; pdm += vm * adm_[ct];
            psl += vl * asl_[ct]; pdl += vl * adl_[ct];
          }
          #pragma unroll
          for (int d = 8; d >= 1; d >>= 1){
            psm += __shfl_xor(psm, d); pdm += __shfl_xor(pdm, d);
            psl += __shfl_xor(psl, d); pdl += __shfl_xor(pdl, d);
          }
          long node = base + w * 32 + rt * 16 + quad * 4 + r;
          if (l15 == 0 && node < n){
            Ss[node]  = psm; Sd[node]  = pdm;
            Ss2[node] = psl; Sd2[node] = pdl;
          }
        }
      }
    }
  }

  __syncthreads();
  float bct[4] = {0.f, 0.f, 0.f, 0.f};
  if constexpr (RELU){
    #pragma unroll
    for (int ct = 0; ct < 4; ++ct) bct[ct] = bias[colw * 64 + ct * 16 + l15];
  }
  #pragma unroll
  for (int rt = 0; rt < 2; ++rt){
    #pragma unroll
    for (int ct = 0; ct < 4; ++ct){
      #pragma unroll
      for (int r = 0; r < 4; ++r){
        int row = roww * 32 + rt * 16 + quad * 4 + r;
        int col = colw * 64 + ct * 16 + l15;
        float o = acc[rt][ct][r];
        if constexpr (RELU) o = fmaxf(o + bct[ct], 0.f);
        int pos = col;
        if constexpr (CW == 1){ pos = (col < 32) ? (col * 2) : ((col - 32) * 2 + 1); }
        As[row * M + pos] = f2bf(o);
      }
    }
  }
  __syncthreads();
  if constexpr (OUT8){
    uint2* Hg = (uint2*)Hout;
    for (int c = t; c < BR * M / 8; c += 256){
      int row = c / (M / 8);
      uint4 v = *(const uint4*)(As + c * 8);
      float f[8]; unp8(v, f);
      if (base + row < n) Hg[base * (M / 8) + c] = pk_fp8(f);
    }
  } else {
    uint4* Hg = (uint4*)Hout;
    for (int c = t; c < BR * M / 8; c += 256){
      int row = c / (M / 8);
      if (base + row < n) Hg[base * (M / 8) + c] = *(const uint4*)(As + c * 8);
    }
  }
}

// ---------------- layer-2 aggregation: fp8 gather, inline exp ----------------
__global__ __launch_bounds__(256) void agg256_kernel(
    const unsigned char* __restrict__ H8,
    const float* __restrict__ Ss, const float* __restrict__ Sd,
    const int* __restrict__ rowptr, const int* __restrict__ colv,
    const float* __restrict__ bias, unsigned short* __restrict__ Out, int n)
{
  int wv = threadIdx.x >> 6, l = threadIdx.x & 63;
  int nid = blockIdx.x * 4 + wv;
  if (nid >= n) return;
  int slot = l >> 5;
  int cl = l & 31;
  int head = cl >> 3;
  float sdv = Sd[(long)nid * 4 + head];
  const uint2* H8v = (const uint2*)H8;
  float acc[8] = {0,0,0,0,0,0,0,0};
  float sumw = 0.f;
  int beg = rowptr[nid], end = rowptr[nid + 1];
  for (int jj = beg + slot; jj < end; jj += 2){
    int s = colv[jj];
    float wt = __expf(lky(Ss[(long)s * 4 + head] + sdv));
    uint2 hv = H8v[(long)s * 32 + cl];
    float xf[8]; unpk_fp8(hv, xf);
    #pragma unroll
    for (int j = 0; j < 8; ++j) acc[j] += wt * xf[j];
    sumw += wt;
  }
  #pragma unroll
  for (int j = 0; j < 8; ++j) acc[j] += __shfl_xor(acc[j], 32);
  sumw += __shfl_xor(sumw, 32);
  float wself = __expf(lky(Ss[(long)nid * 4 + head] + sdv));
  uint2 hv = H8v[(long)nid * 32 + cl];
  float xf[8]; unpk_fp8(hv, xf);
  if (l < 32){
    float inv = 1.f / (sumw + wself + 1e-16f);
    float4 bv0 = *(const float4*)(bias + cl * 8);
    float4 bv1 = *(const float4*)(bias + cl * 8 + 4);
    float o[8];
    o[0] = fmaxf((acc[0] + wself * xf[0]) * inv + bv0.x, 0.f);
    o[1] = fmaxf((acc[1] + wself * xf[1]) * inv + bv0.y, 0.f);
    o[2] = fmaxf((acc[2] + wself * xf[2]) * inv + bv0.z, 0.f);
    o[3] = fmaxf((acc[3] + wself * xf[3]) * inv + bv0.w, 0.f);
    o[4] = fmaxf((acc[4] + wself * xf[4]) * inv + bv1.x, 0.f);
    o[5] = fmaxf((acc[5] + wself * xf[5]) * inv + bv1.y, 0.f);
    o[6] = fmaxf((acc[6] + wself * xf[6]) * inv + bv1.z, 0.f);
    o[7] = fmaxf((acc[7] + wself * xf[7]) * inv + bv1.w, 0.f);
    *((uint4*)Out + (long)nid * 32 + cl) = pack8(o);
  }
}

// ---------------- mu/lv aggregation + reparameterize: wave/node, interleaved Hmuv ----
__global__ __launch_bounds__(256) void agg_muv_kernel(
    const unsigned short* __restrict__ Hmuv,
    const float* __restrict__ Ssm, const float* __restrict__ Sdm,
    const float* __restrict__ Ssl, const float* __restrict__ Sdl,
    const int* __restrict__ rowptr, const int* __restrict__ colv,
    const float* __restrict__ bmu, const float* __restrict__ blv,
    const float* __restrict__ epsv,
    float* __restrict__ out_mu, float* __restrict__ out_lv, float* __restrict__ out_z,
    unsigned short* __restrict__ zb, int n)
{
  int wv = threadIdx.x >> 6, l = threadIdx.x & 63;
  int nid = blockIdx.x * 4 + wv;
  if (nid >= n) return;
  int slot = l >> 5;
  int cl = l & 31;
  float sdm = Sdm[nid], sdl = Sdl[nid];
  const unsigned* Hm32 = (const unsigned*)Hmuv;
  float am = 0.f, al = 0.f, summ = 0.f, suml = 0.f;
  int beg = rowptr[nid], end = rowptr[nid + 1];
  for (int jj = beg + slot; jj < end; jj += 2){
    int s = colv[jj];
    float wm = __expf(lky(Ssm[s] + sdm));
    float wl = __expf(lky(Ssl[s] + sdl));
    unsigned hv = Hm32[(long)s * 32 + cl];
    float mu = __uint_as_float(hv << 16);
    float lv = __uint_as_float(hv & 0xffff0000u);
    am += wm * mu; al += wl * lv;
    summ += wm; suml += wl;
  }
  am += __shfl_xor(am, 32); al += __shfl_xor(al, 32);
  summ += __shfl_xor(summ, 32); suml += __shfl_xor(suml, 32);
  float wms = __expf(lky(Ssm[nid] + sdm));
  float wls = __expf(lky(Ssl[nid] + sdl));
  unsigned hv = Hm32[(long)nid * 32 + cl];
  float mus = __uint_as_float(hv << 16);
  float lvs = __uint_as_float(hv & 0xffff0000u);
  if (l < 32){
    float mu = (am + wms * mus) / (summ + wms + 1e-16f) + bmu[cl];
    float lv = (al + wls * lvs) / (suml + wls + 1e-16f) + blv[cl];
    float z  = mu + epsv[(long)nid * 32 + cl] * expf(0.5f * lv);
    out_mu[(long)nid * 32 + cl] = mu;
    out_lv[(long)nid * 32 + cl] = lv;
    out_z [(long)nid * 32 + cl] = z;
    zb[(long)nid * 32 + cl] = f2bf(z);
  }
}

// ---------------- decoder: MFMA fused, ZD out as fp8 ----------------
__global__ __launch_bounds__(256) void decoder_mfma_kernel(
    const unsigned short* __restrict__ zb,
    const unsigned short* __restrict__ Wfcpk, const float* __restrict__ bfc,
    const unsigned short* __restrict__ Wndpk, const float* __restrict__ bnode,
    unsigned char* __restrict__ ZD8, float* __restrict__ NF, int n)
{
  constexpr int LDA = 40;
  constexpr int LDZ = 72;
  __shared__ unsigned short As[128 * LDA];
  __shared__ unsigned short Zs[128 * LDZ];
  const int t = threadIdx.x;
  const int w = t >> 6, l = t & 63;
  const int quad = l >> 4, l15 = l & 15;
  const long base = (long)blockIdx.x * 128;

  {
    const uint4* Zg = (const uint4*)zb;
    long g0 = base * 4;
    long lim = (long)n * 4;
    for (int c = t; c < 512; c += 256){
      int row = c >> 2, kc = c & 3;
      uint4 v = make_uint4(0u, 0u, 0u, 0u);
      if (g0 + c < lim) v = Zg[g0 + c];
      *(uint4*)(As + row * LDA + kc * 8) = v;
    }
  }
  __syncthreads();

  f32x4 acc[2][4] = {};
  {
    bf16x8 af0 = *(const bf16x8*)(As + (w * 32 + 0  + l15) * LDA + quad * 8);
    bf16x8 af1 = *(const bf16x8*)(As + (w * 32 + 16 + l15) * LDA + quad * 8);
    #pragma unroll
    for (int ct = 0; ct < 4; ++ct){
      bf16x8 bf = *(const bf16x8*)(Wfcpk + (((long)ct) * 64 + l) * 8);
      acc[0][ct] = __builtin_amdgcn_mfma_f32_16x16x32_bf16(af0, bf, acc[0][ct], 0, 0, 0);
      acc[1][ct] = __builtin_amdgcn_mfma_f32_16x16x32_bf16(af1, bf, acc[1][ct], 0, 0, 0);
    }
  }
  #pragma unroll
  for (int rt = 0; rt < 2; ++rt){
    #pragma unroll
    for (int ct = 0; ct < 4; ++ct){
      float b = bfc[ct * 16 + l15];
      #pragma unroll
      for (int r = 0; r < 4; ++r){
        int row = w * 32 + rt * 16 + quad * 4 + r;
        Zs[row * LDZ + ct * 16 + l15] = f2bf(fmaxf(acc[rt][ct][r] + b, 0.f));
      }
    }
  }
  __syncthreads();

  // write ZD as fp8 (64 B/row) coalesced from Zs
  {
    unsigned* Zgo = (unsigned*)ZD8;
    for (int c = t; c < 2048; c += 256){
      int row = c >> 4, kc = c & 15;
      uint2 v = *(const uint2*)(Zs + row * LDZ + kc * 4);
      float f0 = __uint_as_float(v.x << 16);
      float f1 = __uint_as_float(v.x & 0xffff0000u);
      float f2 = __uint_as_float(v.y << 16);
      float f3 = __uint_as_float(v.y & 0xffff0000u);
      if (base + row < n) Zgo[base * 16 + c] = pk_fp8x4(f0, f1, f2, f3);
    }
  }

  f32x4 acc2[2][4] = {};
  #pragma unroll
  for (int s = 0; s < 2; ++s){
    bf16x8 af0 = *(const bf16x8*)(Zs + (w * 32 + 0  + l15) * LDZ + s * 32 + quad * 8);
    bf16x8 af1 = *(const bf16x8*)(Zs + (w * 32 + 16 + l15) * LDZ + s * 32 + quad * 8);
    #pragma unroll
    for (int ct = 0; ct < 4; ++ct){
      bf16x8 bf = *(const bf16x8*)(Wndpk + (((long)ct * 2 + s) * 64 + l) * 8);
      acc2[0][ct] = __builtin_amdgcn_mfma_f32_16x16x32_bf16(af0, bf, acc2[0][ct], 0, 0, 0);
      acc2[1][ct] = __builtin_amdgcn_mfma_f32_16x16x32_bf16(af1, bf, acc2[1][ct], 0, 0, 0);
    }
  }
  #pragma unroll
  for (int rt = 0; rt < 2; ++rt){
    #pragma unroll
    for (int ct = 0; ct < 4; ++ct){
      float b = bnode[ct * 16 + l15];
      #pragma unroll
      for (int r = 0; r < 4; ++r){
        long row = base + w * 32 + rt * 16 + quad * 4 + r;
        if (row < n) NF[row * 64 + ct * 16 + l15] = acc2[rt][ct][r] + b;
      }
    }
  }
}

// ---------------- edge scores: 8 edges per wave, fp8 ZD ----------------
__global__ __launch_bounds__(256) void edge_score_kernel(
    const unsigned char* __restrict__ ZD8, const int* __restrict__ src, const int* __restrict__ dst,
    const float* __restrict__ Wedge, const float* __restrict__ bedge,
    float* __restrict__ out_es, int E)
{
  int gid = blockIdx.x * 256 + threadIdx.x;
  int l = threadIdx.x & 63;
  int slot = l >> 3, chunk = l & 7;
  int e = (gid >> 6) * 8 + slot;
  float4 we0 = *(const float4*)(Wedge + chunk * 8);
  float4 we1 = *(const float4*)(Wedge + chunk * 8 + 4);
  float p = 0.f;
  if (e < E){
    int s = src[e], d = dst[e];
    uint2 zs_ = *((const uint2*)ZD8 + (long)s * 8 + chunk);
    uint2 zd_ = *((const uint2*)ZD8 + (long)d * 8 + chunk);
    float a[8], b[8]; unpk_fp8(zs_, a); unpk_fp8(zd_, b);
    p = a[0]*b[0]*we0.x + a[1]*b[1]*we0.y + a[2]*b[2]*we0.z + a[3]*b[3]*we0.w
      + a[4]*b[4]*we1.x + a[5]*b[5]*we1.y + a[6]*b[6]*we1.z + a[7]*b[7]*we1.w;
  }
  p += __shfl_xor(p, 1);
  p += __shfl_xor(p, 2);
  p += __shfl_xor(p, 4);
  if (chunk == 0 && e < E) out_es[e] = p + bedge[0];
}

// ---------------- launch ----------------
extern "C" void kernel_launch(void* const* d_in, const int* in_sizes, int n_in,
                              void* d_out, int out_size, void* d_ws, size_t ws_size,
                              hipStream_t stream)
{
  const float* x     = (const float*)d_in[0];
  const int*   ei    = (const int*)  d_in[1];
  const float* epsv  = (const float*)d_in[3];
  const float* W1    = (const float*)d_in[4];
  const float* as1   = (const float*)d_in[5];
  const float* ad1   = (const float*)d_in[6];
  const float* b1    = (const float*)d_in[7];
  const float* W2    = (const float*)d_in[8];
  const float* as2   = (const float*)d_in[9];
  const float* ad2   = (const float*)d_in[10];
  const float* b2    = (const float*)d_in[11];
  const float* Wmu   = (const float*)d_in[12];
  const float* asmu  = (const float*)d_in[13];
  const float* admu  = (const float*)d_in[14];
  const float* bmu   = (const float*)d_in[15];
  const float* Wlv   = (const float*)d_in[16];
  const float* aslv  = (const float*)d_in[17];
  const float* adlv  = (const float*)d_in[18];
  const float* blv   = (const float*)d_in[19];
  const float* Wfc   = (const float*)d_in[20];
  const float* bfc   = (const float*)d_in[21];
  const float* Wnode = (const float*)d_in[22];
  const float* bnode = (const float*)d_in[23];
  const float* Wedge = (const float*)d_in[24];
  const float* bedge = (const float*)d_in[25];

  const int N = in_sizes[0] / 64;
  const int E = in_sizes[1] / 2;
  const int* srcA = ei;
  const int* dstA = ei + E;

  char* wsb = (char*)d_ws;
  size_t off = 0;
  auto alloc = [&](size_t bytes) -> void* {
    void* p = wsb + off;
    off += (bytes + 255) & ~(size_t)255;
    return p;
  };
  unsigned short* xb    = (unsigned short*)alloc((size_t)N * 64 * 2);
  unsigned short* bufP  = (unsigned short*)alloc((size_t)N * 256 * 2);  // Xagg, later B2
  unsigned short* bufQ  = (unsigned short*)alloc((size_t)N * 256 * 2);  // B1
  unsigned char*  H8    = (unsigned char*) alloc((size_t)N * 256);     // h2 fp8
  unsigned short* Hmuv  = (unsigned short*)alloc((size_t)N * 64 * 2);  // interleaved mu/lv
  unsigned char*  ZD8   = (unsigned char*) alloc((size_t)N * 64);
  unsigned short* zbb   = (unsigned short*)alloc((size_t)N * 32 * 2);
  unsigned short* W1pk  = (unsigned short*)alloc((size_t)64 * 256 * 2);
  unsigned short* W2pk  = (unsigned short*)alloc((size_t)256 * 256 * 2);
  unsigned short* Wmvpk = (unsigned short*)alloc((size_t)256 * 64 * 2);
  unsigned short* Wfcpk = (unsigned short*)alloc((size_t)32 * 64 * 2);
  unsigned short* Wndpk = (unsigned short*)alloc((size_t)64 * 64 * 2);
  float* P1    = (float*)alloc(512 * 4);
  float* S1s   = (float*)alloc((size_t)N * 4 * 4);
  float* S1d   = (float*)alloc((size_t)N * 4 * 4);
  float* S2s   = (float*)alloc((size_t)N * 4 * 4);
  float* S2d   = (float*)alloc((size_t)N * 4 * 4);
  float* Ssm   = (float*)alloc((size_t)N * 4);
  float* Sdm   = (float*)alloc((size_t)N * 4);
  float* Ssl   = (float*)alloc((size_t)N * 4);
  float* Sdl   = (float*)alloc((size_t)N * 4);
  int*   deg   = (int*)  alloc((size_t)N * 2 * 4);
  int*   cursor= deg + N;
  int*   rowptr= (int*)  alloc((size_t)(N + 1) * 4);
  int*   colv  = (int*)  alloc((size_t)E * 4);
  int*   bsum  = (int*)  alloc(1024);
  (void)ws_size; (void)n_in; (void)out_size;

  float* out_mu = (float*)d_out;
  float* out_lv = out_mu + (size_t)N * 32;
  float* out_z  = out_lv + (size_t)N * 32;
  float* out_nf = out_z  + (size_t)N * 32;
  float* out_es = out_nf + (size_t)N * 64;

  const int nb = (N + 255) / 256;

  // CSR build (5 launches)
  zero_ints_kernel<<<(2 * N + 255) / 256, 256, 0, stream>>>(deg, 2 * N);
  count_deg_kernel<<<(E + 255) / 256, 256, 0, stream>>>(dstA, deg, E);
  scan_chunk_kernel<<<nb, 256, 0, stream>>>(deg, rowptr, bsum, N);
  scan_add_kernel<<<nb, 256, 0, stream>>>(rowptr, bsum, nb, N);
  fill_csr_kernel<<<(E + 255) / 256, 256, 0, stream>>>(srcA, dstA, rowptr, cursor, colv, E);

  // all weight packing + P1 (1 launch)
  packall_kernel<<<410, 256, 0, stream>>>(W1, W1pk, W2, W2pk, Wmu, Wlv, Wmvpk,
                                          Wfc, Wfcpk, Wnode, Wndpk, as1, ad1, P1);

  // layer 1
  score1cvt_kernel<<<(N + 255) / 256, 256, 0, stream>>>(x, P1, xb, S1s, S1d, N);
  aggx_kernel<<<(N + 3) / 4, 256, 0, stream>>>(xb, S1s, S1d, rowptr, colv, bufP, N);
  gemm_mfma_kernel<256, 64, 4, true, false, true, false><<<(N + 31) / 32, 256, 0, stream>>>(
      bufP, W1pk, nullptr, nullptr, nullptr, nullptr, b1, bufQ,
      nullptr, nullptr, nullptr, nullptr, N);

  // layer 2
  gemm_mfma_kernel<256, 256, 4, false, true, false, true><<<(N + 31) / 32, 256, 0, stream>>>(
      bufQ, W2pk, as2, ad2, nullptr, nullptr, nullptr, H8,
      S2s, S2d, nullptr, nullptr, N);
  agg256_kernel<<<(N + 3) / 4, 256, 0, stream>>>(H8, S2s, S2d, rowptr, colv, b2, bufP, N);

  // mu / logvar
  gemm_mfma_kernel<256, 256, 1, false, true, false, false><<<(N + 127) / 128, 256, 0, stream>>>(
      bufP, Wmvpk, asmu, admu, aslv, adlv, nullptr, Hmuv,
      Ssm, Sdm, Ssl, Sdl, N);
  agg_muv_kernel<<<(N + 3) / 4, 256, 0, stream>>>(
      Hmuv, Ssm, Sdm, Ssl, Sdl, rowptr, colv, bmu, blv, epsv,
      out_mu, out_lv, out_z, zbb, N);

  // decoder
  decoder_mfma_kernel<<<(N + 127) / 128, 256, 0, stream>>>(
      zbb, Wfcpk, bfc, Wndpk, bnode, ZD8, out_nf, N);
  {
    long waves = ((long)E + 7) / 8;
    long blocks = (waves + 3) / 4;
    edge_score_kernel<<<(int)blocks, 256, 0, stream>>>(ZD8, srcA, dstA, Wedge, bedge, out_es, E);
  }
}

// Round 8
// 337.119 us; speedup vs baseline: 2.4807x; 1.0509x over previous
//
#include <hip/hip_runtime.h>
#include <math.h>

#define NEG_SLOPE 0.2f

__device__ __forceinline__ float lky(float x){ return x > 0.f ? x : NEG_SLOPE * x; }

__device__ __forceinline__ unsigned short f2bf(float f){
  unsigned int u = __float_as_uint(f);
  unsigned int r = (u + 0x7fffu + ((u >> 16) & 1u)) >> 16;
  return (unsigned short)r;
}
__device__ __forceinline__ float bf2f(unsigned short s){
  return __uint_as_float(((unsigned int)s) << 16);
}
__device__ __forceinline__ void unp8(uint4 v, float* f){
  f[0]=__uint_as_float(v.x<<16); f[1]=__uint_as_float(v.x&0xffff0000u);
  f[2]=__uint_as_float(v.y<<16); f[3]=__uint_as_float(v.y&0xffff0000u);
  f[4]=__uint_as_float(v.z<<16); f[5]=__uint_as_float(v.z&0xffff0000u);
  f[6]=__uint_as_float(v.w<<16); f[7]=__uint_as_float(v.w&0xffff0000u);
}
__device__ __forceinline__ uint4 pack8(const float* o){
  uint4 v;
  v.x = (unsigned)f2bf(o[0]) | ((unsigned)f2bf(o[1])<<16);
  v.y = (unsigned)f2bf(o[2]) | ((unsigned)f2bf(o[3])<<16);
  v.z = (unsigned)f2bf(o[4]) | ((unsigned)f2bf(o[5])<<16);
  v.w = (unsigned)f2bf(o[6]) | ((unsigned)f2bf(o[7])<<16);
  return v;
}

typedef __bf16 bf16x8 __attribute__((ext_vector_type(8)));
typedef float  f32x4  __attribute__((ext_vector_type(4)));
typedef float  f32x2  __attribute__((ext_vector_type(2)));

__device__ __forceinline__ uint2 pk_fp8(const float* f){
  unsigned lo = 0u, hi = 0u;
  lo = __builtin_amdgcn_cvt_pk_fp8_f32(f[0], f[1], (int)lo, false);
  lo = __builtin_amdgcn_cvt_pk_fp8_f32(f[2], f[3], (int)lo, true);
  hi = __builtin_amdgcn_cvt_pk_fp8_f32(f[4], f[5], (int)hi, false);
  hi = __builtin_amdgcn_cvt_pk_fp8_f32(f[6], f[7], (int)hi, true);
  return make_uint2(lo, hi);
}
__device__ __forceinline__ unsigned pk_fp8x4(float f0, float f1, float f2, float f3){
  unsigned u = 0u;
  u = __builtin_amdgcn_cvt_pk_fp8_f32(f0, f1, (int)u, false);
  u = __builtin_amdgcn_cvt_pk_fp8_f32(f2, f3, (int)u, true);
  return u;
}
__device__ __forceinline__ void unpk_fp8(uint2 v, float* f){
  f32x2 a0 = __builtin_amdgcn_cvt_pk_f32_fp8((int)v.x, false);
  f32x2 a1 = __builtin_amdgcn_cvt_pk_f32_fp8((int)v.x, true);
  f32x2 a2 = __builtin_amdgcn_cvt_pk_f32_fp8((int)v.y, false);
  f32x2 a3 = __builtin_amdgcn_cvt_pk_f32_fp8((int)v.y, true);
  f[0]=a0[0]; f[1]=a0[1]; f[2]=a1[0]; f[3]=a1[1];
  f[4]=a2[0]; f[5]=a2[1]; f[6]=a3[0]; f[7]=a3[1];
}

// ---------------- CSR build ----------------
__global__ void zero_ints_kernel(int* __restrict__ p, int n){
  int i = blockIdx.x * blockDim.x + threadIdx.x;
  if (i < n) p[i] = 0;
}
__global__ void scan_chunk_kernel(const int* __restrict__ deg, int* __restrict__ rowptr,
                                  int* __restrict__ bsum, int n){
  __shared__ int s[256];
  int t = threadIdx.x;
  int i = blockIdx.x * 256 + t;
  int v = (i < n) ? deg[i] : 0;
  s[t] = v; __syncthreads();
  for (int off = 1; off < 256; off <<= 1){
    int x = (t >= off) ? s[t - off] : 0;
    __syncthreads();
    s[t] += x;
    __syncthreads();
  }
  if (i < n) rowptr[i + 1] = s[t];
  if (t == 255) bsum[blockIdx.x] = s[255];
}
// scan bsum in every block, add exclusive prefix, zero cursor
__global__ void scan_add_kernel(int* __restrict__ rowptr, const int* __restrict__ bsum,
                                int* __restrict__ cursor, int nb, int n){
  __shared__ int s[256];
  int t = threadIdx.x;
  int v = (t < nb) ? bsum[t] : 0;
  s[t] = v; __syncthreads();
  for (int off = 1; off < 256; off <<= 1){
    int x = (t >= off) ? s[t - off] : 0;
    __syncthreads();
    s[t] += x;
    __syncthreads();
  }
  int b = blockIdx.x;
  int excl = (b == 0) ? 0 : s[b - 1];
  int i = b * 256 + t;
  if (i < n){ rowptr[i + 1] += excl; cursor[i] = 0; }
  if (i == 0) rowptr[0] = 0;
}
__global__ void fill_csr_kernel(const int* __restrict__ src, const int* __restrict__ dst,
                                const int* __restrict__ rowptr, int* __restrict__ cursor,
                                int* __restrict__ colv, int E){
  int e = blockIdx.x * blockDim.x + threadIdx.x;
  if (e >= E) return;
  int d = dst[e];
  int pos = atomicAdd(&cursor[d], 1);
  colv[rowptr[d] + pos] = src[e];
}

// ---------------- pack helper ----------------
__device__ __forceinline__ void pack_one(const float* Wa, const float* Wb,
                                         int K, int M, int Mhalf,
                                         unsigned short* out, int idx){
  if (idx >= K * M) return;
  int j = idx & 7;
  int l = (idx >> 3) & 63;
  int rest = idx >> 9;
  int KS = K >> 5;
  int s = rest % KS, gct = rest / KS;
  int col = gct * 16 + (l & 15);
  int k   = s * 32 + ((l >> 4) << 3) + j;
  float v;
  if (Wb == nullptr) v = Wa[(long)k * M + col];
  else v = (col < Mhalf) ? Wa[(long)k * Mhalf + col] : Wb[(long)k * Mhalf + (col - Mhalf)];
  out[idx] = f2bf(v);
}

// ---------------- mega kernel: count_deg | weight packs | score1+cvt ----------------
__global__ __launch_bounds__(256) void mega_kernel(
    const int* __restrict__ dstA, int* __restrict__ deg, int E, int nbE,
    const float* __restrict__ W1,  unsigned short* __restrict__ W1pk,
    const float* __restrict__ W2,  unsigned short* __restrict__ W2pk,
    const float* __restrict__ Wmu, const float* __restrict__ Wlv,
    unsigned short* __restrict__ Wmvpk,
    const float* __restrict__ Wfc, unsigned short* __restrict__ Wfcpk,
    const float* __restrict__ Wnd, unsigned short* __restrict__ Wndpk,
    const float* __restrict__ as1, const float* __restrict__ ad1,
    const float* __restrict__ x, unsigned short* __restrict__ xb,
    float* __restrict__ S1s, float* __restrict__ S1d, int n)
{
  int b = blockIdx.x, t = threadIdx.x;
  if (b < nbE){
    int e = b * 256 + t;
    if (e < E) atomicAdd(&deg[dstA[e]], 1);
    return;
  }
  b -= nbE;
  if (b < 408){
    if (b < 64)       pack_one(W1, nullptr, 64, 256, 256, W1pk, b * 256 + t);
    else if (b < 320) pack_one(W2, nullptr, 256, 256, 256, W2pk, (b - 64) * 256 + t);
    else if (b < 384) pack_one(Wmu, Wlv, 256, 64, 32, Wmvpk, (b - 320) * 256 + t);
    else if (b < 392) pack_one(Wfc, nullptr, 32, 64, 64, Wfcpk, (b - 384) * 256 + t);
    else              pack_one(Wnd, nullptr, 64, 64, 64, Wndpk, (b - 392) * 256 + t);
    return;
  }
  b -= 408;
  // score1 + cvt role; compute P = W1 @ a in LDS first
  __shared__ float P[512];
  #pragma unroll
  for (int rep = 0; rep < 2; ++rep){
    int idx = t + rep * 256;
    int sd = idx & 1, h = (idx >> 1) & 3, k = idx >> 3;
    const float* av = sd ? ad1 : as1;
    float acc = 0.f;
    for (int c = 0; c < 64; ++c) acc += W1[k * 256 + h * 64 + c] * av[h * 64 + c];
    P[idx] = acc;
  }
  __syncthreads();
  int nid = b * 256 + t;
  if (nid >= n) return;
  const float4* xr = (const float4*)x + (long)nid * 16;
  uint4* xw = (uint4*)xb + (long)nid * 8;
  float acc[8] = {0,0,0,0,0,0,0,0};
  for (int kc = 0; kc < 16; kc += 2){
    float4 v0 = xr[kc], v1 = xr[kc + 1];
    uint4 o;
    o.x = (unsigned)f2bf(v0.x) | ((unsigned)f2bf(v0.y) << 16);
    o.y = (unsigned)f2bf(v0.z) | ((unsigned)f2bf(v0.w) << 16);
    o.z = (unsigned)f2bf(v1.x) | ((unsigned)f2bf(v1.y) << 16);
    o.w = (unsigned)f2bf(v1.z) | ((unsigned)f2bf(v1.w) << 16);
    xw[kc >> 1] = o;
    float vf[8] = {v0.x, v0.y, v0.z, v0.w, v1.x, v1.y, v1.z, v1.w};
    #pragma unroll
    for (int j = 0; j < 8; ++j){
      int k = kc * 4 + j;
      #pragma unroll
      for (int o8 = 0; o8 < 8; ++o8) acc[o8] += vf[j] * P[k * 8 + o8];
    }
  }
  *(float4*)(S1s + nid * 4) = make_float4(acc[0], acc[2], acc[4], acc[6]);
  *(float4*)(S1d + nid * 4) = make_float4(acc[1], acc[3], acc[5], acc[7]);
}

// ---------------- layer-1 aggregation of x: 4 edges in flight ----------------
// slot = l>>4 (edge), cl = l&15 (4 bf16 cols via uint2)
__global__ __launch_bounds__(256) void aggx_kernel(
    const unsigned short* __restrict__ xb,
    const float* __restrict__ Ss, const float* __restrict__ Sd,
    const int* __restrict__ rowptr, const int* __restrict__ colv,
    unsigned short* __restrict__ Xagg, int n)
{
  int wv = threadIdx.x >> 6, l = threadIdx.x & 63;
  int nid = blockIdx.x * 4 + wv;
  if (nid >= n) return;
  int slot = l >> 4;
  int cl = l & 15;
  float4 sdv = *(const float4*)(Sd + (long)nid * 4);
  const uint2* xb2 = (const uint2*)xb;
  float acc[4][4] = {};
  float sumw[4] = {0.f, 0.f, 0.f, 0.f};
  int beg = rowptr[nid], end = rowptr[nid + 1];
  for (int jj = beg + slot; jj < end; jj += 4){
    int s = colv[jj];
    float4 a = *(const float4*)(Ss + (long)s * 4);
    float wx = __expf(lky(a.x + sdv.x));
    float wy = __expf(lky(a.y + sdv.y));
    float wz = __expf(lky(a.z + sdv.z));
    float ww = __expf(lky(a.w + sdv.w));
    uint2 xv = xb2[(long)s * 16 + cl];
    float f0 = __uint_as_float(xv.x << 16);
    float f1 = __uint_as_float(xv.x & 0xffff0000u);
    float f2 = __uint_as_float(xv.y << 16);
    float f3 = __uint_as_float(xv.y & 0xffff0000u);
    acc[0][0] += wx*f0; acc[0][1] += wx*f1; acc[0][2] += wx*f2; acc[0][3] += wx*f3;
    acc[1][0] += wy*f0; acc[1][1] += wy*f1; acc[1][2] += wy*f2; acc[1][3] += wy*f3;
    acc[2][0] += wz*f0; acc[2][1] += wz*f1; acc[2][2] += wz*f2; acc[2][3] += wz*f3;
    acc[3][0] += ww*f0; acc[3][1] += ww*f1; acc[3][2] += ww*f2; acc[3][3] += ww*f3;
    sumw[0] += wx; sumw[1] += wy; sumw[2] += wz; sumw[3] += ww;
  }
  #pragma unroll
  for (int d = 16; d <= 32; d <<= 1){
    #pragma unroll
    for (int h = 0; h < 4; ++h){
      #pragma unroll
      for (int j = 0; j < 4; ++j) acc[h][j] += __shfl_xor(acc[h][j], d);
      sumw[h] += __shfl_xor(sumw[h], d);
    }
  }
  float4 ssv = *(const float4*)(Ss + (long)nid * 4);
  uint2 xv = xb2[(long)nid * 16 + cl];
  float f0 = __uint_as_float(xv.x << 16);
  float f1 = __uint_as_float(xv.x & 0xffff0000u);
  float f2 = __uint_as_float(xv.y << 16);
  float f3 = __uint_as_float(xv.y & 0xffff0000u);
  float wsh[4] = { __expf(lky(ssv.x + sdv.x)), __expf(lky(ssv.y + sdv.y)),
                   __expf(lky(ssv.z + sdv.z)), __expf(lky(ssv.w + sdv.w)) };
  if (l < 16){
    uint2* Xo = (uint2*)Xagg;
    #pragma unroll
    for (int h = 0; h < 4; ++h){
      float inv = 1.f / (sumw[h] + wsh[h] + 1e-16f);
      float o0 = (acc[h][0] + wsh[h] * f0) * inv;
      float o1 = (acc[h][1] + wsh[h] * f1) * inv;
      float o2 = (acc[h][2] + wsh[h] * f2) * inv;
      float o3 = (acc[h][3] + wsh[h] * f3) * inv;
      uint2 ov;
      ov.x = (unsigned)f2bf(o0) | ((unsigned)f2bf(o1) << 16);
      ov.y = (unsigned)f2bf(o2) | ((unsigned)f2bf(o3) << 16);
      Xo[(long)nid * 64 + h * 16 + cl] = ov;
    }
  }
}

// ---------------- fused GEMM1(BD)+relu+GEMM2+scores, fp8 out ----------------
// block = 32 nodes, wave w = head w (cols [w*64,+64) in both GEMMs)
__global__ __launch_bounds__(256) void gemm12_kernel(
    const unsigned short* __restrict__ Xagg,
    const unsigned short* __restrict__ W1pk, const unsigned short* __restrict__ W2pk,
    const float* __restrict__ b1,
    const float* __restrict__ a_s, const float* __restrict__ a_d,
    unsigned char* __restrict__ H8,
    float* __restrict__ Ss, float* __restrict__ Sd, int n)
{
  constexpr int LDA = 264;
  __shared__ unsigned short As[32 * LDA];
  __shared__ unsigned short Bs[32 * LDA];
  const int t = threadIdx.x;
  const int w = t >> 6, l = t & 63;
  const int quad = l >> 4, l15 = l & 15;
  const long base = (long)blockIdx.x * 32;

  {
    const uint4* Xg = (const uint4*)Xagg;
    long g0 = base * 32;
    long lim = (long)n * 32;
    for (int c = t; c < 1024; c += 256){
      int row = c >> 5, kc = c & 31;
      uint4 v = make_uint4(0u, 0u, 0u, 0u);
      if (g0 + c < lim) v = Xg[g0 + c];
      *(uint4*)(As + row * LDA + kc * 8) = v;
    }
  }
  __syncthreads();

  // GEMM1 block-diagonal: K=64 (head w's features)
  f32x4 acc1[2][4] = {};
  const int abase = w * 64;
  #pragma unroll
  for (int s = 0; s < 2; ++s){
    bf16x8 af0 = *(const bf16x8*)(As + (0  + l15) * LDA + abase + s * 32 + quad * 8);
    bf16x8 af1 = *(const bf16x8*)(As + (16 + l15) * LDA + abase + s * 32 + quad * 8);
    #pragma unroll
    for (int ct = 0; ct < 4; ++ct){
      int gct = w * 4 + ct;
      bf16x8 bf = *(const bf16x8*)(W1pk + (((long)gct * 2 + s) * 64 + l) * 8);
      acc1[0][ct] = __builtin_amdgcn_mfma_f32_16x16x32_bf16(af0, bf, acc1[0][ct], 0, 0, 0);
      acc1[1][ct] = __builtin_amdgcn_mfma_f32_16x16x32_bf16(af1, bf, acc1[1][ct], 0, 0, 0);
    }
  }
  // bias + relu -> Bs (B1 tile, never leaves LDS)
  #pragma unroll
  for (int rt = 0; rt < 2; ++rt){
    #pragma unroll
    for (int ct = 0; ct < 4; ++ct){
      float b = b1[w * 64 + ct * 16 + l15];
      #pragma unroll
      for (int r = 0; r < 4; ++r){
        int row = rt * 16 + quad * 4 + r;
        Bs[row * LDA + w * 64 + ct * 16 + l15] = f2bf(fmaxf(acc1[rt][ct][r] + b, 0.f));
      }
    }
  }
  __syncthreads();

  // GEMM2: K=256 from Bs
  f32x4 acc[2][4] = {};
  for (int s = 0; s < 8; ++s){
    bf16x8 af0 = *(const bf16x8*)(Bs + (0  + l15) * LDA + s * 32 + quad * 8);
    bf16x8 af1 = *(const bf16x8*)(Bs + (16 + l15) * LDA + s * 32 + quad * 8);
    #pragma unroll
    for (int ct = 0; ct < 4; ++ct){
      int gct = w * 4 + ct;
      bf16x8 bf = *(const bf16x8*)(W2pk + (((long)gct * 8 + s) * 64 + l) * 8);
      acc[0][ct] = __builtin_amdgcn_mfma_f32_16x16x32_bf16(af0, bf, acc[0][ct], 0, 0, 0);
      acc[1][ct] = __builtin_amdgcn_mfma_f32_16x16x32_bf16(af1, bf, acc[1][ct], 0, 0, 0);
    }
  }

  // fused S2 scores (head = w)
  {
    float asv[4], adv[4];
    #pragma unroll
    for (int ct = 0; ct < 4; ++ct){
      int col = w * 64 + ct * 16 + l15;
      asv[ct] = a_s[col]; adv[ct] = a_d[col];
    }
    #pragma unroll
    for (int rt = 0; rt < 2; ++rt){
      #pragma unroll
      for (int r = 0; r < 4; ++r){
        float ps = 0.f, pd = 0.f;
        #pragma unroll
        for (int ct = 0; ct < 4; ++ct){
          float v = acc[rt][ct][r];
          ps += v * asv[ct]; pd += v * adv[ct];
        }
        ps += __shfl_xor(ps, 8); pd += __shfl_xor(pd, 8);
        ps += __shfl_xor(ps, 4); pd += __shfl_xor(pd, 4);
        ps += __shfl_xor(ps, 2); pd += __shfl_xor(pd, 2);
        ps += __shfl_xor(ps, 1); pd += __shfl_xor(pd, 1);
        long node = base + rt * 16 + quad * 4 + r;
        if (l15 == 0 && node < n){ Ss[node * 4 + w] = ps; Sd[node * 4 + w] = pd; }
      }
    }
  }

  // stage bf16 into As (reuse), then fp8 out
  #pragma unroll
  for (int rt = 0; rt < 2; ++rt){
    #pragma unroll
    for (int ct = 0; ct < 4; ++ct){
      #pragma unroll
      for (int r = 0; r < 4; ++r){
        int row = rt * 16 + quad * 4 + r;
        As[row * 256 + w * 64 + ct * 16 + l15] = f2bf(acc[rt][ct][r]);
      }
    }
  }
  __syncthreads();
  {
    uint2* Hg = (uint2*)H8;
    for (int c = t; c < 1024; c += 256){
      int row = c >> 5;
      uint4 v = *(const uint4*)(As + c * 8);
      float f[8]; unp8(v, f);
      if (base + row < n) Hg[base * 32 + c] = pk_fp8(f);
    }
  }
}

// ---------------- layer-2 aggregation: fp8 gather, 4 edges in flight ----------------
// slot = l>>4, cl = l&15 (16 fp8 cols via uint4; head = cl>>2)
__global__ __launch_bounds__(256) void agg256_kernel(
    const unsigned char* __restrict__ H8,
    const float* __restrict__ Ss, const float* __restrict__ Sd,
    const int* __restrict__ rowptr, const int* __restrict__ colv,
    const float* __restrict__ bias, unsigned short* __restrict__ Out, int n)
{
  int wv = threadIdx.x >> 6, l = threadIdx.x & 63;
  int nid = blockIdx.x * 4 + wv;
  if (nid >= n) return;
  int slot = l >> 4;
  int cl = l & 15;
  int head = cl >> 2;
  float sdv = Sd[(long)nid * 4 + head];
  const uint4* H8v = (const uint4*)H8;
  float acc[16] = {0,0,0,0,0,0,0,0,0,0,0,0,0,0,0,0};
  float sumw = 0.f;
  int beg = rowptr[nid], end = rowptr[nid + 1];
  for (int jj = beg + slot; jj < end; jj += 4){
    int s = colv[jj];
    float wt = __expf(lky(Ss[(long)s * 4 + head] + sdv));
    uint4 hv = H8v[(long)s * 16 + cl];
    float xf[16];
    unpk_fp8(make_uint2(hv.x, hv.y), xf);
    unpk_fp8(make_uint2(hv.z, hv.w), xf + 8);
    #pragma unroll
    for (int j = 0; j < 16; ++j) acc[j] += wt * xf[j];
    sumw += wt;
  }
  #pragma unroll
  for (int d = 16; d <= 32; d <<= 1){
    #pragma unroll
    for (int j = 0; j < 16; ++j) acc[j] += __shfl_xor(acc[j], d);
    sumw += __shfl_xor(sumw, d);
  }
  float wself = __expf(lky(Ss[(long)nid * 4 + head] + sdv));
  uint4 hv = H8v[(long)nid * 16 + cl];
  float xf[16];
  unpk_fp8(make_uint2(hv.x, hv.y), xf);
  unpk_fp8(make_uint2(hv.z, hv.w), xf + 8);
  if (l < 16){
    float inv = 1.f / (sumw + wself + 1e-16f);
    float o[16];
    #pragma unroll
    for (int j = 0; j < 16; ++j){
      float b = bias[cl * 16 + j];
      o[j] = fmaxf((acc[j] + wself * xf[j]) * inv + b, 0.f);
    }
    uint4* Og = (uint4*)Out;
    Og[(long)nid * 32 + cl * 2]     = pack8(o);
    Og[(long)nid * 32 + cl * 2 + 1] = pack8(o + 8);
  }
}

// ---------------- mu/lv GEMM (kept as generic template, CW=1) ----------------
template<int K, int KB, int CW, bool BD, bool SCORES, bool RELU, bool OUT8>
__global__ __launch_bounds__(256) void gemm_mfma_kernel(
    const unsigned short* __restrict__ Xb, const unsigned short* __restrict__ Wpk,
    const float* __restrict__ a_s, const float* __restrict__ a_d,
    const float* __restrict__ a_s2, const float* __restrict__ a_d2,
    const float* __restrict__ bias,
    void* __restrict__ Hout,
    float* __restrict__ Ss, float* __restrict__ Sd,
    float* __restrict__ Ss2, float* __restrict__ Sd2, int n)
{
  constexpr int BR  = (CW == 4) ? 32 : 128;
  constexpr int M   = 64 * CW;
  constexpr int KSB = KB / 32;
  constexpr int LDA = K + 8;
  constexpr int SH  = (BR * LDA > BR * M) ? BR * LDA : BR * M;
  __shared__ unsigned short As[SH];

  const int t = threadIdx.x;
  const int w = t >> 6, l = t & 63;
  const int quad = l >> 4, l15 = l & 15;
  const long base = (long)blockIdx.x * BR;
  const int roww = (CW == 4) ? 0 : w;
  const int colw = (CW == 4) ? w : 0;
  const int abase = BD ? w * KB : 0;

  {
    const uint4* Xg = (const uint4*)Xb;
    long g0 = base * (K / 8);
    long lim = (long)n * (K / 8);
    for (int c = t; c < BR * K / 8; c += 256){
      int row = c / (K / 8), kc = c % (K / 8);
      uint4 v = make_uint4(0u, 0u, 0u, 0u);
      if (g0 + c < lim) v = Xg[g0 + c];
      *(uint4*)(As + row * LDA + kc * 8) = v;
    }
  }
  __syncthreads();

  f32x4 acc[2][4] = {};
  for (int s = 0; s < KSB; ++s){
    bf16x8 af0 = *(const bf16x8*)(As + (roww * 32 + 0  + l15) * LDA + abase + s * 32 + quad * 8);
    bf16x8 af1 = *(const bf16x8*)(As + (roww * 32 + 16 + l15) * LDA + abase + s * 32 + quad * 8);
    #pragma unroll
    for (int ct = 0; ct < 4; ++ct){
      int gct = colw * 4 + ct;
      bf16x8 bf = *(const bf16x8*)(Wpk + (((long)gct * KSB + s) * 64 + l) * 8);
      acc[0][ct] = __builtin_amdgcn_mfma_f32_16x16x32_bf16(af0, bf, acc[0][ct], 0, 0, 0);
      acc[1][ct] = __builtin_amdgcn_mfma_f32_16x16x32_bf16(af1, bf, acc[1][ct], 0, 0, 0);
    }
  }

  if constexpr (SCORES){
    float asm_[2], adm_[2], asl_[2], adl_[2];
    #pragma unroll
    for (int ct = 0; ct < 2; ++ct){
      int col = ct * 16 + l15;
      asm_[ct] = a_s[col];  adm_[ct] = a_d[col];
      asl_[ct] = a_s2[col]; adl_[ct] = a_d2[col];
    }
    #pragma unroll
    for (int rt = 0; rt < 2; ++rt){
      #pragma unroll
      for (int r = 0; r < 4; ++r){
        float psm = 0.f, pdm = 0.f, psl = 0.f, pdl = 0.f;
        #pragma unroll
        for (int ct = 0; ct < 2; ++ct){
          float vm = acc[rt][ct][r];
          float vl = acc[rt][ct + 2][r];
          psm += vm * asm_[ct]; pdm += vm * adm_[ct];
          psl += vl * asl_[ct]; pdl += vl * adl_[ct];
        }
        #pragma unroll
        for (int d = 8; d >= 1; d >>= 1){
          psm += __shfl_xor(psm, d); pdm += __shfl_xor(pdm, d);
          psl += __shfl_xor(psl, d); pdl += __shfl_xor(pdl, d);
        }
        long node = base + w * 32 + rt * 16 + quad * 4 + r;
        if (l15 == 0 && node < n){
          Ss[node]  = psm; Sd[node]  = pdm;
          Ss2[node] = psl; Sd2[node] = pdl;
        }
      }
    }
  }

  __syncthreads();
  #pragma unroll
  for (int rt = 0; rt < 2; ++rt){
    #pragma unroll
    for (int ct = 0; ct < 4; ++ct){
      #pragma unroll
      for (int r = 0; r < 4; ++r){
        int row = roww * 32 + rt * 16 + quad * 4 + r;
        int col = colw * 64 + ct * 16 + l15;
        float o = acc[rt][ct][r];
        int pos = col;
        if constexpr (CW == 1){ pos = (col < 32) ? (col * 2) : ((col - 32) * 2 + 1); }
        As[row * M + pos] = f2bf(o);
      }
    }
  }
  __syncthreads();
  {
    uint4* Hg = (uint4*)Hout;
    for (int c = t; c < BR * M / 8; c += 256){
      int row = c / (M / 8);
      if (base + row < n) Hg[base * (M / 8) + c] = *(const uint4*)(As + c * 8);
    }
  }
}

// ---------------- mu/lv aggregation + reparameterize: 4 edges in flight ----------------
// slot = l>>4, cl = l&15 (2 interleaved (mu,lv) uints via uint2)
__global__ __launch_bounds__(256) void agg_muv_kernel(
    const unsigned short* __restrict__ Hmuv,
    const float* __restrict__ Ssm, const float* __restrict__ Sdm,
    const float* __restrict__ Ssl, const float* __restrict__ Sdl,
    const int* __restrict__ rowptr, const int* __restrict__ colv,
    const float* __restrict__ bmu, const float* __restrict__ blv,
    const float* __restrict__ epsv,
    float* __restrict__ out_mu, float* __restrict__ out_lv, float* __restrict__ out_z,
    unsigned short* __restrict__ zb, int n)
{
  int wv = threadIdx.x >> 6, l = threadIdx.x & 63;
  int nid = blockIdx.x * 4 + wv;
  if (nid >= n) return;
  int slot = l >> 4;
  int cl = l & 15;
  float sdm = Sdm[nid], sdl = Sdl[nid];
  const uint2* Hm2 = (const uint2*)Hmuv;
  float am0 = 0.f, al0 = 0.f, am1 = 0.f, al1 = 0.f, summ = 0.f, suml = 0.f;
  int beg = rowptr[nid], end = rowptr[nid + 1];
  for (int jj = beg + slot; jj < end; jj += 4){
    int s = colv[jj];
    float wm = __expf(lky(Ssm[s] + sdm));
    float wl = __expf(lky(Ssl[s] + sdl));
    uint2 hv = Hm2[(long)s * 16 + cl];
    am0 += wm * __uint_as_float(hv.x << 16);
    al0 += wl * __uint_as_float(hv.x & 0xffff0000u);
    am1 += wm * __uint_as_float(hv.y << 16);
    al1 += wl * __uint_as_float(hv.y & 0xffff0000u);
    summ += wm; suml += wl;
  }
  #pragma unroll
  for (int d = 16; d <= 32; d <<= 1){
    am0 += __shfl_xor(am0, d); al0 += __shfl_xor(al0, d);
    am1 += __shfl_xor(am1, d); al1 += __shfl_xor(al1, d);
    summ += __shfl_xor(summ, d); suml += __shfl_xor(suml, d);
  }
  float wms = __expf(lky(Ssm[nid] + sdm));
  float wls = __expf(lky(Ssl[nid] + sdl));
  uint2 hv = Hm2[(long)nid * 16 + cl];
  float mus0 = __uint_as_float(hv.x << 16);
  float lvs0 = __uint_as_float(hv.x & 0xffff0000u);
  float mus1 = __uint_as_float(hv.y << 16);
  float lvs1 = __uint_as_float(hv.y & 0xffff0000u);
  if (l < 16){
    int c0 = cl * 2;
    float invm = 1.f / (summ + wms + 1e-16f);
    float invl = 1.f / (suml + wls + 1e-16f);
    float mu0 = (am0 + wms * mus0) * invm + bmu[c0];
    float lv0 = (al0 + wls * lvs0) * invl + blv[c0];
    float mu1 = (am1 + wms * mus1) * invm + bmu[c0 + 1];
    float lv1 = (al1 + wls * lvs1) * invl + blv[c0 + 1];
    float2 ev = *(const float2*)(epsv + (long)nid * 32 + c0);
    float z0 = mu0 + ev.x * expf(0.5f * lv0);
    float z1 = mu1 + ev.y * expf(0.5f * lv1);
    *(float2*)(out_mu + (long)nid * 32 + c0) = make_float2(mu0, mu1);
    *(float2*)(out_lv + (long)nid * 32 + c0) = make_float2(lv0, lv1);
    *(float2*)(out_z  + (long)nid * 32 + c0) = make_float2(z0, z1);
    *((unsigned*)zb + (long)nid * 16 + cl) = (unsigned)f2bf(z0) | ((unsigned)f2bf(z1) << 16);
  }
}

// ---------------- decoder: MFMA fused, ZD out as fp8 ----------------
__global__ __launch_bounds__(256) void decoder_mfma_kernel(
    const unsigned short* __restrict__ zb,
    const unsigned short* __restrict__ Wfcpk, const float* __restrict__ bfc,
    const unsigned short* __restrict__ Wndpk, const float* __restrict__ bnode,
    unsigned char* __restrict__ ZD8, float* __restrict__ NF, int n)
{
  constexpr int LDA = 40;
  constexpr int LDZ = 72;
  __shared__ unsigned short As[128 * LDA];
  __shared__ unsigned short Zs[128 * LDZ];
  const int t = threadIdx.x;
  const int w = t >> 6, l = t & 63;
  const int quad = l >> 4, l15 = l & 15;
  const long base = (long)blockIdx.x * 128;

  {
    const uint4* Zg = (const uint4*)zb;
    long g0 = base * 4;
    long lim = (long)n * 4;
    for (int c = t; c < 512; c += 256){
      int row = c >> 2, kc = c & 3;
      uint4 v = make_uint4(0u, 0u, 0u, 0u);
      if (g0 + c < lim) v = Zg[g0 + c];
      *(uint4*)(As + row * LDA + kc * 8) = v;
    }
  }
  __syncthreads();

  f32x4 acc[2][4] = {};
  {
    bf16x8 af0 = *(const bf16x8*)(As + (w * 32 + 0  + l15) * LDA + quad * 8);
    bf16x8 af1 = *(const bf16x8*)(As + (w * 32 + 16 + l15) * LDA + quad * 8);
    #pragma unroll
    for (int ct = 0; ct < 4; ++ct){
      bf16x8 bf = *(const bf16x8*)(Wfcpk + (((long)ct) * 64 + l) * 8);
      acc[0][ct] = __builtin_amdgcn_mfma_f32_16x16x32_bf16(af0, bf, acc[0][ct], 0, 0, 0);
      acc[1][ct] = __builtin_amdgcn_mfma_f32_16x16x32_bf16(af1, bf, acc[1][ct], 0, 0, 0);
    }
  }
  #pragma unroll
  for (int rt = 0; rt < 2; ++rt){
    #pragma unroll
    for (int ct = 0; ct < 4; ++ct){
      float b = bfc[ct * 16 + l15];
      #pragma unroll
      for (int r = 0; r < 4; ++r){
        int row = w * 32 + rt * 16 + quad * 4 + r;
        Zs[row * LDZ + ct * 16 + l15] = f2bf(fmaxf(acc[rt][ct][r] + b, 0.f));
      }
    }
  }
  __syncthreads();

  {
    unsigned* Zgo = (unsigned*)ZD8;
    for (int c = t; c < 2048; c += 256){
      int row = c >> 4, kc = c & 15;
      uint2 v = *(const uint2*)(Zs + row * LDZ + kc * 4);
      float f0 = __uint_as_float(v.x << 16);
      float f1 = __uint_as_float(v.x & 0xffff0000u);
      float f2 = __uint_as_float(v.y << 16);
      float f3 = __uint_as_float(v.y & 0xffff0000u);
      if (base + row < n) Zgo[base * 16 + c] = pk_fp8x4(f0, f1, f2, f3);
    }
  }

  f32x4 acc2[2][4] = {};
  #pragma unroll
  for (int s = 0; s < 2; ++s){
    bf16x8 af0 = *(const bf16x8*)(Zs + (w * 32 + 0  + l15) * LDZ + s * 32 + quad * 8);
    bf16x8 af1 = *(const bf16x8*)(Zs + (w * 32 + 16 + l15) * LDZ + s * 32 + quad * 8);
    #pragma unroll
    for (int ct = 0; ct < 4; ++ct){
      bf16x8 bf = *(const bf16x8*)(Wndpk + (((long)ct * 2 + s) * 64 + l) * 8);
      acc2[0][ct] = __builtin_amdgcn_mfma_f32_16x16x32_bf16(af0, bf, acc2[0][ct], 0, 0, 0);
      acc2[1][ct] = __builtin_amdgcn_mfma_f32_16x16x32_bf16(af1, bf, acc2[1][ct], 0, 0, 0);
    }
  }
  #pragma unroll
  for (int rt = 0; rt < 2; ++rt){
    #pragma unroll
    for (int ct = 0; ct < 4; ++ct){
      float b = bnode[ct * 16 + l15];
      #pragma unroll
      for (int r = 0; r < 4; ++r){
        long row = base + w * 32 + rt * 16 + quad * 4 + r;
        if (row < n) NF[row * 64 + ct * 16 + l15] = acc2[rt][ct][r] + b;
      }
    }
  }
}

// ---------------- edge scores: 8 edges per wave, fp8 ZD ----------------
__global__ __launch_bounds__(256) void edge_score_kernel(
    const unsigned char* __restrict__ ZD8, const int* __restrict__ src, const int* __restrict__ dst,
    const float* __restrict__ Wedge, const float* __restrict__ bedge,
    float* __restrict__ out_es, int E)
{
  int gid = blockIdx.x * 256 + threadIdx.x;
  int l = threadIdx.x & 63;
  int slot = l >> 3, chunk = l & 7;
  int e = (gid >> 6) * 8 + slot;
  float4 we0 = *(const float4*)(Wedge + chunk * 8);
  float4 we1 = *(const float4*)(Wedge + chunk * 8 + 4);
  float p = 0.f;
  if (e < E){
    int s = src[e], d = dst[e];
    uint2 zs_ = *((const uint2*)ZD8 + (long)s * 8 + chunk);
    uint2 zd_ = *((const uint2*)ZD8 + (long)d * 8 + chunk);
    float a[8], b[8]; unpk_fp8(zs_, a); unpk_fp8(zd_, b);
    p = a[0]*b[0]*we0.x + a[1]*b[1]*we0.y + a[2]*b[2]*we0.z + a[3]*b[3]*we0.w
      + a[4]*b[4]*we1.x + a[5]*b[5]*we1.y + a[6]*b[6]*we1.z + a[7]*b[7]*we1.w;
  }
  p += __shfl_xor(p, 1);
  p += __shfl_xor(p, 2);
  p += __shfl_xor(p, 4);
  if (chunk == 0 && e < E) out_es[e] = p + bedge[0];
}

// ---------------- launch ----------------
extern "C" void kernel_launch(void* const* d_in, const int* in_sizes, int n_in,
                              void* d_out, int out_size, void* d_ws, size_t ws_size,
                              hipStream_t stream)
{
  const float* x     = (const float*)d_in[0];
  const int*   ei    = (const int*)  d_in[1];
  const float* epsv  = (const float*)d_in[3];
  const float* W1    = (const float*)d_in[4];
  const float* as1   = (const float*)d_in[5];
  const float* ad1   = (const float*)d_in[6];
  const float* b1    = (const float*)d_in[7];
  const float* W2    = (const float*)d_in[8];
  const float* as2   = (const float*)d_in[9];
  const float* ad2   = (const float*)d_in[10];
  const float* b2    = (const float*)d_in[11];
  const float* Wmu   = (const float*)d_in[12];
  const float* asmu  = (const float*)d_in[13];
  const float* admu  = (const float*)d_in[14];
  const float* bmu   = (const float*)d_in[15];
  const float* Wlv   = (const float*)d_in[16];
  const float* aslv  = (const float*)d_in[17];
  const float* adlv  = (const float*)d_in[18];
  const float* blv   = (const float*)d_in[19];
  const float* Wfc   = (const float*)d_in[20];
  const float* bfc   = (const float*)d_in[21];
  const float* Wnode = (const float*)d_in[22];
  const float* bnode = (const float*)d_in[23];
  const float* Wedge = (const float*)d_in[24];
  const float* bedge = (const float*)d_in[25];

  const int N = in_sizes[0] / 64;
  const int E = in_sizes[1] / 2;
  const int* srcA = ei;
  const int* dstA = ei + E;

  char* wsb = (char*)d_ws;
  size_t off = 0;
  auto alloc = [&](size_t bytes) -> void* {
    void* p = wsb + off;
    off += (bytes + 255) & ~(size_t)255;
    return p;
  };
  unsigned short* xb    = (unsigned short*)alloc((size_t)N * 64 * 2);
  unsigned short* bufP  = (unsigned short*)alloc((size_t)N * 256 * 2);  // Xagg, later B2
  unsigned char*  H8    = (unsigned char*) alloc((size_t)N * 256);     // h2 fp8
  unsigned short* Hmuv  = (unsigned short*)alloc((size_t)N * 64 * 2);  // interleaved mu/lv
  unsigned char*  ZD8   = (unsigned char*) alloc((size_t)N * 64);
  unsigned short* zbb   = (unsigned short*)alloc((size_t)N * 32 * 2);
  unsigned short* W1pk  = (unsigned short*)alloc((size_t)64 * 256 * 2);
  unsigned short* W2pk  = (unsigned short*)alloc((size_t)256 * 256 * 2);
  unsigned short* Wmvpk = (unsigned short*)alloc((size_t)256 * 64 * 2);
  unsigned short* Wfcpk = (unsigned short*)alloc((size_t)32 * 64 * 2);
  unsigned short* Wndpk = (unsigned short*)alloc((size_t)64 * 64 * 2);
  float* S1s   = (float*)alloc((size_t)N * 4 * 4);
  float* S1d   = (float*)alloc((size_t)N * 4 * 4);
  float* S2s   = (float*)alloc((size_t)N * 4 * 4);
  float* S2d   = (float*)alloc((size_t)N * 4 * 4);
  float* Ssm   = (float*)alloc((size_t)N * 4);
  float* Sdm   = (float*)alloc((size_t)N * 4);
  float* Ssl   = (float*)alloc((size_t)N * 4);
  float* Sdl   = (float*)alloc((size_t)N * 4);
  int*   deg   = (int*)  alloc((size_t)N * 4);
  int*   cursor= (int*)  alloc((size_t)N * 4);
  int*   rowptr= (int*)  alloc((size_t)(N + 1) * 4);
  int*   colv  = (int*)  alloc((size_t)E * 4);
  int*   bsum  = (int*)  alloc(1024);
  (void)ws_size; (void)n_in; (void)out_size;

  float* out_mu = (float*)d_out;
  float* out_lv = out_mu + (size_t)N * 32;
  float* out_z  = out_lv + (size_t)N * 32;
  float* out_nf = out_z  + (size_t)N * 32;
  float* out_es = out_nf + (size_t)N * 64;

  const int nb  = (N + 255) / 256;
  const int nbE = (E + 255) / 256;

  zero_ints_kernel<<<nb, 256, 0, stream>>>(deg, N);
  mega_kernel<<<nbE + 408 + nb, 256, 0, stream>>>(
      dstA, deg, E, nbE,
      W1, W1pk, W2, W2pk, Wmu, Wlv, Wmvpk, Wfc, Wfcpk, Wnode, Wndpk,
      as1, ad1, x, xb, S1s, S1d, N);
  scan_chunk_kernel<<<nb, 256, 0, stream>>>(deg, rowptr, bsum, N);
  scan_add_kernel<<<nb, 256, 0, stream>>>(rowptr, bsum, cursor, nb, N);
  fill_csr_kernel<<<nbE, 256, 0, stream>>>(srcA, dstA, rowptr, cursor, colv, E);

  aggx_kernel<<<(N + 3) / 4, 256, 0, stream>>>(xb, S1s, S1d, rowptr, colv, bufP, N);
  gemm12_kernel<<<(N + 31) / 32, 256, 0, stream>>>(
      bufP, W1pk, W2pk, b1, as2, ad2, H8, S2s, S2d, N);
  agg256_kernel<<<(N + 3) / 4, 256, 0, stream>>>(H8, S2s, S2d, rowptr, colv, b2, bufP, N);

  gemm_mfma_kernel<256, 256, 1, false, true, false, false><<<(N + 127) / 128, 256, 0, stream>>>(
      bufP, Wmvpk, asmu, admu, aslv, adlv, nullptr, Hmuv,
      Ssm, Sdm, Ssl, Sdl, N);
  agg_muv_kernel<<<(N + 3) / 4, 256, 0, stream>>>(
      Hmuv, Ssm, Sdm, Ssl, Sdl, rowptr, colv, bmu, blv, epsv,
      out_mu, out_lv, out_z, zbb, N);

  decoder_mfma_kernel<<<(N + 127) / 128, 256, 0, stream>>>(
      zbb, Wfcpk, bfc, Wndpk, bnode, ZD8, out_nf, N);
  {
    long waves = ((long)E + 7) / 8;
    long blocks = (waves + 3) / 4;
    edge_score_kernel<<<(int)blocks, 256, 0, stream>>>(ZD8, srcA, dstA, Wedge, bedge, out_es, E);
  }
}